// Round 7
// baseline (13486.237 us; speedup 1.0000x reference)
//
#include <hip/hip_runtime.h>
#include <hip/hip_bf16.h>
#include <math.h>

#define NB 32      // batch
#define NN 500     // nodes
#define NF 32      // channels

__device__ __forceinline__ float sigf(float x) { return 1.0f / (1.0f + __expf(-x)); }

// h[b,c,n,t] = b_start[c] + sum_ci w_start[c,ci]*padded_x[b,ci,n,t]; pad 7 zeros at front (19)
__global__ void k_start(const float* x, const float* w, const float* bias, float* h) {
  int idx = blockIdx.x * 256 + threadIdx.x;
  const int total = NB * NF * NN * 19;
  if (idx >= total) return;
  int t = idx % 19;
  int n = (idx / 19) % NN;
  int c = (idx / (19 * NN)) % NF;
  int b = idx / (19 * NN * NF);
  float v = bias[c];
  if (t >= 7) {
    int tx = t - 7;
    v += w[c * 2 + 0] * x[((size_t)(b * 2 + 0) * NN + n) * 12 + tx];
    v += w[c * 2 + 1] * x[((size_t)(b * 2 + 1) * NN + n) * 12 + tx];
  }
  h[idx] = v;
}

// skip0[b,c,n] = b_sk0[c] + sum_{ci,k>=7} w_sk0[c,ci,k]*x[b,ci,n,k-7]
__global__ void k_skip0(const float* x, const float* w, const float* bias, float* s0) {
  int idx = blockIdx.x * 256 + threadIdx.x;
  const int total = NB * 64 * NN;
  if (idx >= total) return;
  int n = idx % NN;
  int c = (idx / NN) % 64;
  int b = idx / (NN * 64);
  float v = bias[c];
  for (int ci = 0; ci < 2; ci++)
    for (int k = 7; k < 19; k++)
      v += w[(c * 2 + ci) * 19 + k] * x[((size_t)(b * 2 + ci) * NN + n) * 12 + (k - 7)];
  s0[idx] = v;
}

// ---- fused gated-TCN + fc, register-blocked, 8 nodes per block ----
template<int K, int L, int TP, int TCAT, int TO>
__device__ __forceinline__ void gtu_seg(const float* __restrict__ wseg,
                                        const float* __restrict__ bg,
                                        const float* __restrict__ hbase,
                                        const float* __restrict__ fw,
                                        float (&oacc)[TO], int c, int tbase) {
  float y0[L], y1[L];
#pragma unroll
  for (int t = 0; t < L; t++) { y0[t] = 0.f; y1[t] = 0.f; }
#pragma unroll 2
  for (int ci = 0; ci < NF; ci++) {
    float hrow[L + K - 1];
#pragma unroll
    for (int t = 0; t < L + K - 1; t++) hrow[t] = hbase[ci * TP + t];
    float w0[K], w1[K];
#pragma unroll
    for (int j = 0; j < K; j++) {
      w0[j] = wseg[(c * NF + ci) * K + j];
      w1[j] = wseg[((c + 32) * NF + ci) * K + j];
    }
#pragma unroll
    for (int t = 0; t < L; t++)
#pragma unroll
      for (int j = 0; j < K; j++) {
        y0[t] += w0[j] * hrow[t + j];
        y1[t] += w1[j] * hrow[t + j];
      }
  }
  float b0 = bg[c], b1 = bg[c + 32];
#pragma unroll
  for (int t = 0; t < L; t++) {
    float tcv = tanhf(y0[t] + b0) * sigf(y1[t] + b1);
#pragma unroll
    for (int o = 0; o < TO; o++) oacc[o] += tcv * fw[o * TCAT + tbase + t];
  }
}

template<int TI, int TO>
__global__ __launch_bounds__(256) void k_gtufc_t(
    const float* __restrict__ h,
    const float* __restrict__ wg3, const float* __restrict__ bg3,
    const float* __restrict__ wg5, const float* __restrict__ bg5,
    const float* __restrict__ wg7, const float* __restrict__ bg7,
    const float* __restrict__ fw, const float* __restrict__ fb,
    const float* __restrict__ res, float* __restrict__ out) {
  constexpr int TCAT = 3 * TI - 12;
  constexpr int TP = (TI + 3) & ~3;
  constexpr int OFF = TI - TO;
  const int b = blockIdx.y;
  const int n0 = blockIdx.x * 8;
  const int tid = threadIdx.x;
  const int c = tid & 31, nn = tid >> 5;
  const int n = n0 + nn;
  __shared__ float hs[8 * NF * TP];
  for (int l = tid; l < 8 * NF * TP; l += 256) {
    int t = l % TP;
    int ci = (l / TP) % NF;
    int n2 = l / (TP * NF);
    int gn = n0 + n2;
    hs[l] = (t < TI && gn < NN) ? h[((size_t)(b * NF + ci) * NN + gn) * TI + t] : 0.f;
  }
  __syncthreads();
  const float* hbase = hs + nn * NF * TP;
  float oacc[TO];
#pragma unroll
  for (int o = 0; o < TO; o++) oacc[o] = 0.f;
  gtu_seg<3, TI - 2, TP, TCAT, TO>(wg3, bg3, hbase, fw, oacc, c, 0);
  gtu_seg<5, TI - 4, TP, TCAT, TO>(wg5, bg5, hbase, fw, oacc, c, TI - 2);
  gtu_seg<7, TI - 6, TP, TCAT, TO>(wg7, bg7, hbase, fw, oacc, c, 2 * TI - 6);
  if (n < NN) {
    size_t base = (size_t)(b * NF + c) * NN + n;
#pragma unroll
    for (int o = 0; o < TO; o++) {
      float v = fmaxf(hbase[c * TP + OFF + o] + oacc[o] + fb[o], 0.f);
      if (res) v += res[base * TI + OFF + o];
      out[base * TO + o] = v;
    }
  }
}

// ---- skip conv, LDS h staging, weights in registers, K unrolled ----
template<int TI, int K>
__global__ __launch_bounds__(256) void k_skipconv_t(
    const float* __restrict__ h, const float* __restrict__ w,
    const float* __restrict__ bias, const float* __restrict__ prev, int prevT,
    float* __restrict__ out) {
  constexpr int TP = (TI + 3) & ~3;
  const int b = blockIdx.y, n0 = blockIdx.x * 8, tid = threadIdx.x;
  __shared__ float hs[8 * NF * TP];
  for (int l = tid; l < 8 * NF * TP; l += 256) {
    int t = l % TP;
    int ci = (l / TP) % NF;
    int n2 = l / (TP * NF);
    int gn = n0 + n2;
    hs[l] = (t < TI && gn < NN) ? h[((size_t)(b * NF + ci) * NN + gn) * TI + t] : 0.f;
  }
  __syncthreads();
  const int c = tid & 63, ng = tid >> 6;
  float bv = bias[c];
  float o[2][7];
#pragma unroll
  for (int q = 0; q < 2; q++)
#pragma unroll
    for (int t = 0; t < 7; t++) o[q][t] = bv;
  for (int ci = 0; ci < NF; ci++) {
    float wv[K];
#pragma unroll
    for (int j = 0; j < K; j++) wv[j] = w[(c * NF + ci) * K + j];
#pragma unroll
    for (int q = 0; q < 2; q++) {
      const float* hp = hs + ((ng + q * 4) * NF + ci) * TP;
#pragma unroll
      for (int t = 0; t < 7; t++) {
        float s = 0.f;
#pragma unroll
        for (int j = 0; j < K; j++) s += wv[j] * hp[t + j];
        o[q][t] += s;
      }
    }
  }
#pragma unroll
  for (int q = 0; q < 2; q++) {
    int n = n0 + ng + q * 4;
    if (n < NN) {
      size_t base = (size_t)(b * 64 + c) * NN + n;
#pragma unroll
      for (int t = 0; t < 7; t++) {
        float pv = (prevT == 1) ? prev[base] : prev[base * 7 + t];
        out[base * 7 + t] = o[q][t] + pv;
      }
    }
  }
}

// ---- temporal attention ----
__global__ void k_ta_lhs1(const float* h, const float* u1, float* out, int T) {
  int total = NB * T * NF;
  int idx = blockIdx.x * 256 + threadIdx.x;
  if (idx >= total) return;
  int f = idx % NF;
  int t = (idx / NF) % T;
  int b = idx / (NF * T);
  const float* hp = h + ((size_t)(b * NF + f) * NN) * T + t;
  float acc = 0.f;
  for (int n = 0; n < NN; n++) acc += hp[(size_t)n * T] * u1[n];
  out[(b * T + t) * NF + f] = acc;
}
__global__ void k_ta_lhs(const float* l1, const float* u2, float* out, int T) {
  int total = NB * T * NN;
  int idx = blockIdx.x * 256 + threadIdx.x;
  if (idx >= total) return;
  int n = idx % NN;
  int t = (idx / NN) % T;
  int b = idx / (NN * T);
  float acc = 0.f;
  for (int f = 0; f < NF; f++) acc += l1[(b * T + t) * NF + f] * u2[f * NN + n];
  out[idx] = acc;  // (b,t,n)
}
__global__ void k_ta_rhs(const float* h, const float* u3, float* out, int T) {
  int total = NB * NN * T;
  int idx = blockIdx.x * 256 + threadIdx.x;
  if (idx >= total) return;
  int t = idx % T;
  int n = (idx / T) % NN;
  int b = idx / (T * NN);
  float acc = 0.f;
  for (int f = 0; f < NF; f++) acc += u3[f] * h[((size_t)(b * NF + f) * NN + n) * T + t];
  out[idx] = acc;  // (b,n,t)
}
// fused: e0 = sigf(lhs@rhs + be); e1 = ve@e0; e = softmax over t. one block per b.
__global__ __launch_bounds__(256) void k_ta_att(const float* __restrict__ lhs,
                                                const float* __restrict__ rhs,
                                                const float* __restrict__ be,
                                                const float* __restrict__ ve,
                                                float* __restrict__ e, int T) {
  int b = blockIdx.x, tid = threadIdx.x;
  __shared__ float e0[19 * 19];
  __shared__ float e1[19 * 19];
  int TT = T * T;
  for (int l = tid; l < TT; l += 256) {
    int t = l / T, m = l % T;
    float acc = 0.f;
    const float* lp = lhs + ((size_t)b * T + t) * NN;
    const float* rp = rhs + (size_t)b * NN * T + m;
    for (int n = 0; n < NN; n++) acc += lp[n] * rp[(size_t)n * T];
    e0[l] = sigf(acc + be[l]);
  }
  __syncthreads();
  for (int l = tid; l < TT; l += 256) {
    int t = l / T, m = l % T;
    float acc = 0.f;
    for (int j = 0; j < T; j++) acc += ve[t * T + j] * e0[j * T + m];
    e1[l] = acc;
  }
  __syncthreads();
  if (tid < T) {
    int m = tid;
    float mx = -1e30f;
    for (int t = 0; t < T; t++) mx = fmaxf(mx, e1[t * T + m]);
    float s = 0.f;
    for (int t = 0; t < T; t++) s += __expf(e1[t * T + m] - mx);
    float inv = 1.f / s;
    for (int t = 0; t < T; t++)
      e[((size_t)b * T + t) * T + m] = __expf(e1[t * T + m] - mx) * inv;
  }
}
// xt[b,f,n,t] = sum_j e[b,t,j] * h[b,f,n,j]
__global__ void k_xtat(const float* e, const float* h, float* xt, int T) {
  int total = NB * NF * NN * T;
  int idx = blockIdx.x * 256 + threadIdx.x;
  if (idx >= total) return;
  int t = idx % T;
  int n = (idx / T) % NN;
  int f = (idx / (T * NN)) % NF;
  int b = idx / (T * NN * NF);
  const float* hp = h + ((size_t)(b * NF + f) * NN + n) * T;
  float acc = 0.f;
  for (int j = 0; j < T; j++) acc += e[(b * T + t) * T + j] * hp[j];
  xt[idx] = acc;
}

// ---- spatial attention ----
__global__ void k_sa_lhs1(const float* xt, const float* w1, float* out, int T) {
  int total = NB * NN * NF;
  int idx = blockIdx.x * 256 + threadIdx.x;
  if (idx >= total) return;
  int f = idx % NF;
  int n = (idx / NF) % NN;
  int b = idx / (NF * NN);
  const float* xp = xt + ((size_t)(b * NF + f) * NN + n) * T;
  float acc = 0.f;
  for (int t = 0; t < T; t++) acc += xp[t] * w1[t];
  out[(b * NN + n) * NF + f] = acc;
}
__global__ void k_sa_lhs(const float* l1, const float* w2, float* out, int T) {
  int total = NB * NN * T;
  int idx = blockIdx.x * 256 + threadIdx.x;
  if (idx >= total) return;
  int t = idx % T;
  int n = (idx / T) % NN;
  int b = idx / (T * NN);
  float acc = 0.f;
  for (int f = 0; f < NF; f++) acc += l1[(b * NN + n) * NF + f] * w2[f * T + t];
  out[idx] = acc;  // (b,n,t)
}
__global__ void k_sa_rhs(const float* xt, const float* w3, float* out, int T) {
  int total = NB * T * NN;
  int idx = blockIdx.x * 256 + threadIdx.x;
  if (idx >= total) return;
  int n = idx % NN;
  int t = (idx / NN) % T;
  int b = idx / (NN * T);
  float acc = 0.f;
  for (int f = 0; f < NF; f++) acc += w3[f] * xt[((size_t)(b * NF + f) * NN + n) * T + t];
  out[idx] = acc;  // (b,t,n)
}
__global__ void k_sa_prod(const float* lhs, const float* rhs, const float* bs, float* s0, int T) {
  int total = NB * NN * NN;
  int idx = blockIdx.x * 256 + threadIdx.x;
  if (idx >= total) return;
  int m = idx % NN;
  int n = (idx / NN) % NN;
  int b = idx / (NN * NN);
  float acc = 0.f;
  for (int t = 0; t < T; t++)
    acc += lhs[((size_t)b * NN + n) * T + t] * rhs[((size_t)b * T + t) * NN + m];
  s0[idx] = sigf(acc + bs[(size_t)n * NN + m]);
}

// 500x500 transpose (for vs)
__global__ __launch_bounds__(256) void k_transpose(const float* in, float* outT) {
  __shared__ float tile[32][33];
  int x0 = blockIdx.x * 32, y0 = blockIdx.y * 32;
  int tx = threadIdx.x & 31, ty8 = threadIdx.x >> 5;
  for (int yy = ty8; yy < 32; yy += 8) {
    int x = x0 + tx, y = y0 + yy;
    tile[yy][tx] = (x < NN && y < NN) ? in[(size_t)y * NN + x] : 0.f;
  }
  __syncthreads();
  for (int yy = ty8; yy < 32; yy += 8) {
    int x = y0 + tx, y = x0 + yy;
    if (x < NN && y < NN) outT[(size_t)y * NN + x] = tile[tx][yy];
  }
}

// s1T[b,c,r] = (vs @ s0[b])[r,c] — A from vsT (coalesced), b128 LDS reads both sides
__global__ __launch_bounds__(256) void k_gemm_vs(const float* __restrict__ vsT,
                                                 const float* __restrict__ s0,
                                                 float* __restrict__ s1t) {
  __shared__ float As[16][68];
  __shared__ float Bs[16][68];
  int b = blockIdx.z;
  int row0 = blockIdx.y * 64, col0 = blockIdx.x * 64;
  int tx = threadIdx.x, ty = threadIdx.y;
  int tid = ty * 16 + tx;
  float acc[4][4] = {};
  const float* S0 = s0 + (size_t)b * NN * NN;
  for (int k0 = 0; k0 < NN; k0 += 16) {
    for (int l = tid; l < 1024; l += 256) {
      int kk = l >> 6, r = l & 63;
      int gi = row0 + r, gk = k0 + kk;
      As[kk][r] = (gi < NN && gk < NN) ? vsT[(size_t)gk * NN + gi] : 0.f;
    }
    for (int l = tid; l < 1024; l += 256) {
      int kk = l >> 6, cc = l & 63;
      int gk = k0 + kk, gc = col0 + cc;
      Bs[kk][cc] = (gk < NN && gc < NN) ? S0[(size_t)gk * NN + gc] : 0.f;
    }
    __syncthreads();
    for (int kk = 0; kk < 16; kk++) {
      float4 a4 = *(const float4*)&As[kk][ty * 4];
      float4 b4 = *(const float4*)&Bs[kk][tx * 4];
      float a[4] = {a4.x, a4.y, a4.z, a4.w};
      float bb[4] = {b4.x, b4.y, b4.z, b4.w};
#pragma unroll
      for (int i = 0; i < 4; i++)
#pragma unroll
        for (int j = 0; j < 4; j++) acc[i][j] += a[i] * bb[j];
    }
    __syncthreads();
  }
  float* S1 = s1t + (size_t)b * NN * NN;
  for (int j = 0; j < 4; j++)
    for (int i = 0; i < 4; i++) {
      int gi = row0 + ty * 4 + i, gc = col0 + tx * 4 + j;
      if (gi < NN && gc < NN) S1[(size_t)gc * NN + gi] = acc[i][j];  // transposed
    }
}
// softmax over r (contiguous): st[b,c,r] = softmax_r(s1t[b,c,r]); block per (c,b)
__global__ __launch_bounds__(256) void k_sa_smax_row(const float* s1t, float* st) {
  int c = blockIdx.x, b = blockIdx.y;
  int tid = threadIdx.x;
  const float* S = s1t + ((size_t)b * NN + c) * NN;
  float* O = st + ((size_t)b * NN + c) * NN;
  __shared__ float red[256];
  float mx = -1e30f;
  for (int i = tid; i < NN; i += 256) mx = fmaxf(mx, S[i]);
  red[tid] = mx;
  __syncthreads();
  for (int s = 128; s > 0; s >>= 1) {
    if (tid < s) red[tid] = fmaxf(red[tid], red[tid + s]);
    __syncthreads();
  }
  mx = red[0];
  __syncthreads();
  float sum = 0.f;
  for (int i = tid; i < NN; i += 256) sum += __expf(S[i] - mx);
  red[tid] = sum;
  __syncthreads();
  for (int s = 128; s > 0; s >>= 1) {
    if (tid < s) red[tid] += red[tid + s];
    __syncthreads();
  }
  float inv = 1.f / red[0];
  for (int i = tid; i < NN; i += 256) O[i] = __expf(S[i] - mx) * inv;
}

// chebT[k,n,m] = cheb[k,m,n]
__global__ void k_chebT(const float* cheb, float* ct) {
  int total = 3 * NN * NN;
  int idx = blockIdx.x * 256 + threadIdx.x;
  if (idx >= total) return;
  int m = idx % NN;
  int n = (idx / NN) % NN;
  int k = idx / (NN * NN);
  ct[idx] = cheb[((size_t)k * NN + m) * NN + n];
}

// ---- chebyshev conv, wave-per-node, m-chunked LDS (PADDED rows), b128 inner reads ----
template<int T>
__global__ __launch_bounds__(256) void k_cheb_t(const float* __restrict__ h,
                                                const float* __restrict__ st,
                                                const float* __restrict__ ct,
                                                const float* __restrict__ theta,
                                                float* __restrict__ out) {
  constexpr int NFT = NF * T;
  constexpr int HP = NFT + 4;     // padded row stride: NFT%32==0 is a 13-way conflict trap
  constexpr int MC = 16;
  constexpr int R = (NFT + 255) / 256;
  const int b = blockIdx.y;
  const int n0 = blockIdx.x * 4;
  const int tid = threadIdx.x;
  const int g = tid >> 6, lane = tid & 63;  // one node per wave
  __shared__ float hS[MC * HP];
  __shared__ float wS[3][4][MC];
  float acc[3][R][4];
#pragma unroll
  for (int k = 0; k < 3; k++)
#pragma unroll
    for (int r = 0; r < R; r++)
#pragma unroll
      for (int v = 0; v < 4; v++) acc[k][r][v] = 0.f;
  const float* hB = h + (size_t)b * NF * NN * T;
  for (int m0 = 0; m0 < NN; m0 += MC) {
    if (tid < 3 * 4 * MC) {
      int mm = tid & (MC - 1), gg = (tid >> 4) & 3, k = tid >> 6;
      int m = m0 + mm, n = n0 + gg;
      wS[k][gg][mm] = (m < NN)
          ? ct[((size_t)k * NN + n) * NN + m] * st[((size_t)b * NN + n) * NN + m] : 0.f;
    }
    for (int l = tid; l < NF * MC * T; l += 256) {
      int f = l / (MC * T), r = l % (MC * T);
      int mm = r / T, t = r % T;
      int m = m0 + mm;
      hS[mm * HP + f * T + t] = (m < NN) ? hB[(size_t)f * NN * T + (size_t)m * T + t] : 0.f;
    }
    __syncthreads();
#pragma unroll
    for (int mm = 0; mm < MC; mm++) {
      float w0 = wS[0][g][mm], w1 = wS[1][g][mm], w2 = wS[2][g][mm];
#pragma unroll
      for (int r = 0; r < R; r++) {
        int ft = r * 256 + lane * 4;
        if (ft < NFT) {
          float4 x = *(const float4*)&hS[mm * HP + ft];
          acc[0][r][0] += w0 * x.x; acc[0][r][1] += w0 * x.y;
          acc[0][r][2] += w0 * x.z; acc[0][r][3] += w0 * x.w;
          acc[1][r][0] += w1 * x.x; acc[1][r][1] += w1 * x.y;
          acc[1][r][2] += w1 * x.z; acc[1][r][3] += w1 * x.w;
          acc[2][r][0] += w2 * x.x; acc[2][r][1] += w2 * x.y;
          acc[2][r][2] += w2 * x.z; acc[2][r][3] += w2 * x.w;
        }
      }
    }
    __syncthreads();
  }
  // stage acc to LDS (reuse hS), then theta + relu + store
  float* accS = hS;  // 12*NFT <= MC*HP
#pragma unroll
  for (int r = 0; r < R; r++) {
    int ft = r * 256 + lane * 4;
    if (ft < NFT) {
#pragma unroll
      for (int k = 0; k < 3; k++)
#pragma unroll
        for (int v = 0; v < 4; v++) accS[(k * 4 + g) * NFT + ft + v] = acc[k][r][v];
    }
  }
  __syncthreads();
  for (int j = 0; j < (4 * NFT + 255) / 256; j++) {
    int it = tid + j * 256;
    if (it < 4 * NFT) {
      int gg = it / NFT, f2t = it % NFT, f2 = f2t / T, t = f2t % T;
      float o = 0.f;
#pragma unroll
      for (int k = 0; k < 3; k++)
        for (int f = 0; f < NF; f++)
          o += accS[(k * 4 + gg) * NFT + f * T + t] * theta[(k * NF + f) * NF + f2];
      out[((size_t)(b * NF + f2) * NN + (n0 + gg)) * T + t] = fmaxf(o, 0.f);
    }
  }
}

// ---- layer norm over (C,N,T) per sample ----
__global__ void k_zero(float* p, int n) {
  int i = blockIdx.x * 256 + threadIdx.x;
  if (i < n) p[i] = 0.f;
}
__global__ void k_ln_part(const float* x, float* acc, int M) {
  int b = blockIdx.y;
  const float* xp = x + (size_t)b * M;
  float s1 = 0.f, s2 = 0.f;
  for (int i = blockIdx.x * blockDim.x + threadIdx.x; i < M; i += gridDim.x * blockDim.x) {
    float v = xp[i]; s1 += v; s2 += v * v;
  }
  __shared__ float r1[256], r2[256];
  int tid = threadIdx.x;
  r1[tid] = s1; r2[tid] = s2;
  __syncthreads();
  for (int s = 128; s > 0; s >>= 1) {
    if (tid < s) { r1[tid] += r1[tid + s]; r2[tid] += r2[tid + s]; }
    __syncthreads();
  }
  if (tid == 0) { atomicAdd(&acc[b * 2], r1[0]); atomicAdd(&acc[b * 2 + 1], r2[0]); }
}
__global__ void k_ln_norm(const float* x, const float* acc, const float* wn, const float* bn,
                          float* out, int M) {
  int total = NB * M;
  int idx = blockIdx.x * 256 + threadIdx.x;
  if (idx >= total) return;
  int b = idx / M;
  int i = idx % M;
  float mean = acc[b * 2] / M;
  float var = acc[b * 2 + 1] / M - mean * mean;
  float y = (x[idx] - mean) * rsqrtf(var + 1e-5f);
  out[idx] = y * wn[i] + bn[i];
}

// ---- final head ----
__global__ void k_fin1(const float* h, const float* w, const float* bias, const float* skip,
                       float* out) {
  int total = NB * 64 * NN;
  int idx = blockIdx.x * 256 + threadIdx.x;
  if (idx >= total) return;
  int n = idx % NN;
  int c = (idx / NN) % 64;
  int b = idx / (NN * 64);
  float v = bias[c];
  for (int ci = 0; ci < 32; ci++) v += w[c * 32 + ci] * h[(b * NF + ci) * NN + n];
  v += skip[((size_t)(b * 64 + c) * NN + n) * 7 + 6];
  out[idx] = fmaxf(v, 0.f);
}
__global__ void k_fin2(const float* in, const float* w, const float* bias, float* out) {
  int total = NB * 128 * NN;
  int idx = blockIdx.x * 256 + threadIdx.x;
  if (idx >= total) return;
  int n = idx % NN;
  int c = (idx / NN) % 128;
  int b = idx / (NN * 128);
  float v = bias[c];
  for (int ci = 0; ci < 64; ci++) v += w[c * 64 + ci] * in[(b * 64 + ci) * NN + n];
  out[idx] = fmaxf(v, 0.f);
}
__global__ void k_fin3(const float* in, const float* w, const float* bias, float* out) {
  int total = NB * 12 * NN;
  int idx = blockIdx.x * 256 + threadIdx.x;
  if (idx >= total) return;
  int n = idx % NN;
  int c = (idx / NN) % 12;
  int b = idx / (NN * 12);
  float v = bias[c];
  for (int ci = 0; ci < 128; ci++) v += w[c * 128 + ci] * in[(b * 128 + ci) * NN + n];
  out[idx] = v;
}

#define G1(tot) dim3((unsigned)(((tot) + 255) / 256)), dim3(256), 0, stream

extern "C" void kernel_launch(void* const* d_in, const int* in_sizes, int n_in,
                              void* d_out, int out_size, void* d_ws, size_t ws_size,
                              hipStream_t stream) {
  (void)in_sizes; (void)n_in; (void)out_size; (void)ws_size;
  auto I = [&](int i) { return (const float*)d_in[i]; };
  float* W = (float*)d_ws;
  size_t off = 0;
  auto alloc = [&](size_t nel) { float* p = W + off; off += nel; return p; };

  float* bufA  = alloc(9728000);   // h / residual [B,32,N,19max]
  float* bufB  = alloc(9728000);   // h after fc1 / after fc2
  float* bufC  = alloc(9728000);   // x_tat -> s1T(P2) -> cheb output
  float* bufSK = alloc(7168000);   // skip [B,64,N,7]
  float* skip0 = alloc(1024000);   // skip [B,64,N,1]
  float* P1    = alloc(8000000);   // s0 / st; reused for F1/F2 at end
  float* CT    = alloc(750000);    // chebT
  float* VST   = alloc(250000);    // vs transposed (per layer)
  float* TL1   = alloc(19456);
  float* TLH   = alloc(304000);
  float* TRH   = alloc(304000);
  float* TE    = alloc(11552);
  float* SL1   = alloc(512000);
  float* SLH   = alloc(304000);
  float* SRH   = alloc(304000);
  float* ACC   = alloc(64);
  float* P2 = bufC;                // [B,500,500] s1T lives in bufC before k_cheb writes it
  float* F1 = P1;                  // [B,64,N] final head, after P1 (st) is dead
  float* F2 = P1 + 1024000;        // [B,128,N]

  k_start<<<G1(NB * NF * NN * 19)>>>(I(0), I(1), I(2), bufA);
  k_skip0<<<G1(NB * 64 * NN)>>>(I(0), I(3), I(4), skip0);
  k_chebT<<<G1(3 * NN * NN)>>>(I(59), CT);

  dim3 ggt((NN + 7) / 8, NB), bgt(256);
  auto gtufc = [&](int Ti, int To, const float* hin, const float* fw, const float* fb,
                   const float* res, float* o) {
    if (Ti == 19 && To == 19)
      k_gtufc_t<19, 19><<<ggt, bgt, 0, stream>>>(hin, I(5), I(6), I(7), I(8), I(9), I(10), fw, fb, res, o);
    else if (Ti == 19 && To == 13)
      k_gtufc_t<19, 13><<<ggt, bgt, 0, stream>>>(hin, I(5), I(6), I(7), I(8), I(9), I(10), fw, fb, res, o);
    else if (Ti == 13 && To == 13)
      k_gtufc_t<13, 13><<<ggt, bgt, 0, stream>>>(hin, I(5), I(6), I(7), I(8), I(9), I(10), fw, fb, res, o);
    else if (Ti == 13 && To == 7)
      k_gtufc_t<13, 7><<<ggt, bgt, 0, stream>>>(hin, I(5), I(6), I(7), I(8), I(9), I(10), fw, fb, res, o);
    else if (Ti == 7 && To == 7)
      k_gtufc_t<7, 7><<<ggt, bgt, 0, stream>>>(hin, I(5), I(6), I(7), I(8), I(9), I(10), fw, fb, res, o);
    else
      k_gtufc_t<7, 1><<<ggt, bgt, 0, stream>>>(hin, I(5), I(6), I(7), I(8), I(9), I(10), fw, fb, res, o);
  };

  const int Tin[3] = {19, 13, 7}, Tout[3] = {13, 7, 1};
  for (int i = 0; i < 3; i++) {
    int Ti = Tin[i], To = Tout[i];
    // gated TCN + fc1 + relu-add
    gtufc(Ti, Ti, bufA, I(11 + 2 * i), I(12 + 2 * i), nullptr, bufB);
    // skip conv (+ broadcast of T=1 skip0 on first layer)
    if (i == 0)
      k_skipconv_t<19, 13><<<ggt, bgt, 0, stream>>>(bufB, I(23), I(24), skip0, 1, bufSK);
    else if (i == 1)
      k_skipconv_t<13, 7><<<ggt, bgt, 0, stream>>>(bufB, I(25), I(26), bufSK, 7, bufSK);
    else
      k_skipconv_t<7, 1><<<ggt, bgt, 0, stream>>>(bufB, I(27), I(28), bufSK, 7, bufSK);
    // temporal attention
    int ba = 29 + i * 10;
    k_ta_lhs1<<<G1(NB * Ti * NF)>>>(bufB, I(ba + 0), TL1, Ti);
    k_ta_lhs<<<G1(NB * Ti * NN)>>>(TL1, I(ba + 1), TLH, Ti);
    k_ta_rhs<<<G1(NB * NN * Ti)>>>(bufB, I(ba + 2), TRH, Ti);
    k_ta_att<<<dim3(NB), dim3(256), 0, stream>>>(TLH, TRH, I(ba + 3), I(ba + 4), TE, Ti);
    k_xtat<<<G1(NB * NF * NN * Ti)>>>(TE, bufB, bufC, Ti);  // x_tat into bufC
    // spatial attention
    k_sa_lhs1<<<G1(NB * NN * NF)>>>(bufC, I(ba + 5), SL1, Ti);
    k_sa_lhs<<<G1(NB * NN * Ti)>>>(SL1, I(ba + 6), SLH, Ti);
    k_sa_rhs<<<G1(NB * Ti * NN)>>>(bufC, I(ba + 7), SRH, Ti);
    k_sa_prod<<<G1(NB * NN * NN)>>>(SLH, SRH, I(ba + 8), P1, Ti);  // x_tat consumed
    k_transpose<<<dim3(16, 16), dim3(256), 0, stream>>>(I(ba + 9), VST);
    {
      dim3 gg(8, 8, NB), bb(16, 16);
      k_gemm_vs<<<gg, bb, 0, stream>>>(VST, P1, P2);  // s1T into bufC
    }
    k_sa_smax_row<<<dim3(NN, NB), dim3(256), 0, stream>>>(P2, P1);
    // chebyshev graph conv
    {
      dim3 gc(NN / 4, NB), bc(256);
      if (Ti == 19)      k_cheb_t<19><<<gc, bc, 0, stream>>>(bufB, P1, CT, I(60), bufC);
      else if (Ti == 13) k_cheb_t<13><<<gc, bc, 0, stream>>>(bufB, P1, CT, I(60), bufC);
      else               k_cheb_t<7><<<gc, bc, 0, stream>>>(bufB, P1, CT, I(60), bufC);
    }
    // second gated TCN + fc2 + relu-add + residual
    gtufc(Ti, To, bufC, I(17 + 2 * i), I(18 + 2 * i), bufA, bufB);
    // layer norm: bufB -> bufA
    int M = NF * NN * To;
    k_zero<<<dim3(1), dim3(256), 0, stream>>>(ACC, 64);
    k_ln_part<<<dim3(16, NB), dim3(256), 0, stream>>>(bufB, ACC, M);
    k_ln_norm<<<G1(NB * M)>>>(bufB, ACC, I(61 + 2 * i), I(62 + 2 * i), bufA, M);
  }
  // final head
  k_fin1<<<G1(NB * 64 * NN)>>>(bufA, I(67), I(68), bufSK, F1);
  k_fin2<<<G1(NB * 128 * NN)>>>(F1, I(69), I(70), F2);
  k_fin3<<<G1(NB * 12 * NN)>>>(F2, I(71), I(72), (float*)d_out);
}

// Round 8
// 9348.067 us; speedup vs baseline: 1.4427x; 1.4427x over previous
//
#include <hip/hip_runtime.h>
#include <hip/hip_bf16.h>
#include <math.h>

#define NB 32      // batch
#define NN 500     // nodes
#define NF 32      // channels

__device__ __forceinline__ float sigf(float x) { return 1.0f / (1.0f + __expf(-x)); }

// h[b,c,n,t] = b_start[c] + sum_ci w_start[c,ci]*padded_x[b,ci,n,t]; pad 7 zeros at front (19)
__global__ void k_start(const float* x, const float* w, const float* bias, float* h) {
  int idx = blockIdx.x * 256 + threadIdx.x;
  const int total = NB * NF * NN * 19;
  if (idx >= total) return;
  int t = idx % 19;
  int n = (idx / 19) % NN;
  int c = (idx / (19 * NN)) % NF;
  int b = idx / (19 * NN * NF);
  float v = bias[c];
  if (t >= 7) {
    int tx = t - 7;
    v += w[c * 2 + 0] * x[((size_t)(b * 2 + 0) * NN + n) * 12 + tx];
    v += w[c * 2 + 1] * x[((size_t)(b * 2 + 1) * NN + n) * 12 + tx];
  }
  h[idx] = v;
}

// skip0[b,c,n] = b_sk0[c] + sum_{ci,k>=7} w_sk0[c,ci,k]*x[b,ci,n,k-7]
__global__ void k_skip0(const float* x, const float* w, const float* bias, float* s0) {
  int idx = blockIdx.x * 256 + threadIdx.x;
  const int total = NB * 64 * NN;
  if (idx >= total) return;
  int n = idx % NN;
  int c = (idx / NN) % 64;
  int b = idx / (NN * 64);
  float v = bias[c];
  for (int ci = 0; ci < 2; ci++)
    for (int k = 7; k < 19; k++)
      v += w[(c * 2 + ci) * 19 + k] * x[((size_t)(b * 2 + ci) * NN + n) * 12 + (k - 7)];
  s0[idx] = v;
}

// ---- fused gated-TCN + fc, register-blocked, 8 nodes per block ----
template<int K, int L, int TP, int TCAT, int TO>
__device__ __forceinline__ void gtu_seg(const float* __restrict__ wseg,
                                        const float* __restrict__ bg,
                                        const float* __restrict__ hbase,
                                        const float* __restrict__ fw,
                                        float (&oacc)[TO], int c, int tbase) {
  float y0[L], y1[L];
#pragma unroll
  for (int t = 0; t < L; t++) { y0[t] = 0.f; y1[t] = 0.f; }
#pragma unroll 2
  for (int ci = 0; ci < NF; ci++) {
    float hrow[L + K - 1];
#pragma unroll
    for (int t = 0; t < L + K - 1; t++) hrow[t] = hbase[ci * TP + t];
    float w0[K], w1[K];
#pragma unroll
    for (int j = 0; j < K; j++) {
      w0[j] = wseg[(c * NF + ci) * K + j];
      w1[j] = wseg[((c + 32) * NF + ci) * K + j];
    }
#pragma unroll
    for (int t = 0; t < L; t++)
#pragma unroll
      for (int j = 0; j < K; j++) {
        y0[t] += w0[j] * hrow[t + j];
        y1[t] += w1[j] * hrow[t + j];
      }
  }
  float b0 = bg[c], b1 = bg[c + 32];
#pragma unroll
  for (int t = 0; t < L; t++) {
    float tcv = tanhf(y0[t] + b0) * sigf(y1[t] + b1);
#pragma unroll
    for (int o = 0; o < TO; o++) oacc[o] += tcv * fw[o * TCAT + tbase + t];
  }
}

template<int TI, int TO>
__global__ __launch_bounds__(256) void k_gtufc_t(
    const float* __restrict__ h,
    const float* __restrict__ wg3, const float* __restrict__ bg3,
    const float* __restrict__ wg5, const float* __restrict__ bg5,
    const float* __restrict__ wg7, const float* __restrict__ bg7,
    const float* __restrict__ fw, const float* __restrict__ fb,
    const float* __restrict__ res, float* __restrict__ out) {
  constexpr int TCAT = 3 * TI - 12;
  constexpr int TP = (TI + 3) & ~3;
  constexpr int OFF = TI - TO;
  const int b = blockIdx.y;
  const int n0 = blockIdx.x * 8;
  const int tid = threadIdx.x;
  const int c = tid & 31, nn = tid >> 5;
  const int n = n0 + nn;
  __shared__ float hs[8 * NF * TP];
  for (int l = tid; l < 8 * NF * TP; l += 256) {
    int t = l % TP;
    int ci = (l / TP) % NF;
    int n2 = l / (TP * NF);
    int gn = n0 + n2;
    hs[l] = (t < TI && gn < NN) ? h[((size_t)(b * NF + ci) * NN + gn) * TI + t] : 0.f;
  }
  __syncthreads();
  const float* hbase = hs + nn * NF * TP;
  float oacc[TO];
#pragma unroll
  for (int o = 0; o < TO; o++) oacc[o] = 0.f;
  gtu_seg<3, TI - 2, TP, TCAT, TO>(wg3, bg3, hbase, fw, oacc, c, 0);
  gtu_seg<5, TI - 4, TP, TCAT, TO>(wg5, bg5, hbase, fw, oacc, c, TI - 2);
  gtu_seg<7, TI - 6, TP, TCAT, TO>(wg7, bg7, hbase, fw, oacc, c, 2 * TI - 6);
  if (n < NN) {
    size_t base = (size_t)(b * NF + c) * NN + n;
#pragma unroll
    for (int o = 0; o < TO; o++) {
      float v = fmaxf(hbase[c * TP + OFF + o] + oacc[o] + fb[o], 0.f);
      if (res) v += res[base * TI + OFF + o];
      out[base * TO + o] = v;
    }
  }
}

// ---- skip conv, LDS h staging, weights in registers, K unrolled ----
template<int TI, int K>
__global__ __launch_bounds__(256) void k_skipconv_t(
    const float* __restrict__ h, const float* __restrict__ w,
    const float* __restrict__ bias, const float* __restrict__ prev, int prevT,
    float* __restrict__ out) {
  constexpr int TP = (TI + 3) & ~3;
  const int b = blockIdx.y, n0 = blockIdx.x * 8, tid = threadIdx.x;
  __shared__ float hs[8 * NF * TP];
  for (int l = tid; l < 8 * NF * TP; l += 256) {
    int t = l % TP;
    int ci = (l / TP) % NF;
    int n2 = l / (TP * NF);
    int gn = n0 + n2;
    hs[l] = (t < TI && gn < NN) ? h[((size_t)(b * NF + ci) * NN + gn) * TI + t] : 0.f;
  }
  __syncthreads();
  const int c = tid & 63, ng = tid >> 6;
  float bv = bias[c];
  float o[2][7];
#pragma unroll
  for (int q = 0; q < 2; q++)
#pragma unroll
    for (int t = 0; t < 7; t++) o[q][t] = bv;
  for (int ci = 0; ci < NF; ci++) {
    float wv[K];
#pragma unroll
    for (int j = 0; j < K; j++) wv[j] = w[(c * NF + ci) * K + j];
#pragma unroll
    for (int q = 0; q < 2; q++) {
      const float* hp = hs + ((ng + q * 4) * NF + ci) * TP;
#pragma unroll
      for (int t = 0; t < 7; t++) {
        float s = 0.f;
#pragma unroll
        for (int j = 0; j < K; j++) s += wv[j] * hp[t + j];
        o[q][t] += s;
      }
    }
  }
#pragma unroll
  for (int q = 0; q < 2; q++) {
    int n = n0 + ng + q * 4;
    if (n < NN) {
      size_t base = (size_t)(b * 64 + c) * NN + n;
#pragma unroll
      for (int t = 0; t < 7; t++) {
        float pv = (prevT == 1) ? prev[base] : prev[base * 7 + t];
        out[base * 7 + t] = o[q][t] + pv;
      }
    }
  }
}

// ---- temporal attention ----
__global__ void k_ta_lhs1(const float* h, const float* u1, float* out, int T) {
  int total = NB * T * NF;
  int idx = blockIdx.x * 256 + threadIdx.x;
  if (idx >= total) return;
  int f = idx % NF;
  int t = (idx / NF) % T;
  int b = idx / (NF * T);
  const float* hp = h + ((size_t)(b * NF + f) * NN) * T + t;
  float acc = 0.f;
  for (int n = 0; n < NN; n++) acc += hp[(size_t)n * T] * u1[n];
  out[(b * T + t) * NF + f] = acc;
}
__global__ void k_ta_lhs(const float* l1, const float* u2, float* out, int T) {
  int total = NB * T * NN;
  int idx = blockIdx.x * 256 + threadIdx.x;
  if (idx >= total) return;
  int n = idx % NN;
  int t = (idx / NN) % T;
  int b = idx / (NN * T);
  float acc = 0.f;
  for (int f = 0; f < NF; f++) acc += l1[(b * T + t) * NF + f] * u2[f * NN + n];
  out[idx] = acc;  // (b,t,n)
}
__global__ void k_ta_rhs(const float* h, const float* u3, float* out, int T) {
  int total = NB * NN * T;
  int idx = blockIdx.x * 256 + threadIdx.x;
  if (idx >= total) return;
  int t = idx % T;
  int n = (idx / T) % NN;
  int b = idx / (T * NN);
  float acc = 0.f;
  for (int f = 0; f < NF; f++) acc += u3[f] * h[((size_t)(b * NF + f) * NN + n) * T + t];
  out[idx] = acc;  // (b,n,t)
}
// fused: e0 = sigf(lhs@rhs + be); e1 = ve@e0; e = softmax over t. one block per b.
__global__ __launch_bounds__(256) void k_ta_att(const float* __restrict__ lhs,
                                                const float* __restrict__ rhs,
                                                const float* __restrict__ be,
                                                const float* __restrict__ ve,
                                                float* __restrict__ e, int T) {
  int b = blockIdx.x, tid = threadIdx.x;
  __shared__ float e0[19 * 19];
  __shared__ float e1[19 * 19];
  int TT = T * T;
  for (int l = tid; l < TT; l += 256) {
    int t = l / T, m = l % T;
    float acc = 0.f;
    const float* lp = lhs + ((size_t)b * T + t) * NN;
    const float* rp = rhs + (size_t)b * NN * T + m;
    for (int n = 0; n < NN; n++) acc += lp[n] * rp[(size_t)n * T];
    e0[l] = sigf(acc + be[l]);
  }
  __syncthreads();
  for (int l = tid; l < TT; l += 256) {
    int t = l / T, m = l % T;
    float acc = 0.f;
    for (int j = 0; j < T; j++) acc += ve[t * T + j] * e0[j * T + m];
    e1[l] = acc;
  }
  __syncthreads();
  if (tid < T) {
    int m = tid;
    float mx = -1e30f;
    for (int t = 0; t < T; t++) mx = fmaxf(mx, e1[t * T + m]);
    float s = 0.f;
    for (int t = 0; t < T; t++) s += __expf(e1[t * T + m] - mx);
    float inv = 1.f / s;
    for (int t = 0; t < T; t++)
      e[((size_t)b * T + t) * T + m] = __expf(e1[t * T + m] - mx) * inv;
  }
}
// xt[b,f,n,t] = sum_j e[b,t,j] * h[b,f,n,j]
__global__ void k_xtat(const float* e, const float* h, float* xt, int T) {
  int total = NB * NF * NN * T;
  int idx = blockIdx.x * 256 + threadIdx.x;
  if (idx >= total) return;
  int t = idx % T;
  int n = (idx / T) % NN;
  int f = (idx / (T * NN)) % NF;
  int b = idx / (T * NN * NF);
  const float* hp = h + ((size_t)(b * NF + f) * NN + n) * T;
  float acc = 0.f;
  for (int j = 0; j < T; j++) acc += e[(b * T + t) * T + j] * hp[j];
  xt[idx] = acc;
}

// ---- spatial attention ----
__global__ void k_sa_lhs1(const float* xt, const float* w1, float* out, int T) {
  int total = NB * NN * NF;
  int idx = blockIdx.x * 256 + threadIdx.x;
  if (idx >= total) return;
  int f = idx % NF;
  int n = (idx / NF) % NN;
  int b = idx / (NF * NN);
  const float* xp = xt + ((size_t)(b * NF + f) * NN + n) * T;
  float acc = 0.f;
  for (int t = 0; t < T; t++) acc += xp[t] * w1[t];
  out[(b * NN + n) * NF + f] = acc;
}
__global__ void k_sa_lhs(const float* l1, const float* w2, float* out, int T) {
  int total = NB * NN * T;
  int idx = blockIdx.x * 256 + threadIdx.x;
  if (idx >= total) return;
  int t = idx % T;
  int n = (idx / T) % NN;
  int b = idx / (T * NN);
  float acc = 0.f;
  for (int f = 0; f < NF; f++) acc += l1[(b * NN + n) * NF + f] * w2[f * T + t];
  out[idx] = acc;  // (b,n,t)
}
__global__ void k_sa_rhs(const float* xt, const float* w3, float* out, int T) {
  int total = NB * T * NN;
  int idx = blockIdx.x * 256 + threadIdx.x;
  if (idx >= total) return;
  int n = idx % NN;
  int t = (idx / NN) % T;
  int b = idx / (NN * T);
  float acc = 0.f;
  for (int f = 0; f < NF; f++) acc += w3[f] * xt[((size_t)(b * NF + f) * NN + n) * T + t];
  out[idx] = acc;  // (b,t,n)
}
__global__ void k_sa_prod(const float* lhs, const float* rhs, const float* bs, float* s0, int T) {
  int total = NB * NN * NN;
  int idx = blockIdx.x * 256 + threadIdx.x;
  if (idx >= total) return;
  int m = idx % NN;
  int n = (idx / NN) % NN;
  int b = idx / (NN * NN);
  float acc = 0.f;
  for (int t = 0; t < T; t++)
    acc += lhs[((size_t)b * NN + n) * T + t] * rhs[((size_t)b * T + t) * NN + m];
  s0[idx] = sigf(acc + bs[(size_t)n * NN + m]);
}

// 500x500 transpose (for vs)
__global__ __launch_bounds__(256) void k_transpose(const float* in, float* outT) {
  __shared__ float tile[32][33];
  int x0 = blockIdx.x * 32, y0 = blockIdx.y * 32;
  int tx = threadIdx.x & 31, ty8 = threadIdx.x >> 5;
  for (int yy = ty8; yy < 32; yy += 8) {
    int x = x0 + tx, y = y0 + yy;
    tile[yy][tx] = (x < NN && y < NN) ? in[(size_t)y * NN + x] : 0.f;
  }
  __syncthreads();
  for (int yy = ty8; yy < 32; yy += 8) {
    int x = y0 + tx, y = x0 + yy;
    if (x < NN && y < NN) outT[(size_t)y * NN + x] = tile[tx][yy];
  }
}

// s1T[b,c,r] = (vs @ s0[b])[r,c] — A from vsT (coalesced), b128 LDS reads both sides
__global__ __launch_bounds__(256) void k_gemm_vs(const float* __restrict__ vsT,
                                                 const float* __restrict__ s0,
                                                 float* __restrict__ s1t) {
  __shared__ float As[16][68];
  __shared__ float Bs[16][68];
  int b = blockIdx.z;
  int row0 = blockIdx.y * 64, col0 = blockIdx.x * 64;
  int tx = threadIdx.x, ty = threadIdx.y;
  int tid = ty * 16 + tx;
  float acc[4][4] = {};
  const float* S0 = s0 + (size_t)b * NN * NN;
  for (int k0 = 0; k0 < NN; k0 += 16) {
    for (int l = tid; l < 1024; l += 256) {
      int kk = l >> 6, r = l & 63;
      int gi = row0 + r, gk = k0 + kk;
      As[kk][r] = (gi < NN && gk < NN) ? vsT[(size_t)gk * NN + gi] : 0.f;
    }
    for (int l = tid; l < 1024; l += 256) {
      int kk = l >> 6, cc = l & 63;
      int gk = k0 + kk, gc = col0 + cc;
      Bs[kk][cc] = (gk < NN && gc < NN) ? S0[(size_t)gk * NN + gc] : 0.f;
    }
    __syncthreads();
    for (int kk = 0; kk < 16; kk++) {
      float4 a4 = *(const float4*)&As[kk][ty * 4];
      float4 b4 = *(const float4*)&Bs[kk][tx * 4];
      float a[4] = {a4.x, a4.y, a4.z, a4.w};
      float bb[4] = {b4.x, b4.y, b4.z, b4.w};
#pragma unroll
      for (int i = 0; i < 4; i++)
#pragma unroll
        for (int j = 0; j < 4; j++) acc[i][j] += a[i] * bb[j];
    }
    __syncthreads();
  }
  float* S1 = s1t + (size_t)b * NN * NN;
  for (int j = 0; j < 4; j++)
    for (int i = 0; i < 4; i++) {
      int gi = row0 + ty * 4 + i, gc = col0 + tx * 4 + j;
      if (gi < NN && gc < NN) S1[(size_t)gc * NN + gi] = acc[i][j];  // transposed
    }
}
// softmax over r (contiguous): st[b,c,r] = softmax_r(s1t[b,c,r]); block per (c,b)
__global__ __launch_bounds__(256) void k_sa_smax_row(const float* s1t, float* st) {
  int c = blockIdx.x, b = blockIdx.y;
  int tid = threadIdx.x;
  const float* S = s1t + ((size_t)b * NN + c) * NN;
  float* O = st + ((size_t)b * NN + c) * NN;
  __shared__ float red[256];
  float mx = -1e30f;
  for (int i = tid; i < NN; i += 256) mx = fmaxf(mx, S[i]);
  red[tid] = mx;
  __syncthreads();
  for (int s = 128; s > 0; s >>= 1) {
    if (tid < s) red[tid] = fmaxf(red[tid], red[tid + s]);
    __syncthreads();
  }
  mx = red[0];
  __syncthreads();
  float sum = 0.f;
  for (int i = tid; i < NN; i += 256) sum += __expf(S[i] - mx);
  red[tid] = sum;
  __syncthreads();
  for (int s = 128; s > 0; s >>= 1) {
    if (tid < s) red[tid] += red[tid + s];
    __syncthreads();
  }
  float inv = 1.f / red[0];
  for (int i = tid; i < NN; i += 256) O[i] = __expf(S[i] - mx) * inv;
}

// chebT[k,n,m] = cheb[k,m,n]
__global__ void k_chebT(const float* cheb, float* ct) {
  int total = 3 * NN * NN;
  int idx = blockIdx.x * 256 + threadIdx.x;
  if (idx >= total) return;
  int m = idx % NN;
  int n = (idx / NN) % NN;
  int k = idx / (NN * NN);
  ct[idx] = cheb[((size_t)k * NN + m) * NN + n];
}

// hT[b][m][f*T+t] = h[b][f][m][t]  (coalesced writes)
__global__ void k_htrans(const float* __restrict__ h, float* __restrict__ hT, int T) {
  int NFT = NF * T;
  int total = NB * NN * NFT;
  int idx = blockIdx.x * 256 + threadIdx.x;
  if (idx >= total) return;
  int ft = idx % NFT;
  int m = (idx / NFT) % NN;
  int b = idx / (NFT * NN);
  int f = ft / T, t = ft % T;
  hT[idx] = h[((size_t)(b * NF + f) * NN + m) * T + t];
}

// ---- chebyshev conv v3: coalesced hT loads, 2 nodes/block, k=0 via identity ----
// out[b,f2,n,t] = relu( sum_k sum_f theta[k,f,f2] * Y_k[n,f,t] )
//   Y_0[n,f,t] = st[b,n,n] * h[b,f,n,t]   (cheb[0] == I, exact)
//   Y_k[n,f,t] = sum_m (ct[k,n,m]*st[b,n,m]) * h[b,f,m,t], k=1,2
template<int T>
__global__ __launch_bounds__(256) void k_cheb3(const float* __restrict__ hT,
                                               const float* __restrict__ st,
                                               const float* __restrict__ ct,
                                               const float* __restrict__ theta,
                                               float* __restrict__ out) {
  constexpr int NFT = NF * T;
  constexpr int R = (NFT + 255) / 256;
  const int b = blockIdx.y;
  const int n0 = blockIdx.x * 2;
  const int tid = threadIdx.x;
  __shared__ float w[2][2][NN];      // [k-1][nn][m]
  __shared__ float accS[6][NFT];     // [k*2+nn][ft]
  __shared__ float sdiag[2];
  for (int m = tid; m < NN; m += 256) {
#pragma unroll
    for (int nn = 0; nn < 2; nn++) {
      int n = n0 + nn;
      float sv = st[((size_t)b * NN + n) * NN + m];
      w[0][nn][m] = ct[((size_t)1 * NN + n) * NN + m] * sv;
      w[1][nn][m] = ct[((size_t)2 * NN + n) * NN + m] * sv;
    }
  }
  if (tid < 2) {
    int n = n0 + tid;
    sdiag[tid] = st[((size_t)b * NN + n) * NN + n];
  }
  __syncthreads();
  float acc[2][2][R];  // [k-1][nn][r]
#pragma unroll
  for (int k = 0; k < 2; k++)
#pragma unroll
    for (int nn = 0; nn < 2; nn++)
#pragma unroll
      for (int r = 0; r < R; r++) acc[k][nn][r] = 0.f;
  const float* hTb = hT + (size_t)b * NN * NFT;
#pragma unroll 4
  for (int m = 0; m < NN; m++) {
    float w00 = w[0][0][m], w01 = w[0][1][m];
    float w10 = w[1][0][m], w11 = w[1][1][m];
#pragma unroll
    for (int r = 0; r < R; r++) {
      int ft = tid + r * 256;
      if (ft < NFT) {
        float x = hTb[(size_t)m * NFT + ft];
        acc[0][0][r] += w00 * x;
        acc[0][1][r] += w01 * x;
        acc[1][0][r] += w10 * x;
        acc[1][1][r] += w11 * x;
      }
    }
  }
  // stage Y_k into LDS: Y_0 from diagonal, Y_1/Y_2 from acc
#pragma unroll
  for (int r = 0; r < R; r++) {
    int ft = tid + r * 256;
    if (ft < NFT) {
#pragma unroll
      for (int nn = 0; nn < 2; nn++) {
        accS[0 * 2 + nn][ft] = sdiag[nn] * hTb[(size_t)(n0 + nn) * NFT + ft];
        accS[1 * 2 + nn][ft] = acc[0][nn][r];
        accS[2 * 2 + nn][ft] = acc[1][nn][r];
      }
    }
  }
  __syncthreads();
  for (int it = tid; it < 2 * NFT; it += 256) {
    int nn = it / NFT;
    int f2t = it % NFT;
    int f2 = f2t / T, t = f2t % T;
    float o = 0.f;
#pragma unroll
    for (int k = 0; k < 3; k++)
      for (int f = 0; f < NF; f++)
        o += accS[k * 2 + nn][f * T + t] * theta[(k * NF + f) * NF + f2];
    out[((size_t)(b * NF + f2) * NN + (n0 + nn)) * T + t] = fmaxf(o, 0.f);
  }
}

// ---- layer norm over (C,N,T) per sample ----
__global__ void k_zero(float* p, int n) {
  int i = blockIdx.x * 256 + threadIdx.x;
  if (i < n) p[i] = 0.f;
}
__global__ void k_ln_part(const float* x, float* acc, int M) {
  int b = blockIdx.y;
  const float* xp = x + (size_t)b * M;
  float s1 = 0.f, s2 = 0.f;
  for (int i = blockIdx.x * blockDim.x + threadIdx.x; i < M; i += gridDim.x * blockDim.x) {
    float v = xp[i]; s1 += v; s2 += v * v;
  }
  __shared__ float r1[256], r2[256];
  int tid = threadIdx.x;
  r1[tid] = s1; r2[tid] = s2;
  __syncthreads();
  for (int s = 128; s > 0; s >>= 1) {
    if (tid < s) { r1[tid] += r1[tid + s]; r2[tid] += r2[tid + s]; }
    __syncthreads();
  }
  if (tid == 0) { atomicAdd(&acc[b * 2], r1[0]); atomicAdd(&acc[b * 2 + 1], r2[0]); }
}
__global__ void k_ln_norm(const float* x, const float* acc, const float* wn, const float* bn,
                          float* out, int M) {
  int total = NB * M;
  int idx = blockIdx.x * 256 + threadIdx.x;
  if (idx >= total) return;
  int b = idx / M;
  int i = idx % M;
  float mean = acc[b * 2] / M;
  float var = acc[b * 2 + 1] / M - mean * mean;
  float y = (x[idx] - mean) * rsqrtf(var + 1e-5f);
  out[idx] = y * wn[i] + bn[i];
}

// ---- final head ----
__global__ void k_fin1(const float* h, const float* w, const float* bias, const float* skip,
                       float* out) {
  int total = NB * 64 * NN;
  int idx = blockIdx.x * 256 + threadIdx.x;
  if (idx >= total) return;
  int n = idx % NN;
  int c = (idx / NN) % 64;
  int b = idx / (NN * 64);
  float v = bias[c];
  for (int ci = 0; ci < 32; ci++) v += w[c * 32 + ci] * h[(b * NF + ci) * NN + n];
  v += skip[((size_t)(b * 64 + c) * NN + n) * 7 + 6];
  out[idx] = fmaxf(v, 0.f);
}
__global__ void k_fin2(const float* in, const float* w, const float* bias, float* out) {
  int total = NB * 128 * NN;
  int idx = blockIdx.x * 256 + threadIdx.x;
  if (idx >= total) return;
  int n = idx % NN;
  int c = (idx / NN) % 128;
  int b = idx / (NN * 128);
  float v = bias[c];
  for (int ci = 0; ci < 64; ci++) v += w[c * 64 + ci] * in[(b * 64 + ci) * NN + n];
  out[idx] = fmaxf(v, 0.f);
}
__global__ void k_fin3(const float* in, const float* w, const float* bias, float* out) {
  int total = NB * 12 * NN;
  int idx = blockIdx.x * 256 + threadIdx.x;
  if (idx >= total) return;
  int n = idx % NN;
  int c = (idx / NN) % 12;
  int b = idx / (NN * 12);
  float v = bias[c];
  for (int ci = 0; ci < 128; ci++) v += w[c * 128 + ci] * in[(b * 128 + ci) * NN + n];
  out[idx] = v;
}

#define G1(tot) dim3((unsigned)(((tot) + 255) / 256)), dim3(256), 0, stream

extern "C" void kernel_launch(void* const* d_in, const int* in_sizes, int n_in,
                              void* d_out, int out_size, void* d_ws, size_t ws_size,
                              hipStream_t stream) {
  (void)in_sizes; (void)n_in; (void)out_size; (void)ws_size;
  auto I = [&](int i) { return (const float*)d_in[i]; };
  float* W = (float*)d_ws;
  size_t off = 0;
  auto alloc = [&](size_t nel) { float* p = W + off; off += nel; return p; };

  float* bufA  = alloc(9728000);   // h / residual [B,32,N,19max]
  float* bufB  = alloc(9728000);   // h after fc1; later cheb output
  float* bufC  = alloc(9728000);   // x_tat -> s1T -> hT ; later gtufc#2 output
  float* bufSK = alloc(7168000);   // skip [B,64,N,7]
  float* skip0 = alloc(1024000);   // skip [B,64,N,1]
  float* P1    = alloc(8000000);   // s0 / st; reused for F1/F2 at end
  float* CT    = alloc(750000);    // chebT
  float* VST   = alloc(250000);    // vs transposed (per layer)
  float* TL1   = alloc(19456);
  float* TLH   = alloc(304000);
  float* TRH   = alloc(304000);
  float* TE    = alloc(11552);
  float* SL1   = alloc(512000);
  float* SLH   = alloc(304000);
  float* SRH   = alloc(304000);
  float* ACC   = alloc(64);
  float* P2 = bufC;                // [B,500,500] s1T lives in bufC until smax consumes it
  float* HT = bufC;                // hT[b][m][ft] lives in bufC after smax
  float* F1 = P1;                  // [B,64,N] final head, after P1 (st) is dead
  float* F2 = P1 + 1024000;        // [B,128,N]

  k_start<<<G1(NB * NF * NN * 19)>>>(I(0), I(1), I(2), bufA);
  k_skip0<<<G1(NB * 64 * NN)>>>(I(0), I(3), I(4), skip0);
  k_chebT<<<G1(3 * NN * NN)>>>(I(59), CT);

  dim3 ggt((NN + 7) / 8, NB), bgt(256);
  auto gtufc = [&](int Ti, int To, const float* hin, const float* fw, const float* fb,
                   const float* res, float* o) {
    if (Ti == 19 && To == 19)
      k_gtufc_t<19, 19><<<ggt, bgt, 0, stream>>>(hin, I(5), I(6), I(7), I(8), I(9), I(10), fw, fb, res, o);
    else if (Ti == 19 && To == 13)
      k_gtufc_t<19, 13><<<ggt, bgt, 0, stream>>>(hin, I(5), I(6), I(7), I(8), I(9), I(10), fw, fb, res, o);
    else if (Ti == 13 && To == 13)
      k_gtufc_t<13, 13><<<ggt, bgt, 0, stream>>>(hin, I(5), I(6), I(7), I(8), I(9), I(10), fw, fb, res, o);
    else if (Ti == 13 && To == 7)
      k_gtufc_t<13, 7><<<ggt, bgt, 0, stream>>>(hin, I(5), I(6), I(7), I(8), I(9), I(10), fw, fb, res, o);
    else if (Ti == 7 && To == 7)
      k_gtufc_t<7, 7><<<ggt, bgt, 0, stream>>>(hin, I(5), I(6), I(7), I(8), I(9), I(10), fw, fb, res, o);
    else
      k_gtufc_t<7, 1><<<ggt, bgt, 0, stream>>>(hin, I(5), I(6), I(7), I(8), I(9), I(10), fw, fb, res, o);
  };

  const int Tin[3] = {19, 13, 7}, Tout[3] = {13, 7, 1};
  for (int i = 0; i < 3; i++) {
    int Ti = Tin[i], To = Tout[i];
    // gated TCN + fc1 + relu-add : bufA -> bufB
    gtufc(Ti, Ti, bufA, I(11 + 2 * i), I(12 + 2 * i), nullptr, bufB);
    // skip conv
    if (i == 0)
      k_skipconv_t<19, 13><<<ggt, bgt, 0, stream>>>(bufB, I(23), I(24), skip0, 1, bufSK);
    else if (i == 1)
      k_skipconv_t<13, 7><<<ggt, bgt, 0, stream>>>(bufB, I(25), I(26), bufSK, 7, bufSK);
    else
      k_skipconv_t<7, 1><<<ggt, bgt, 0, stream>>>(bufB, I(27), I(28), bufSK, 7, bufSK);
    // temporal attention
    int ba = 29 + i * 10;
    k_ta_lhs1<<<G1(NB * Ti * NF)>>>(bufB, I(ba + 0), TL1, Ti);
    k_ta_lhs<<<G1(NB * Ti * NN)>>>(TL1, I(ba + 1), TLH, Ti);
    k_ta_rhs<<<G1(NB * NN * Ti)>>>(bufB, I(ba + 2), TRH, Ti);
    k_ta_att<<<dim3(NB), dim3(256), 0, stream>>>(TLH, TRH, I(ba + 3), I(ba + 4), TE, Ti);
    k_xtat<<<G1(NB * NF * NN * Ti)>>>(TE, bufB, bufC, Ti);  // x_tat into bufC
    // spatial attention
    k_sa_lhs1<<<G1(NB * NN * NF)>>>(bufC, I(ba + 5), SL1, Ti);
    k_sa_lhs<<<G1(NB * NN * Ti)>>>(SL1, I(ba + 6), SLH, Ti);
    k_sa_rhs<<<G1(NB * Ti * NN)>>>(bufC, I(ba + 7), SRH, Ti);
    k_sa_prod<<<G1(NB * NN * NN)>>>(SLH, SRH, I(ba + 8), P1, Ti);  // x_tat consumed
    k_transpose<<<dim3(16, 16), dim3(256), 0, stream>>>(I(ba + 9), VST);
    {
      dim3 gg(8, 8, NB), bb(16, 16);
      k_gemm_vs<<<gg, bb, 0, stream>>>(VST, P1, P2);  // s1T into bufC
    }
    k_sa_smax_row<<<dim3(NN, NB), dim3(256), 0, stream>>>(P2, P1);  // st into P1; bufC free
    // transpose h for cheb: bufB -> HT (bufC)
    k_htrans<<<G1(NB * NN * NF * Ti)>>>(bufB, HT, Ti);
    // chebyshev graph conv: HT + st -> bufB (h dead)
    {
      dim3 gc(NN / 2, NB), bc(256);
      if (Ti == 19)      k_cheb3<19><<<gc, bc, 0, stream>>>(HT, P1, CT, I(60), bufB);
      else if (Ti == 13) k_cheb3<13><<<gc, bc, 0, stream>>>(HT, P1, CT, I(60), bufB);
      else               k_cheb3<7><<<gc, bc, 0, stream>>>(HT, P1, CT, I(60), bufB);
    }
    // second gated TCN + fc2 + relu-add + residual : bufB (+bufA) -> bufC
    gtufc(Ti, To, bufB, I(17 + 2 * i), I(18 + 2 * i), bufA, bufC);
    // layer norm: bufC -> bufA
    int M = NF * NN * To;
    k_zero<<<dim3(1), dim3(256), 0, stream>>>(ACC, 64);
    k_ln_part<<<dim3(16, NB), dim3(256), 0, stream>>>(bufC, ACC, M);
    k_ln_norm<<<G1(NB * M)>>>(bufC, ACC, I(61 + 2 * i), I(62 + 2 * i), bufA, M);
  }
  // final head
  k_fin1<<<G1(NB * 64 * NN)>>>(bufA, I(67), I(68), bufSK, F1);
  k_fin2<<<G1(NB * 128 * NN)>>>(F1, I(69), I(70), F2);
  k_fin3<<<G1(NB * 12 * NN)>>>(F2, I(71), I(72), (float*)d_out);
}

// Round 9
// 6288.025 us; speedup vs baseline: 2.1447x; 1.4866x over previous
//
#include <hip/hip_runtime.h>
#include <hip/hip_bf16.h>
#include <math.h>

#define NB 32      // batch
#define NN 500     // nodes
#define NF 32      // channels

__device__ __forceinline__ float sigf(float x) { return 1.0f / (1.0f + __expf(-x)); }

// h[b,c,n,t] = b_start[c] + sum_ci w_start[c,ci]*padded_x[b,ci,n,t]; pad 7 zeros at front (19)
__global__ void k_start(const float* x, const float* w, const float* bias, float* h) {
  int idx = blockIdx.x * 256 + threadIdx.x;
  const int total = NB * NF * NN * 19;
  if (idx >= total) return;
  int t = idx % 19;
  int n = (idx / 19) % NN;
  int c = (idx / (19 * NN)) % NF;
  int b = idx / (19 * NN * NF);
  float v = bias[c];
  if (t >= 7) {
    int tx = t - 7;
    v += w[c * 2 + 0] * x[((size_t)(b * 2 + 0) * NN + n) * 12 + tx];
    v += w[c * 2 + 1] * x[((size_t)(b * 2 + 1) * NN + n) * 12 + tx];
  }
  h[idx] = v;
}

// skip0[b,c,n] = b_sk0[c] + sum_{ci,k>=7} w_sk0[c,ci,k]*x[b,ci,n,k-7]
__global__ void k_skip0(const float* x, const float* w, const float* bias, float* s0) {
  int idx = blockIdx.x * 256 + threadIdx.x;
  const int total = NB * 64 * NN;
  if (idx >= total) return;
  int n = idx % NN;
  int c = (idx / NN) % 64;
  int b = idx / (NN * 64);
  float v = bias[c];
  for (int ci = 0; ci < 2; ci++)
    for (int k = 7; k < 19; k++)
      v += w[(c * 2 + ci) * 19 + k] * x[((size_t)(b * 2 + ci) * NN + n) * 12 + (k - 7)];
  s0[idx] = v;
}

// ---- fused gated-TCN + fc, register-blocked, 8 nodes per block ----
template<int K, int L, int TP, int TCAT, int TO>
__device__ __forceinline__ void gtu_seg(const float* __restrict__ wseg,
                                        const float* __restrict__ bg,
                                        const float* __restrict__ hbase,
                                        const float* __restrict__ fw,
                                        float (&oacc)[TO], int c, int tbase) {
  float y0[L], y1[L];
#pragma unroll
  for (int t = 0; t < L; t++) { y0[t] = 0.f; y1[t] = 0.f; }
#pragma unroll 2
  for (int ci = 0; ci < NF; ci++) {
    float hrow[L + K - 1];
#pragma unroll
    for (int t = 0; t < L + K - 1; t++) hrow[t] = hbase[ci * TP + t];
    float w0[K], w1[K];
#pragma unroll
    for (int j = 0; j < K; j++) {
      w0[j] = wseg[(c * NF + ci) * K + j];
      w1[j] = wseg[((c + 32) * NF + ci) * K + j];
    }
#pragma unroll
    for (int t = 0; t < L; t++)
#pragma unroll
      for (int j = 0; j < K; j++) {
        y0[t] += w0[j] * hrow[t + j];
        y1[t] += w1[j] * hrow[t + j];
      }
  }
  float b0 = bg[c], b1 = bg[c + 32];
#pragma unroll
  for (int t = 0; t < L; t++) {
    float tcv = tanhf(y0[t] + b0) * sigf(y1[t] + b1);
#pragma unroll
    for (int o = 0; o < TO; o++) oacc[o] += tcv * fw[o * TCAT + tbase + t];
  }
}

template<int TI, int TO>
__global__ __launch_bounds__(256) void k_gtufc_t(
    const float* __restrict__ h,
    const float* __restrict__ wg3, const float* __restrict__ bg3,
    const float* __restrict__ wg5, const float* __restrict__ bg5,
    const float* __restrict__ wg7, const float* __restrict__ bg7,
    const float* __restrict__ fw, const float* __restrict__ fb,
    const float* __restrict__ res, float* __restrict__ out) {
  constexpr int TCAT = 3 * TI - 12;
  constexpr int TP = (TI + 3) & ~3;
  constexpr int OFF = TI - TO;
  const int b = blockIdx.y;
  const int n0 = blockIdx.x * 8;
  const int tid = threadIdx.x;
  const int c = tid & 31, nn = tid >> 5;
  const int n = n0 + nn;
  __shared__ float hs[8 * NF * TP];
  for (int l = tid; l < 8 * NF * TP; l += 256) {
    int t = l % TP;
    int ci = (l / TP) % NF;
    int n2 = l / (TP * NF);
    int gn = n0 + n2;
    hs[l] = (t < TI && gn < NN) ? h[((size_t)(b * NF + ci) * NN + gn) * TI + t] : 0.f;
  }
  __syncthreads();
  const float* hbase = hs + nn * NF * TP;
  float oacc[TO];
#pragma unroll
  for (int o = 0; o < TO; o++) oacc[o] = 0.f;
  gtu_seg<3, TI - 2, TP, TCAT, TO>(wg3, bg3, hbase, fw, oacc, c, 0);
  gtu_seg<5, TI - 4, TP, TCAT, TO>(wg5, bg5, hbase, fw, oacc, c, TI - 2);
  gtu_seg<7, TI - 6, TP, TCAT, TO>(wg7, bg7, hbase, fw, oacc, c, 2 * TI - 6);
  if (n < NN) {
    size_t base = (size_t)(b * NF + c) * NN + n;
#pragma unroll
    for (int o = 0; o < TO; o++) {
      float v = fmaxf(hbase[c * TP + OFF + o] + oacc[o] + fb[o], 0.f);
      if (res) v += res[base * TI + OFF + o];
      out[base * TO + o] = v;
    }
  }
}

// ---- skip conv, LDS h staging, weights in registers, K unrolled ----
template<int TI, int K>
__global__ __launch_bounds__(256) void k_skipconv_t(
    const float* __restrict__ h, const float* __restrict__ w,
    const float* __restrict__ bias, const float* __restrict__ prev, int prevT,
    float* __restrict__ out) {
  constexpr int TP = (TI + 3) & ~3;
  const int b = blockIdx.y, n0 = blockIdx.x * 8, tid = threadIdx.x;
  __shared__ float hs[8 * NF * TP];
  for (int l = tid; l < 8 * NF * TP; l += 256) {
    int t = l % TP;
    int ci = (l / TP) % NF;
    int n2 = l / (TP * NF);
    int gn = n0 + n2;
    hs[l] = (t < TI && gn < NN) ? h[((size_t)(b * NF + ci) * NN + gn) * TI + t] : 0.f;
  }
  __syncthreads();
  const int c = tid & 63, ng = tid >> 6;
  float bv = bias[c];
  float o[2][7];
#pragma unroll
  for (int q = 0; q < 2; q++)
#pragma unroll
    for (int t = 0; t < 7; t++) o[q][t] = bv;
  for (int ci = 0; ci < NF; ci++) {
    float wv[K];
#pragma unroll
    for (int j = 0; j < K; j++) wv[j] = w[(c * NF + ci) * K + j];
#pragma unroll
    for (int q = 0; q < 2; q++) {
      const float* hp = hs + ((ng + q * 4) * NF + ci) * TP;
#pragma unroll
      for (int t = 0; t < 7; t++) {
        float s = 0.f;
#pragma unroll
        for (int j = 0; j < K; j++) s += wv[j] * hp[t + j];
        o[q][t] += s;
      }
    }
  }
#pragma unroll
  for (int q = 0; q < 2; q++) {
    int n = n0 + ng + q * 4;
    if (n < NN) {
      size_t base = (size_t)(b * 64 + c) * NN + n;
#pragma unroll
      for (int t = 0; t < 7; t++) {
        float pv = (prevT == 1) ? prev[base] : prev[base * 7 + t];
        out[base * 7 + t] = o[q][t] + pv;
      }
    }
  }
}

// ---- temporal attention ----
__global__ void k_ta_lhs1(const float* h, const float* u1, float* out, int T) {
  int total = NB * T * NF;
  int idx = blockIdx.x * 256 + threadIdx.x;
  if (idx >= total) return;
  int f = idx % NF;
  int t = (idx / NF) % T;
  int b = idx / (NF * T);
  const float* hp = h + ((size_t)(b * NF + f) * NN) * T + t;
  float acc = 0.f;
  for (int n = 0; n < NN; n++) acc += hp[(size_t)n * T] * u1[n];
  out[(b * T + t) * NF + f] = acc;
}
__global__ void k_ta_lhs(const float* l1, const float* u2, float* out, int T) {
  int total = NB * T * NN;
  int idx = blockIdx.x * 256 + threadIdx.x;
  if (idx >= total) return;
  int n = idx % NN;
  int t = (idx / NN) % T;
  int b = idx / (NN * T);
  float acc = 0.f;
  for (int f = 0; f < NF; f++) acc += l1[(b * T + t) * NF + f] * u2[f * NN + n];
  out[idx] = acc;  // (b,t,n)
}
__global__ void k_ta_rhs(const float* h, const float* u3, float* out, int T) {
  int total = NB * NN * T;
  int idx = blockIdx.x * 256 + threadIdx.x;
  if (idx >= total) return;
  int t = idx % T;
  int n = (idx / T) % NN;
  int b = idx / (T * NN);
  float acc = 0.f;
  for (int f = 0; f < NF; f++) acc += u3[f] * h[((size_t)(b * NF + f) * NN + n) * T + t];
  out[idx] = acc;  // (b,n,t)
}
// fused: e0 = sigf(lhs@rhs + be); e1 = ve@e0; e = softmax over t. one block per b.
__global__ __launch_bounds__(256) void k_ta_att(const float* __restrict__ lhs,
                                                const float* __restrict__ rhs,
                                                const float* __restrict__ be,
                                                const float* __restrict__ ve,
                                                float* __restrict__ e, int T) {
  int b = blockIdx.x, tid = threadIdx.x;
  __shared__ float e0[19 * 19];
  __shared__ float e1[19 * 19];
  int TT = T * T;
  for (int l = tid; l < TT; l += 256) {
    int t = l / T, m = l % T;
    float acc = 0.f;
    const float* lp = lhs + ((size_t)b * T + t) * NN;
    const float* rp = rhs + (size_t)b * NN * T + m;
    for (int n = 0; n < NN; n++) acc += lp[n] * rp[(size_t)n * T];
    e0[l] = sigf(acc + be[l]);
  }
  __syncthreads();
  for (int l = tid; l < TT; l += 256) {
    int t = l / T, m = l % T;
    float acc = 0.f;
    for (int j = 0; j < T; j++) acc += ve[t * T + j] * e0[j * T + m];
    e1[l] = acc;
  }
  __syncthreads();
  if (tid < T) {
    int m = tid;
    float mx = -1e30f;
    for (int t = 0; t < T; t++) mx = fmaxf(mx, e1[t * T + m]);
    float s = 0.f;
    for (int t = 0; t < T; t++) s += __expf(e1[t * T + m] - mx);
    float inv = 1.f / s;
    for (int t = 0; t < T; t++)
      e[((size_t)b * T + t) * T + m] = __expf(e1[t * T + m] - mx) * inv;
  }
}
// xt[b,f,n,t] = sum_j e[b,t,j] * h[b,f,n,j]
__global__ void k_xtat(const float* e, const float* h, float* xt, int T) {
  int total = NB * NF * NN * T;
  int idx = blockIdx.x * 256 + threadIdx.x;
  if (idx >= total) return;
  int t = idx % T;
  int n = (idx / T) % NN;
  int f = (idx / (T * NN)) % NF;
  int b = idx / (T * NN * NF);
  const float* hp = h + ((size_t)(b * NF + f) * NN + n) * T;
  float acc = 0.f;
  for (int j = 0; j < T; j++) acc += e[(b * T + t) * T + j] * hp[j];
  xt[idx] = acc;
}

// ---- spatial attention ----
__global__ void k_sa_lhs1(const float* xt, const float* w1, float* out, int T) {
  int total = NB * NN * NF;
  int idx = blockIdx.x * 256 + threadIdx.x;
  if (idx >= total) return;
  int f = idx % NF;
  int n = (idx / NF) % NN;
  int b = idx / (NF * NN);
  const float* xp = xt + ((size_t)(b * NF + f) * NN + n) * T;
  float acc = 0.f;
  for (int t = 0; t < T; t++) acc += xp[t] * w1[t];
  out[(b * NN + n) * NF + f] = acc;
}
__global__ void k_sa_lhs(const float* l1, const float* w2, float* out, int T) {
  int total = NB * NN * T;
  int idx = blockIdx.x * 256 + threadIdx.x;
  if (idx >= total) return;
  int t = idx % T;
  int n = (idx / T) % NN;
  int b = idx / (T * NN);
  float acc = 0.f;
  for (int f = 0; f < NF; f++) acc += l1[(b * NN + n) * NF + f] * w2[f * T + t];
  out[idx] = acc;  // (b,n,t)
}
__global__ void k_sa_rhs(const float* xt, const float* w3, float* out, int T) {
  int total = NB * T * NN;
  int idx = blockIdx.x * 256 + threadIdx.x;
  if (idx >= total) return;
  int n = idx % NN;
  int t = (idx / NN) % T;
  int b = idx / (NN * T);
  float acc = 0.f;
  for (int f = 0; f < NF; f++) acc += w3[f] * xt[((size_t)(b * NF + f) * NN + n) * T + t];
  out[idx] = acc;  // (b,t,n)
}
__global__ void k_sa_prod(const float* lhs, const float* rhs, const float* bs, float* s0, int T) {
  int total = NB * NN * NN;
  int idx = blockIdx.x * 256 + threadIdx.x;
  if (idx >= total) return;
  int m = idx % NN;
  int n = (idx / NN) % NN;
  int b = idx / (NN * NN);
  float acc = 0.f;
  for (int t = 0; t < T; t++)
    acc += lhs[((size_t)b * NN + n) * T + t] * rhs[((size_t)b * T + t) * NN + m];
  s0[idx] = sigf(acc + bs[(size_t)n * NN + m]);
}

// 500x500 transpose (for vs)
__global__ __launch_bounds__(256) void k_transpose(const float* in, float* outT) {
  __shared__ float tile[32][33];
  int x0 = blockIdx.x * 32, y0 = blockIdx.y * 32;
  int tx = threadIdx.x & 31, ty8 = threadIdx.x >> 5;
  for (int yy = ty8; yy < 32; yy += 8) {
    int x = x0 + tx, y = y0 + yy;
    tile[yy][tx] = (x < NN && y < NN) ? in[(size_t)y * NN + x] : 0.f;
  }
  __syncthreads();
  for (int yy = ty8; yy < 32; yy += 8) {
    int x = y0 + tx, y = x0 + yy;
    if (x < NN && y < NN) outT[(size_t)y * NN + x] = tile[tx][yy];
  }
}

// s1T[b,c,r] = (vs @ s0[b])[r,c] — A from vsT (coalesced), b128 LDS reads both sides
__global__ __launch_bounds__(256) void k_gemm_vs(const float* __restrict__ vsT,
                                                 const float* __restrict__ s0,
                                                 float* __restrict__ s1t) {
  __shared__ float As[16][68];
  __shared__ float Bs[16][68];
  int b = blockIdx.z;
  int row0 = blockIdx.y * 64, col0 = blockIdx.x * 64;
  int tx = threadIdx.x, ty = threadIdx.y;
  int tid = ty * 16 + tx;
  float acc[4][4] = {};
  const float* S0 = s0 + (size_t)b * NN * NN;
  for (int k0 = 0; k0 < NN; k0 += 16) {
    for (int l = tid; l < 1024; l += 256) {
      int kk = l >> 6, r = l & 63;
      int gi = row0 + r, gk = k0 + kk;
      As[kk][r] = (gi < NN && gk < NN) ? vsT[(size_t)gk * NN + gi] : 0.f;
    }
    for (int l = tid; l < 1024; l += 256) {
      int kk = l >> 6, cc = l & 63;
      int gk = k0 + kk, gc = col0 + cc;
      Bs[kk][cc] = (gk < NN && gc < NN) ? S0[(size_t)gk * NN + gc] : 0.f;
    }
    __syncthreads();
    for (int kk = 0; kk < 16; kk++) {
      float4 a4 = *(const float4*)&As[kk][ty * 4];
      float4 b4 = *(const float4*)&Bs[kk][tx * 4];
      float a[4] = {a4.x, a4.y, a4.z, a4.w};
      float bb[4] = {b4.x, b4.y, b4.z, b4.w};
#pragma unroll
      for (int i = 0; i < 4; i++)
#pragma unroll
        for (int j = 0; j < 4; j++) acc[i][j] += a[i] * bb[j];
    }
    __syncthreads();
  }
  float* S1 = s1t + (size_t)b * NN * NN;
  for (int j = 0; j < 4; j++)
    for (int i = 0; i < 4; i++) {
      int gi = row0 + ty * 4 + i, gc = col0 + tx * 4 + j;
      if (gi < NN && gc < NN) S1[(size_t)gc * NN + gi] = acc[i][j];  // transposed
    }
}
// softmax over r (contiguous): st[b,c,r] = softmax_r(s1t[b,c,r]); block per (c,b)
__global__ __launch_bounds__(256) void k_sa_smax_row(const float* s1t, float* st) {
  int c = blockIdx.x, b = blockIdx.y;
  int tid = threadIdx.x;
  const float* S = s1t + ((size_t)b * NN + c) * NN;
  float* O = st + ((size_t)b * NN + c) * NN;
  __shared__ float red[256];
  float mx = -1e30f;
  for (int i = tid; i < NN; i += 256) mx = fmaxf(mx, S[i]);
  red[tid] = mx;
  __syncthreads();
  for (int s = 128; s > 0; s >>= 1) {
    if (tid < s) red[tid] = fmaxf(red[tid], red[tid + s]);
    __syncthreads();
  }
  mx = red[0];
  __syncthreads();
  float sum = 0.f;
  for (int i = tid; i < NN; i += 256) sum += __expf(S[i] - mx);
  red[tid] = sum;
  __syncthreads();
  for (int s = 128; s > 0; s >>= 1) {
    if (tid < s) red[tid] += red[tid + s];
    __syncthreads();
  }
  float inv = 1.f / red[0];
  for (int i = tid; i < NN; i += 256) O[i] = __expf(S[i] - mx) * inv;
}

// chebT[k,n,m] = cheb[k,m,n]
__global__ void k_chebT(const float* cheb, float* ct) {
  int total = 3 * NN * NN;
  int idx = blockIdx.x * 256 + threadIdx.x;
  if (idx >= total) return;
  int m = idx % NN;
  int n = (idx / NN) % NN;
  int k = idx / (NN * NN);
  ct[idx] = cheb[((size_t)k * NN + m) * NN + n];
}

// hT2[b][m][t*NF+f] = h[b][f][m][t]  (t-major columns; coalesced writes)
__global__ void k_htrans(const float* __restrict__ h, float* __restrict__ hT2, int T) {
  int NFT = NF * T;
  int total = NB * NN * NFT;
  int idx = blockIdx.x * 256 + threadIdx.x;
  if (idx >= total) return;
  int tf = idx % NFT;
  int m = (idx / NFT) % NN;
  int b = idx / (NFT * NN);
  int f = tf & 31, t = tf >> 5;
  hT2[idx] = h[((size_t)(b * NF + f) * NN + m) * T + t];
}

// ---- chebyshev conv as fused tiled GEMM + theta epilogue ----
// grid (ceil(T/2), 8, NB); 64-node x (2t x 32f) tile; K=500; k=0 via identity-diagonal.
template<int T>
__global__ __launch_bounds__(256) void k_chebf(const float* __restrict__ hT2,
                                               const float* __restrict__ st,
                                               const float* __restrict__ ct,
                                               const float* __restrict__ theta,
                                               float* __restrict__ out) {
  constexpr int NFT = NF * T;
  const int b = blockIdx.z;
  const int n0 = blockIdx.y * 64;
  const int t0 = blockIdx.x * 2;
  const int tid = threadIdx.x;
  const int tx = tid & 15, ty = tid >> 4;
  __shared__ float smem[12480];     // union: GEMM tiles | epilogue staging
  __shared__ float sdiag[64];
  float* As = smem;                 // [2][16][68]
  float* Bs = smem + 2176;          // [16][68]
  float acc1[4][4] = {}, acc2[4][4] = {};
  const float* hTb = hT2 + (size_t)b * NN * NFT;
  const int cb = t0 * NF;
  for (int m0 = 0; m0 < NN; m0 += 16) {
    for (int l = tid; l < 2048; l += 256) {
      int kk = l & 15, nn = (l >> 4) & 63, ks = l >> 10;
      int n = n0 + nn, m = m0 + kk;
      float v = 0.f;
      if (n < NN && m < NN)
        v = ct[((size_t)(ks + 1) * NN + n) * NN + m] * st[((size_t)b * NN + n) * NN + m];
      As[ks * 1088 + kk * 68 + nn] = v;
    }
    for (int l = tid; l < 1024; l += 256) {
      int kk = l >> 6, cc = l & 63;
      int m = m0 + kk, c = cb + cc;
      Bs[kk * 68 + cc] = (m < NN && c < NFT) ? hTb[(size_t)m * NFT + c] : 0.f;
    }
    __syncthreads();
#pragma unroll
    for (int kk = 0; kk < 16; kk++) {
      float4 a1 = *(const float4*)&As[kk * 68 + ty * 4];
      float4 a2 = *(const float4*)&As[1088 + kk * 68 + ty * 4];
      float4 bv = *(const float4*)&Bs[kk * 68 + tx * 4];
      float av1[4] = {a1.x, a1.y, a1.z, a1.w};
      float av2[4] = {a2.x, a2.y, a2.z, a2.w};
      float bb[4] = {bv.x, bv.y, bv.z, bv.w};
#pragma unroll
      for (int i = 0; i < 4; i++)
#pragma unroll
        for (int j = 0; j < 4; j++) {
          acc1[i][j] += av1[i] * bb[j];
          acc2[i][j] += av2[i] * bb[j];
        }
    }
    __syncthreads();
  }
  // epilogue staging: Y1/Y2 (stride 65) + diag rows of hT2 + st diagonal
  float* Y1 = smem;                 // [64][65]
  float* Y2 = smem + 4160;
  float* HD = smem + 8320;
  if (tid < 64) {
    int n = n0 + tid;
    sdiag[tid] = (n < NN) ? st[((size_t)b * NN + n) * NN + n] : 0.f;
  }
#pragma unroll
  for (int i = 0; i < 4; i++)
#pragma unroll
    for (int j = 0; j < 4; j++) {
      Y1[(ty * 4 + i) * 65 + tx * 4 + j] = acc1[i][j];
      Y2[(ty * 4 + i) * 65 + tx * 4 + j] = acc2[i][j];
    }
  for (int l = tid; l < 4096; l += 256) {
    int nn = l >> 6, cc = l & 63;
    int n = n0 + nn, c = cb + cc;
    HD[nn * 65 + cc] = (n < NN && c < NFT) ? hTb[(size_t)n * NFT + c] : 0.f;
  }
  __syncthreads();
  for (int j = 0; j < 16; j++) {
    int it = tid + j * 256;
    int nn = it & 63, f2 = (it >> 6) & 31, ts = it >> 11;
    int n = n0 + nn, t = t0 + ts;
    if (n < NN && t < T) {
      float sd = sdiag[nn];
      float o = 0.f;
      int cbb = ts * NF;
#pragma unroll 8
      for (int f = 0; f < NF; f++) {
        float hv = HD[nn * 65 + cbb + f];
        float y1 = Y1[nn * 65 + cbb + f];
        float y2 = Y2[nn * 65 + cbb + f];
        o += theta[f * NF + f2] * (sd * hv)
           + theta[(NF + f) * NF + f2] * y1
           + theta[(2 * NF + f) * NF + f2] * y2;
      }
      out[((size_t)(b * NF + f2) * NN + n) * T + t] = fmaxf(o, 0.f);
    }
  }
}

// ---- layer norm over (C,N,T) per sample ----
__global__ void k_zero(float* p, int n) {
  int i = blockIdx.x * 256 + threadIdx.x;
  if (i < n) p[i] = 0.f;
}
__global__ void k_ln_part(const float* x, float* acc, int M) {
  int b = blockIdx.y;
  const float* xp = x + (size_t)b * M;
  float s1 = 0.f, s2 = 0.f;
  for (int i = blockIdx.x * blockDim.x + threadIdx.x; i < M; i += gridDim.x * blockDim.x) {
    float v = xp[i]; s1 += v; s2 += v * v;
  }
  __shared__ float r1[256], r2[256];
  int tid = threadIdx.x;
  r1[tid] = s1; r2[tid] = s2;
  __syncthreads();
  for (int s = 128; s > 0; s >>= 1) {
    if (tid < s) { r1[tid] += r1[tid + s]; r2[tid] += r2[tid + s]; }
    __syncthreads();
  }
  if (tid == 0) { atomicAdd(&acc[b * 2], r1[0]); atomicAdd(&acc[b * 2 + 1], r2[0]); }
}
__global__ void k_ln_norm(const float* x, const float* acc, const float* wn, const float* bn,
                          float* out, int M) {
  int total = NB * M;
  int idx = blockIdx.x * 256 + threadIdx.x;
  if (idx >= total) return;
  int b = idx / M;
  int i = idx % M;
  float mean = acc[b * 2] / M;
  float var = acc[b * 2 + 1] / M - mean * mean;
  float y = (x[idx] - mean) * rsqrtf(var + 1e-5f);
  out[idx] = y * wn[i] + bn[i];
}

// ---- final head ----
__global__ void k_fin1(const float* h, const float* w, const float* bias, const float* skip,
                       float* out) {
  int total = NB * 64 * NN;
  int idx = blockIdx.x * 256 + threadIdx.x;
  if (idx >= total) return;
  int n = idx % NN;
  int c = (idx / NN) % 64;
  int b = idx / (NN * 64);
  float v = bias[c];
  for (int ci = 0; ci < 32; ci++) v += w[c * 32 + ci] * h[(b * NF + ci) * NN + n];
  v += skip[((size_t)(b * 64 + c) * NN + n) * 7 + 6];
  out[idx] = fmaxf(v, 0.f);
}
__global__ void k_fin2(const float* in, const float* w, const float* bias, float* out) {
  int total = NB * 128 * NN;
  int idx = blockIdx.x * 256 + threadIdx.x;
  if (idx >= total) return;
  int n = idx % NN;
  int c = (idx / NN) % 128;
  int b = idx / (NN * 128);
  float v = bias[c];
  for (int ci = 0; ci < 64; ci++) v += w[c * 64 + ci] * in[(b * 64 + ci) * NN + n];
  out[idx] = fmaxf(v, 0.f);
}
__global__ void k_fin3(const float* in, const float* w, const float* bias, float* out) {
  int total = NB * 12 * NN;
  int idx = blockIdx.x * 256 + threadIdx.x;
  if (idx >= total) return;
  int n = idx % NN;
  int c = (idx / NN) % 12;
  int b = idx / (NN * 12);
  float v = bias[c];
  for (int ci = 0; ci < 128; ci++) v += w[c * 128 + ci] * in[(b * 128 + ci) * NN + n];
  out[idx] = v;
}

#define G1(tot) dim3((unsigned)(((tot) + 255) / 256)), dim3(256), 0, stream

extern "C" void kernel_launch(void* const* d_in, const int* in_sizes, int n_in,
                              void* d_out, int out_size, void* d_ws, size_t ws_size,
                              hipStream_t stream) {
  (void)in_sizes; (void)n_in; (void)out_size; (void)ws_size;
  auto I = [&](int i) { return (const float*)d_in[i]; };
  float* W = (float*)d_ws;
  size_t off = 0;
  auto alloc = [&](size_t nel) { float* p = W + off; off += nel; return p; };

  float* bufA  = alloc(9728000);   // h / residual [B,32,N,19max]
  float* bufB  = alloc(9728000);   // h after fc1; later cheb output
  float* bufC  = alloc(9728000);   // x_tat -> s1T -> hT2 ; later gtufc#2 output
  float* bufSK = alloc(7168000);   // skip [B,64,N,7]
  float* skip0 = alloc(1024000);   // skip [B,64,N,1]
  float* P1    = alloc(8000000);   // s0 / st; reused for F1/F2 at end
  float* CT    = alloc(750000);    // chebT
  float* VST   = alloc(250000);    // vs transposed (per layer)
  float* TL1   = alloc(19456);
  float* TLH   = alloc(304000);
  float* TRH   = alloc(304000);
  float* TE    = alloc(11552);
  float* SL1   = alloc(512000);
  float* SLH   = alloc(304000);
  float* SRH   = alloc(304000);
  float* ACC   = alloc(64);
  float* P2 = bufC;                // s1T lives in bufC until smax consumes it
  float* HT = bufC;                // hT2[b][m][t*NF+f] lives in bufC after smax
  float* F1 = P1;                  // [B,64,N] final head, after P1 (st) is dead
  float* F2 = P1 + 1024000;        // [B,128,N]

  k_start<<<G1(NB * NF * NN * 19)>>>(I(0), I(1), I(2), bufA);
  k_skip0<<<G1(NB * 64 * NN)>>>(I(0), I(3), I(4), skip0);
  k_chebT<<<G1(3 * NN * NN)>>>(I(59), CT);

  dim3 ggt((NN + 7) / 8, NB), bgt(256);
  auto gtufc = [&](int Ti, int To, const float* hin, const float* fw, const float* fb,
                   const float* res, float* o) {
    if (Ti == 19 && To == 19)
      k_gtufc_t<19, 19><<<ggt, bgt, 0, stream>>>(hin, I(5), I(6), I(7), I(8), I(9), I(10), fw, fb, res, o);
    else if (Ti == 19 && To == 13)
      k_gtufc_t<19, 13><<<ggt, bgt, 0, stream>>>(hin, I(5), I(6), I(7), I(8), I(9), I(10), fw, fb, res, o);
    else if (Ti == 13 && To == 13)
      k_gtufc_t<13, 13><<<ggt, bgt, 0, stream>>>(hin, I(5), I(6), I(7), I(8), I(9), I(10), fw, fb, res, o);
    else if (Ti == 13 && To == 7)
      k_gtufc_t<13, 7><<<ggt, bgt, 0, stream>>>(hin, I(5), I(6), I(7), I(8), I(9), I(10), fw, fb, res, o);
    else if (Ti == 7 && To == 7)
      k_gtufc_t<7, 7><<<ggt, bgt, 0, stream>>>(hin, I(5), I(6), I(7), I(8), I(9), I(10), fw, fb, res, o);
    else
      k_gtufc_t<7, 1><<<ggt, bgt, 0, stream>>>(hin, I(5), I(6), I(7), I(8), I(9), I(10), fw, fb, res, o);
  };

  const int Tin[3] = {19, 13, 7}, Tout[3] = {13, 7, 1};
  for (int i = 0; i < 3; i++) {
    int Ti = Tin[i], To = Tout[i];
    // gated TCN + fc1 + relu-add : bufA -> bufB
    gtufc(Ti, Ti, bufA, I(11 + 2 * i), I(12 + 2 * i), nullptr, bufB);
    // skip conv
    if (i == 0)
      k_skipconv_t<19, 13><<<ggt, bgt, 0, stream>>>(bufB, I(23), I(24), skip0, 1, bufSK);
    else if (i == 1)
      k_skipconv_t<13, 7><<<ggt, bgt, 0, stream>>>(bufB, I(25), I(26), bufSK, 7, bufSK);
    else
      k_skipconv_t<7, 1><<<ggt, bgt, 0, stream>>>(bufB, I(27), I(28), bufSK, 7, bufSK);
    // temporal attention
    int ba = 29 + i * 10;
    k_ta_lhs1<<<G1(NB * Ti * NF)>>>(bufB, I(ba + 0), TL1, Ti);
    k_ta_lhs<<<G1(NB * Ti * NN)>>>(TL1, I(ba + 1), TLH, Ti);
    k_ta_rhs<<<G1(NB * NN * Ti)>>>(bufB, I(ba + 2), TRH, Ti);
    k_ta_att<<<dim3(NB), dim3(256), 0, stream>>>(TLH, TRH, I(ba + 3), I(ba + 4), TE, Ti);
    k_xtat<<<G1(NB * NF * NN * Ti)>>>(TE, bufB, bufC, Ti);  // x_tat into bufC
    // spatial attention
    k_sa_lhs1<<<G1(NB * NN * NF)>>>(bufC, I(ba + 5), SL1, Ti);
    k_sa_lhs<<<G1(NB * NN * Ti)>>>(SL1, I(ba + 6), SLH, Ti);
    k_sa_rhs<<<G1(NB * Ti * NN)>>>(bufC, I(ba + 7), SRH, Ti);
    k_sa_prod<<<G1(NB * NN * NN)>>>(SLH, SRH, I(ba + 8), P1, Ti);  // x_tat consumed
    k_transpose<<<dim3(16, 16), dim3(256), 0, stream>>>(I(ba + 9), VST);
    {
      dim3 gg(8, 8, NB), bb(16, 16);
      k_gemm_vs<<<gg, bb, 0, stream>>>(VST, P1, P2);  // s1T into bufC
    }
    k_sa_smax_row<<<dim3(NN, NB), dim3(256), 0, stream>>>(P2, P1);  // st into P1; bufC free
    // transpose h for cheb (t-major): bufB -> HT (bufC)
    k_htrans<<<G1(NB * NN * NF * Ti)>>>(bufB, HT, Ti);
    // chebyshev fused GEMM+theta: HT + st -> bufB (h dead)
    {
      dim3 gc((Ti + 1) / 2, 8, NB), bc(256);
      if (Ti == 19)      k_chebf<19><<<gc, bc, 0, stream>>>(HT, P1, CT, I(60), bufB);
      else if (Ti == 13) k_chebf<13><<<gc, bc, 0, stream>>>(HT, P1, CT, I(60), bufB);
      else               k_chebf<7><<<gc, bc, 0, stream>>>(HT, P1, CT, I(60), bufB);
    }
    // second gated TCN + fc2 + relu-add + residual : bufB (+bufA) -> bufC
    gtufc(Ti, To, bufB, I(17 + 2 * i), I(18 + 2 * i), bufA, bufC);
    // layer norm: bufC -> bufA
    int M = NF * NN * To;
    k_zero<<<dim3(1), dim3(256), 0, stream>>>(ACC, 64);
    k_ln_part<<<dim3(16, NB), dim3(256), 0, stream>>>(bufC, ACC, M);
    k_ln_norm<<<G1(NB * M)>>>(bufC, ACC, I(61 + 2 * i), I(62 + 2 * i), bufA, M);
  }
  // final head
  k_fin1<<<G1(NB * 64 * NN)>>>(bufA, I(67), I(68), bufSK, F1);
  k_fin2<<<G1(NB * 128 * NN)>>>(F1, I(69), I(70), F2);
  k_fin3<<<G1(NB * 12 * NN)>>>(F2, I(71), I(72), (float*)d_out);
}

// Round 10
// 5971.603 us; speedup vs baseline: 2.2584x; 1.0530x over previous
//
#include <hip/hip_runtime.h>
#include <hip/hip_bf16.h>
#include <math.h>

#define NB 32      // batch
#define NN 500     // nodes
#define NF 32      // channels

__device__ __forceinline__ float sigf(float x) { return 1.0f / (1.0f + __expf(-x)); }

// h[b,c,n,t] = b_start[c] + sum_ci w_start[c,ci]*padded_x[b,ci,n,t]; pad 7 zeros at front (19)
__global__ void k_start(const float* x, const float* w, const float* bias, float* h) {
  int idx = blockIdx.x * 256 + threadIdx.x;
  const int total = NB * NF * NN * 19;
  if (idx >= total) return;
  int t = idx % 19;
  int n = (idx / 19) % NN;
  int c = (idx / (19 * NN)) % NF;
  int b = idx / (19 * NN * NF);
  float v = bias[c];
  if (t >= 7) {
    int tx = t - 7;
    v += w[c * 2 + 0] * x[((size_t)(b * 2 + 0) * NN + n) * 12 + tx];
    v += w[c * 2 + 1] * x[((size_t)(b * 2 + 1) * NN + n) * 12 + tx];
  }
  h[idx] = v;
}

// skip0[b,c,n] = b_sk0[c] + sum_{ci,k>=7} w_sk0[c,ci,k]*x[b,ci,n,k-7]
__global__ void k_skip0(const float* x, const float* w, const float* bias, float* s0) {
  int idx = blockIdx.x * 256 + threadIdx.x;
  const int total = NB * 64 * NN;
  if (idx >= total) return;
  int n = idx % NN;
  int c = (idx / NN) % 64;
  int b = idx / (NN * 64);
  float v = bias[c];
  for (int ci = 0; ci < 2; ci++)
    for (int k = 7; k < 19; k++)
      v += w[(c * 2 + ci) * 19 + k] * x[((size_t)(b * 2 + ci) * NN + n) * 12 + (k - 7)];
  s0[idx] = v;
}

// ---- fused gated-TCN + fc; gtu_seg generalized over LDS strides (TS=time, CS=channel) ----
template<int K, int L, int TS, int CS, int TCAT, int TO>
__device__ __forceinline__ void gtu_seg(const float* __restrict__ wseg,
                                        const float* __restrict__ bg,
                                        const float* __restrict__ hbase,
                                        const float* __restrict__ fw,
                                        float (&oacc)[TO], int c, int tbase) {
  float y0[L], y1[L];
#pragma unroll
  for (int t = 0; t < L; t++) { y0[t] = 0.f; y1[t] = 0.f; }
#pragma unroll 2
  for (int ci = 0; ci < NF; ci++) {
    float hrow[L + K - 1];
#pragma unroll
    for (int t = 0; t < L + K - 1; t++) hrow[t] = hbase[ci * CS + t * TS];
    float w0[K], w1[K];
#pragma unroll
    for (int j = 0; j < K; j++) {
      w0[j] = wseg[(c * NF + ci) * K + j];
      w1[j] = wseg[((c + 32) * NF + ci) * K + j];
    }
#pragma unroll
    for (int t = 0; t < L; t++)
#pragma unroll
      for (int j = 0; j < K; j++) {
        y0[t] += w0[j] * hrow[t + j];
        y1[t] += w1[j] * hrow[t + j];
      }
  }
  float b0 = bg[c], b1 = bg[c + 32];
#pragma unroll
  for (int t = 0; t < L; t++) {
    float tcv = tanhf(y0[t] + b0) * sigf(y1[t] + b1);
#pragma unroll
    for (int o = 0; o < TO; o++) oacc[o] += tcv * fw[o * TCAT + tbase + t];
  }
}

// standard-layout input h[b,c,n,t]
template<int TI, int TO>
__global__ __launch_bounds__(256) void k_gtufc_t(
    const float* __restrict__ h,
    const float* __restrict__ wg3, const float* __restrict__ bg3,
    const float* __restrict__ wg5, const float* __restrict__ bg5,
    const float* __restrict__ wg7, const float* __restrict__ bg7,
    const float* __restrict__ fw, const float* __restrict__ fb,
    const float* __restrict__ res, float* __restrict__ out) {
  constexpr int TCAT = 3 * TI - 12;
  constexpr int TP = (TI + 3) & ~3;
  constexpr int OFF = TI - TO;
  const int b = blockIdx.y;
  const int n0 = blockIdx.x * 8;
  const int tid = threadIdx.x;
  const int c = tid & 31, nn = tid >> 5;
  const int n = n0 + nn;
  __shared__ float hs[8 * NF * TP];
  for (int l = tid; l < 8 * NF * TP; l += 256) {
    int t = l % TP;
    int ci = (l / TP) % NF;
    int n2 = l / (TP * NF);
    int gn = n0 + n2;
    hs[l] = (t < TI && gn < NN) ? h[((size_t)(b * NF + ci) * NN + gn) * TI + t] : 0.f;
  }
  __syncthreads();
  const float* hbase = hs + nn * NF * TP;
  float oacc[TO];
#pragma unroll
  for (int o = 0; o < TO; o++) oacc[o] = 0.f;
  gtu_seg<3, TI - 2, 1, TP, TCAT, TO>(wg3, bg3, hbase, fw, oacc, c, 0);
  gtu_seg<5, TI - 4, 1, TP, TCAT, TO>(wg5, bg5, hbase, fw, oacc, c, TI - 2);
  gtu_seg<7, TI - 6, 1, TP, TCAT, TO>(wg7, bg7, hbase, fw, oacc, c, 2 * TI - 6);
  if (n < NN) {
    size_t base = (size_t)(b * NF + c) * NN + n;
#pragma unroll
    for (int o = 0; o < TO; o++) {
      float v = fmaxf(hbase[c * TP + OFF + o] + oacc[o] + fb[o], 0.f);
      if (res) v += res[base * TI + OFF + o];
      out[base * TO + o] = v;
    }
  }
}

// t-major input hX[b][n][t*NF+f] (chebf output layout); output standard layout
template<int TI, int TO>
__global__ __launch_bounds__(256) void k_gtufc_x(
    const float* __restrict__ hX,
    const float* __restrict__ wg3, const float* __restrict__ bg3,
    const float* __restrict__ wg5, const float* __restrict__ bg5,
    const float* __restrict__ wg7, const float* __restrict__ bg7,
    const float* __restrict__ fw, const float* __restrict__ fb,
    const float* __restrict__ res, float* __restrict__ out) {
  constexpr int TCAT = 3 * TI - 12;
  constexpr int NFT = NF * TI;
  constexpr int OFF = TI - TO;
  const int b = blockIdx.y;
  const int n0 = blockIdx.x * 8;
  const int tid = threadIdx.x;
  const int c = tid & 31, nn = tid >> 5;
  const int n = n0 + nn;
  __shared__ float hs[8 * NFT];
  for (int l = tid; l < 8 * NFT; l += 256) {
    int n2 = l / NFT, l2 = l % NFT;
    int gn = n0 + n2;
    hs[l] = (gn < NN) ? hX[(size_t)(b * NN + gn) * NFT + l2] : 0.f;
  }
  __syncthreads();
  const float* hbase = hs + nn * NFT;
  float oacc[TO];
#pragma unroll
  for (int o = 0; o < TO; o++) oacc[o] = 0.f;
  gtu_seg<3, TI - 2, NF, 1, TCAT, TO>(wg3, bg3, hbase, fw, oacc, c, 0);
  gtu_seg<5, TI - 4, NF, 1, TCAT, TO>(wg5, bg5, hbase, fw, oacc, c, TI - 2);
  gtu_seg<7, TI - 6, NF, 1, TCAT, TO>(wg7, bg7, hbase, fw, oacc, c, 2 * TI - 6);
  if (n < NN) {
    size_t base = (size_t)(b * NF + c) * NN + n;
#pragma unroll
    for (int o = 0; o < TO; o++) {
      float v = fmaxf(hbase[(OFF + o) * NF + c] + oacc[o] + fb[o], 0.f);
      if (res) v += res[base * TI + OFF + o];
      out[base * TO + o] = v;
    }
  }
}

// ---- skip conv, LDS h staging, weights in registers, K unrolled ----
template<int TI, int K>
__global__ __launch_bounds__(256) void k_skipconv_t(
    const float* __restrict__ h, const float* __restrict__ w,
    const float* __restrict__ bias, const float* __restrict__ prev, int prevT,
    float* __restrict__ out) {
  constexpr int TP = (TI + 3) & ~3;
  const int b = blockIdx.y, n0 = blockIdx.x * 8, tid = threadIdx.x;
  __shared__ float hs[8 * NF * TP];
  for (int l = tid; l < 8 * NF * TP; l += 256) {
    int t = l % TP;
    int ci = (l / TP) % NF;
    int n2 = l / (TP * NF);
    int gn = n0 + n2;
    hs[l] = (t < TI && gn < NN) ? h[((size_t)(b * NF + ci) * NN + gn) * TI + t] : 0.f;
  }
  __syncthreads();
  const int c = tid & 63, ng = tid >> 6;
  float bv = bias[c];
  float o[2][7];
#pragma unroll
  for (int q = 0; q < 2; q++)
#pragma unroll
    for (int t = 0; t < 7; t++) o[q][t] = bv;
  for (int ci = 0; ci < NF; ci++) {
    float wv[K];
#pragma unroll
    for (int j = 0; j < K; j++) wv[j] = w[(c * NF + ci) * K + j];
#pragma unroll
    for (int q = 0; q < 2; q++) {
      const float* hp = hs + ((ng + q * 4) * NF + ci) * TP;
#pragma unroll
      for (int t = 0; t < 7; t++) {
        float s = 0.f;
#pragma unroll
        for (int j = 0; j < K; j++) s += wv[j] * hp[t + j];
        o[q][t] += s;
      }
    }
  }
#pragma unroll
  for (int q = 0; q < 2; q++) {
    int n = n0 + ng + q * 4;
    if (n < NN) {
      size_t base = (size_t)(b * 64 + c) * NN + n;
#pragma unroll
      for (int t = 0; t < 7; t++) {
        float pv = (prevT == 1) ? prev[base] : prev[base * 7 + t];
        out[base * 7 + t] = o[q][t] + pv;
      }
    }
  }
}

// ---- temporal attention ----
__global__ void k_ta_lhs1(const float* h, const float* u1, float* out, int T) {
  int total = NB * T * NF;
  int idx = blockIdx.x * 256 + threadIdx.x;
  if (idx >= total) return;
  int f = idx % NF;
  int t = (idx / NF) % T;
  int b = idx / (NF * T);
  const float* hp = h + ((size_t)(b * NF + f) * NN) * T + t;
  float acc = 0.f;
  for (int n = 0; n < NN; n++) acc += hp[(size_t)n * T] * u1[n];
  out[(b * T + t) * NF + f] = acc;
}
__global__ void k_ta_lhs(const float* l1, const float* u2, float* out, int T) {
  int total = NB * T * NN;
  int idx = blockIdx.x * 256 + threadIdx.x;
  if (idx >= total) return;
  int n = idx % NN;
  int t = (idx / NN) % T;
  int b = idx / (NN * T);
  float acc = 0.f;
  for (int f = 0; f < NF; f++) acc += l1[(b * T + t) * NF + f] * u2[f * NN + n];
  out[idx] = acc;  // (b,t,n)
}
__global__ void k_ta_rhs(const float* h, const float* u3, float* out, int T) {
  int total = NB * NN * T;
  int idx = blockIdx.x * 256 + threadIdx.x;
  if (idx >= total) return;
  int t = idx % T;
  int n = (idx / T) % NN;
  int b = idx / (T * NN);
  float acc = 0.f;
  for (int f = 0; f < NF; f++) acc += u3[f] * h[((size_t)(b * NF + f) * NN + n) * T + t];
  out[idx] = acc;  // (b,n,t)
}
// fused: e0 = sigf(lhs@rhs + be); e1 = ve@e0; e = softmax over t. one block per b.
__global__ __launch_bounds__(256) void k_ta_att(const float* __restrict__ lhs,
                                                const float* __restrict__ rhs,
                                                const float* __restrict__ be,
                                                const float* __restrict__ ve,
                                                float* __restrict__ e, int T) {
  int b = blockIdx.x, tid = threadIdx.x;
  __shared__ float e0[19 * 19];
  __shared__ float e1[19 * 19];
  int TT = T * T;
  for (int l = tid; l < TT; l += 256) {
    int t = l / T, m = l % T;
    float acc = 0.f;
    const float* lp = lhs + ((size_t)b * T + t) * NN;
    const float* rp = rhs + (size_t)b * NN * T + m;
    for (int n = 0; n < NN; n++) acc += lp[n] * rp[(size_t)n * T];
    e0[l] = sigf(acc + be[l]);
  }
  __syncthreads();
  for (int l = tid; l < TT; l += 256) {
    int t = l / T, m = l % T;
    float acc = 0.f;
    for (int j = 0; j < T; j++) acc += ve[t * T + j] * e0[j * T + m];
    e1[l] = acc;
  }
  __syncthreads();
  if (tid < T) {
    int m = tid;
    float mx = -1e30f;
    for (int t = 0; t < T; t++) mx = fmaxf(mx, e1[t * T + m]);
    float s = 0.f;
    for (int t = 0; t < T; t++) s += __expf(e1[t * T + m] - mx);
    float inv = 1.f / s;
    for (int t = 0; t < T; t++)
      e[((size_t)b * T + t) * T + m] = __expf(e1[t * T + m] - mx) * inv;
  }
}
// xt[b,f,n,t] = sum_j e[b,t,j] * h[b,f,n,j]
__global__ void k_xtat(const float* e, const float* h, float* xt, int T) {
  int total = NB * NF * NN * T;
  int idx = blockIdx.x * 256 + threadIdx.x;
  if (idx >= total) return;
  int t = idx % T;
  int n = (idx / T) % NN;
  int f = (idx / (T * NN)) % NF;
  int b = idx / (T * NN * NF);
  const float* hp = h + ((size_t)(b * NF + f) * NN + n) * T;
  float acc = 0.f;
  for (int j = 0; j < T; j++) acc += e[(b * T + t) * T + j] * hp[j];
  xt[idx] = acc;
}

// ---- spatial attention ----
__global__ void k_sa_lhs1(const float* xt, const float* w1, float* out, int T) {
  int total = NB * NN * NF;
  int idx = blockIdx.x * 256 + threadIdx.x;
  if (idx >= total) return;
  int f = idx % NF;
  int n = (idx / NF) % NN;
  int b = idx / (NF * NN);
  const float* xp = xt + ((size_t)(b * NF + f) * NN + n) * T;
  float acc = 0.f;
  for (int t = 0; t < T; t++) acc += xp[t] * w1[t];
  out[(b * NN + n) * NF + f] = acc;
}
__global__ void k_sa_lhs(const float* l1, const float* w2, float* out, int T) {
  int total = NB * NN * T;
  int idx = blockIdx.x * 256 + threadIdx.x;
  if (idx >= total) return;
  int t = idx % T;
  int n = (idx / T) % NN;
  int b = idx / (T * NN);
  float acc = 0.f;
  for (int f = 0; f < NF; f++) acc += l1[(b * NN + n) * NF + f] * w2[f * T + t];
  out[idx] = acc;  // (b,n,t)
}
__global__ void k_sa_rhs(const float* xt, const float* w3, float* out, int T) {
  int total = NB * T * NN;
  int idx = blockIdx.x * 256 + threadIdx.x;
  if (idx >= total) return;
  int n = idx % NN;
  int t = (idx / NN) % T;
  int b = idx / (NN * T);
  float acc = 0.f;
  for (int f = 0; f < NF; f++) acc += w3[f] * xt[((size_t)(b * NF + f) * NN + n) * T + t];
  out[idx] = acc;  // (b,t,n)
}
__global__ void k_sa_prod(const float* lhs, const float* rhs, const float* bs, float* s0, int T) {
  int total = NB * NN * NN;
  int idx = blockIdx.x * 256 + threadIdx.x;
  if (idx >= total) return;
  int m = idx % NN;
  int n = (idx / NN) % NN;
  int b = idx / (NN * NN);
  float acc = 0.f;
  for (int t = 0; t < T; t++)
    acc += lhs[((size_t)b * NN + n) * T + t] * rhs[((size_t)b * T + t) * NN + m];
  s0[idx] = sigf(acc + bs[(size_t)n * NN + m]);
}

// 500x500 transpose (for vs)
__global__ __launch_bounds__(256) void k_transpose(const float* in, float* outT) {
  __shared__ float tile[32][33];
  int x0 = blockIdx.x * 32, y0 = blockIdx.y * 32;
  int tx = threadIdx.x & 31, ty8 = threadIdx.x >> 5;
  for (int yy = ty8; yy < 32; yy += 8) {
    int x = x0 + tx, y = y0 + yy;
    tile[yy][tx] = (x < NN && y < NN) ? in[(size_t)y * NN + x] : 0.f;
  }
  __syncthreads();
  for (int yy = ty8; yy < 32; yy += 8) {
    int x = y0 + tx, y = x0 + yy;
    if (x < NN && y < NN) outT[(size_t)y * NN + x] = tile[tx][yy];
  }
}

// s1T[b,c,r] = (vs @ s0[b])[r,c] — A from vsT (coalesced), b128 LDS reads both sides
__global__ __launch_bounds__(256) void k_gemm_vs(const float* __restrict__ vsT,
                                                 const float* __restrict__ s0,
                                                 float* __restrict__ s1t) {
  __shared__ float As[16][68];
  __shared__ float Bs[16][68];
  int b = blockIdx.z;
  int row0 = blockIdx.y * 64, col0 = blockIdx.x * 64;
  int tx = threadIdx.x, ty = threadIdx.y;
  int tid = ty * 16 + tx;
  float acc[4][4] = {};
  const float* S0 = s0 + (size_t)b * NN * NN;
  for (int k0 = 0; k0 < NN; k0 += 16) {
    for (int l = tid; l < 1024; l += 256) {
      int kk = l >> 6, r = l & 63;
      int gi = row0 + r, gk = k0 + kk;
      As[kk][r] = (gi < NN && gk < NN) ? vsT[(size_t)gk * NN + gi] : 0.f;
    }
    for (int l = tid; l < 1024; l += 256) {
      int kk = l >> 6, cc = l & 63;
      int gk = k0 + kk, gc = col0 + cc;
      Bs[kk][cc] = (gk < NN && gc < NN) ? S0[(size_t)gk * NN + gc] : 0.f;
    }
    __syncthreads();
    for (int kk = 0; kk < 16; kk++) {
      float4 a4 = *(const float4*)&As[kk][ty * 4];
      float4 b4 = *(const float4*)&Bs[kk][tx * 4];
      float a[4] = {a4.x, a4.y, a4.z, a4.w};
      float bb[4] = {b4.x, b4.y, b4.z, b4.w};
#pragma unroll
      for (int i = 0; i < 4; i++)
#pragma unroll
        for (int j = 0; j < 4; j++) acc[i][j] += a[i] * bb[j];
    }
    __syncthreads();
  }
  float* S1 = s1t + (size_t)b * NN * NN;
  for (int j = 0; j < 4; j++)
    for (int i = 0; i < 4; i++) {
      int gi = row0 + ty * 4 + i, gc = col0 + tx * 4 + j;
      if (gi < NN && gc < NN) S1[(size_t)gc * NN + gi] = acc[i][j];  // transposed
    }
}
// softmax over r (contiguous): st[b,c,r] = softmax_r(s1t[b,c,r]); block per (c,b)
__global__ __launch_bounds__(256) void k_sa_smax_row(const float* s1t, float* st) {
  int c = blockIdx.x, b = blockIdx.y;
  int tid = threadIdx.x;
  const float* S = s1t + ((size_t)b * NN + c) * NN;
  float* O = st + ((size_t)b * NN + c) * NN;
  __shared__ float red[256];
  float mx = -1e30f;
  for (int i = tid; i < NN; i += 256) mx = fmaxf(mx, S[i]);
  red[tid] = mx;
  __syncthreads();
  for (int s = 128; s > 0; s >>= 1) {
    if (tid < s) red[tid] = fmaxf(red[tid], red[tid + s]);
    __syncthreads();
  }
  mx = red[0];
  __syncthreads();
  float sum = 0.f;
  for (int i = tid; i < NN; i += 256) sum += __expf(S[i] - mx);
  red[tid] = sum;
  __syncthreads();
  for (int s = 128; s > 0; s >>= 1) {
    if (tid < s) red[tid] += red[tid + s];
    __syncthreads();
  }
  float inv = 1.f / red[0];
  for (int i = tid; i < NN; i += 256) O[i] = __expf(S[i] - mx) * inv;
}

// chebT[k,n,m] = cheb[k,m,n]
__global__ void k_chebT(const float* cheb, float* ct) {
  int total = 3 * NN * NN;
  int idx = blockIdx.x * 256 + threadIdx.x;
  if (idx >= total) return;
  int m = idx % NN;
  int n = (idx / NN) % NN;
  int k = idx / (NN * NN);
  ct[idx] = cheb[((size_t)k * NN + m) * NN + n];
}

// hT2[b][m][t*NF+f] = h[b][f][m][t]  (t-major columns; coalesced writes)
__global__ void k_htrans(const float* __restrict__ h, float* __restrict__ hT2, int T) {
  int NFT = NF * T;
  int total = NB * NN * NFT;
  int idx = blockIdx.x * 256 + threadIdx.x;
  if (idx >= total) return;
  int tf = idx % NFT;
  int m = (idx / NFT) % NN;
  int b = idx / (NFT * NN);
  int f = tf & 31, t = tf >> 5;
  hT2[idx] = h[((size_t)(b * NF + f) * NN + m) * T + t];
}

// ---- chebyshev conv as fused tiled GEMM + theta epilogue; t-major output ----
// outX[b][n][t*NF+f2] = relu(sum_k sum_f theta[k,f,f2]*Y_k); k=0 via identity-diagonal.
template<int T>
__global__ __launch_bounds__(256) void k_chebf(const float* __restrict__ hT2,
                                               const float* __restrict__ st,
                                               const float* __restrict__ ct,
                                               const float* __restrict__ theta,
                                               float* __restrict__ outX) {
  constexpr int NFT = NF * T;
  const int b = blockIdx.z;
  const int n0 = blockIdx.y * 64;
  const int t0 = blockIdx.x * 2;
  const int tid = threadIdx.x;
  const int tx = tid & 15, ty = tid >> 4;
  __shared__ float smem[8704];      // union: GEMM tiles (3264) | epilogue Y1/Y2 (2*4352)
  __shared__ float sdiag[64];
  float* As = smem;                 // [2][16][68]
  float* Bs = smem + 2176;          // [16][68]
  float acc1[4][4] = {}, acc2[4][4] = {};
  const float* hTb = hT2 + (size_t)b * NN * NFT;
  const int cb = t0 * NF;
  for (int m0 = 0; m0 < NN; m0 += 16) {
    for (int l = tid; l < 2048; l += 256) {
      int kk = l & 15, nn = (l >> 4) & 63, ks = l >> 10;
      int n = n0 + nn, m = m0 + kk;
      float v = 0.f;
      if (n < NN && m < NN)
        v = ct[((size_t)(ks + 1) * NN + n) * NN + m] * st[((size_t)b * NN + n) * NN + m];
      As[ks * 1088 + kk * 68 + nn] = v;
    }
    for (int l = tid; l < 1024; l += 256) {
      int kk = l >> 6, cc = l & 63;
      int m = m0 + kk, c = cb + cc;
      Bs[kk * 68 + cc] = (m < NN && c < NFT) ? hTb[(size_t)m * NFT + c] : 0.f;
    }
    __syncthreads();
#pragma unroll
    for (int kk = 0; kk < 16; kk++) {
      float4 a1 = *(const float4*)&As[kk * 68 + ty * 4];
      float4 a2 = *(const float4*)&As[1088 + kk * 68 + ty * 4];
      float4 bv = *(const float4*)&Bs[kk * 68 + tx * 4];
      float av1[4] = {a1.x, a1.y, a1.z, a1.w};
      float av2[4] = {a2.x, a2.y, a2.z, a2.w};
      float bb[4] = {bv.x, bv.y, bv.z, bv.w};
#pragma unroll
      for (int i = 0; i < 4; i++)
#pragma unroll
        for (int j = 0; j < 4; j++) {
          acc1[i][j] += av1[i] * bb[j];
          acc2[i][j] += av2[i] * bb[j];
        }
    }
    __syncthreads();
  }
  // epilogue: stage Y1/Y2 (stride 68), diagonal term direct from global
  float* Y1 = smem;                 // [64][68]
  float* Y2 = smem + 4352;
  if (tid < 64) {
    int n = n0 + tid;
    sdiag[tid] = (n < NN) ? st[((size_t)b * NN + n) * NN + n] : 0.f;
  }
#pragma unroll
  for (int i = 0; i < 4; i++)
#pragma unroll
    for (int j = 0; j < 4; j++) {
      Y1[(ty * 4 + i) * 68 + tx * 4 + j] = acc1[i][j];
      Y2[(ty * 4 + i) * 68 + tx * 4 + j] = acc2[i][j];
    }
  __syncthreads();
  for (int j = 0; j < 16; j++) {
    int it = tid + j * 256;
    int cc = it & 63, nn = it >> 6;
    int n = n0 + nn, c = cb + cc;
    if (n < NN && c < NFT) {
      int ts = cc >> 5, f2 = cc & 31;
      int cbb = ts * NF;
      float sd = sdiag[nn];
      const float* hrow = hTb + (size_t)n * NFT + cb + cbb;  // diag row (broadcast, L2-hot)
      float o = 0.f;
#pragma unroll 8
      for (int f = 0; f < NF; f++) {
        o += theta[f * NF + f2] * (sd * hrow[f])
           + theta[(NF + f) * NF + f2] * Y1[nn * 68 + cbb + f]
           + theta[(2 * NF + f) * NF + f2] * Y2[nn * 68 + cbb + f];
      }
      outX[(size_t)(b * NN + n) * NFT + c] = fmaxf(o, 0.f);
    }
  }
}

// ---- layer norm over (C,N,T) per sample ----
__global__ void k_zero(float* p, int n) {
  int i = blockIdx.x * 256 + threadIdx.x;
  if (i < n) p[i] = 0.f;
}
__global__ void k_ln_part(const float* x, float* acc, int M) {
  int b = blockIdx.y;
  const float* xp = x + (size_t)b * M;
  float s1 = 0.f, s2 = 0.f;
  for (int i = blockIdx.x * blockDim.x + threadIdx.x; i < M; i += gridDim.x * blockDim.x) {
    float v = xp[i]; s1 += v; s2 += v * v;
  }
  __shared__ float r1[256], r2[256];
  int tid = threadIdx.x;
  r1[tid] = s1; r2[tid] = s2;
  __syncthreads();
  for (int s = 128; s > 0; s >>= 1) {
    if (tid < s) { r1[tid] += r1[tid + s]; r2[tid] += r2[tid + s]; }
    __syncthreads();
  }
  if (tid == 0) { atomicAdd(&acc[b * 2], r1[0]); atomicAdd(&acc[b * 2 + 1], r2[0]); }
}
__global__ void k_ln_norm(const float* x, const float* acc, const float* wn, const float* bn,
                          float* out, int M) {
  int total = NB * M;
  int idx = blockIdx.x * 256 + threadIdx.x;
  if (idx >= total) return;
  int b = idx / M;
  int i = idx % M;
  float mean = acc[b * 2] / M;
  float var = acc[b * 2 + 1] / M - mean * mean;
  float y = (x[idx] - mean) * rsqrtf(var + 1e-5f);
  out[idx] = y * wn[i] + bn[i];
}

// ---- final head ----
__global__ void k_fin1(const float* h, const float* w, const float* bias, const float* skip,
                       float* out) {
  int total = NB * 64 * NN;
  int idx = blockIdx.x * 256 + threadIdx.x;
  if (idx >= total) return;
  int n = idx % NN;
  int c = (idx / NN) % 64;
  int b = idx / (NN * 64);
  float v = bias[c];
  for (int ci = 0; ci < 32; ci++) v += w[c * 32 + ci] * h[(b * NF + ci) * NN + n];
  v += skip[((size_t)(b * 64 + c) * NN + n) * 7 + 6];
  out[idx] = fmaxf(v, 0.f);
}
__global__ void k_fin2(const float* in, const float* w, const float* bias, float* out) {
  int total = NB * 128 * NN;
  int idx = blockIdx.x * 256 + threadIdx.x;
  if (idx >= total) return;
  int n = idx % NN;
  int c = (idx / NN) % 128;
  int b = idx / (NN * 128);
  float v = bias[c];
  for (int ci = 0; ci < 64; ci++) v += w[c * 64 + ci] * in[(b * 64 + ci) * NN + n];
  out[idx] = fmaxf(v, 0.f);
}
__global__ void k_fin3(const float* in, const float* w, const float* bias, float* out) {
  int total = NB * 12 * NN;
  int idx = blockIdx.x * 256 + threadIdx.x;
  if (idx >= total) return;
  int n = idx % NN;
  int c = (idx / NN) % 12;
  int b = idx / (NN * 12);
  float v = bias[c];
  for (int ci = 0; ci < 128; ci++) v += w[c * 128 + ci] * in[(b * 128 + ci) * NN + n];
  out[idx] = v;
}

#define G1(tot) dim3((unsigned)(((tot) + 255) / 256)), dim3(256), 0, stream

extern "C" void kernel_launch(void* const* d_in, const int* in_sizes, int n_in,
                              void* d_out, int out_size, void* d_ws, size_t ws_size,
                              hipStream_t stream) {
  (void)in_sizes; (void)n_in; (void)out_size; (void)ws_size;
  auto I = [&](int i) { return (const float*)d_in[i]; };
  float* W = (float*)d_ws;
  size_t off = 0;
  auto alloc = [&](size_t nel) { float* p = W + off; off += nel; return p; };

  float* bufA  = alloc(9728000);   // h / residual [B,32,N,19max]
  float* bufB  = alloc(9728000);   // h after fc1; later cheb output (t-major)
  float* bufC  = alloc(9728000);   // x_tat -> s1T -> hT2 ; later gtufc#2 output
  float* bufSK = alloc(7168000);   // skip [B,64,N,7]
  float* skip0 = alloc(1024000);   // skip [B,64,N,1]
  float* P1    = alloc(8000000);   // s0 / st; reused for F1/F2 at end
  float* CT    = alloc(750000);    // chebT
  float* VST   = alloc(250000);    // vs transposed (per layer)
  float* TL1   = alloc(19456);
  float* TLH   = alloc(304000);
  float* TRH   = alloc(304000);
  float* TE    = alloc(11552);
  float* SL1   = alloc(512000);
  float* SLH   = alloc(304000);
  float* SRH   = alloc(304000);
  float* ACC   = alloc(64);
  float* P2 = bufC;                // s1T lives in bufC until smax consumes it
  float* HT = bufC;                // hT2[b][m][t*NF+f] lives in bufC after smax
  float* F1 = P1;                  // [B,64,N] final head, after P1 (st) is dead
  float* F2 = P1 + 1024000;        // [B,128,N]

  k_start<<<G1(NB * NF * NN * 19)>>>(I(0), I(1), I(2), bufA);
  k_skip0<<<G1(NB * 64 * NN)>>>(I(0), I(3), I(4), skip0);
  k_chebT<<<G1(3 * NN * NN)>>>(I(59), CT);

  dim3 ggt((NN + 7) / 8, NB), bgt(256);
  auto gtufc = [&](int Ti, int To, const float* hin, const float* fw, const float* fb,
                   const float* res, float* o) {
    if (Ti == 19 && To == 19)
      k_gtufc_t<19, 19><<<ggt, bgt, 0, stream>>>(hin, I(5), I(6), I(7), I(8), I(9), I(10), fw, fb, res, o);
    else if (Ti == 13 && To == 13)
      k_gtufc_t<13, 13><<<ggt, bgt, 0, stream>>>(hin, I(5), I(6), I(7), I(8), I(9), I(10), fw, fb, res, o);
    else
      k_gtufc_t<7, 7><<<ggt, bgt, 0, stream>>>(hin, I(5), I(6), I(7), I(8), I(9), I(10), fw, fb, res, o);
  };
  auto gtufcx = [&](int Ti, int To, const float* hin, const float* fw, const float* fb,
                    const float* res, float* o) {
    if (Ti == 19)
      k_gtufc_x<19, 13><<<ggt, bgt, 0, stream>>>(hin, I(5), I(6), I(7), I(8), I(9), I(10), fw, fb, res, o);
    else if (Ti == 13)
      k_gtufc_x<13, 7><<<ggt, bgt, 0, stream>>>(hin, I(5), I(6), I(7), I(8), I(9), I(10), fw, fb, res, o);
    else
      k_gtufc_x<7, 1><<<ggt, bgt, 0, stream>>>(hin, I(5), I(6), I(7), I(8), I(9), I(10), fw, fb, res, o);
  };

  const int Tin[3] = {19, 13, 7}, Tout[3] = {13, 7, 1};
  for (int i = 0; i < 3; i++) {
    int Ti = Tin[i], To = Tout[i];
    // gated TCN + fc1 + relu-add : bufA -> bufB
    gtufc(Ti, Ti, bufA, I(11 + 2 * i), I(12 + 2 * i), nullptr, bufB);
    // skip conv
    if (i == 0)
      k_skipconv_t<19, 13><<<ggt, bgt, 0, stream>>>(bufB, I(23), I(24), skip0, 1, bufSK);
    else if (i == 1)
      k_skipconv_t<13, 7><<<ggt, bgt, 0, stream>>>(bufB, I(25), I(26), bufSK, 7, bufSK);
    else
      k_skipconv_t<7, 1><<<ggt, bgt, 0, stream>>>(bufB, I(27), I(28), bufSK, 7, bufSK);
    // temporal attention
    int ba = 29 + i * 10;
    k_ta_lhs1<<<G1(NB * Ti * NF)>>>(bufB, I(ba + 0), TL1, Ti);
    k_ta_lhs<<<G1(NB * Ti * NN)>>>(TL1, I(ba + 1), TLH, Ti);
    k_ta_rhs<<<G1(NB * NN * Ti)>>>(bufB, I(ba + 2), TRH, Ti);
    k_ta_att<<<dim3(NB), dim3(256), 0, stream>>>(TLH, TRH, I(ba + 3), I(ba + 4), TE, Ti);
    k_xtat<<<G1(NB * NF * NN * Ti)>>>(TE, bufB, bufC, Ti);  // x_tat into bufC
    // spatial attention
    k_sa_lhs1<<<G1(NB * NN * NF)>>>(bufC, I(ba + 5), SL1, Ti);
    k_sa_lhs<<<G1(NB * NN * Ti)>>>(SL1, I(ba + 6), SLH, Ti);
    k_sa_rhs<<<G1(NB * Ti * NN)>>>(bufC, I(ba + 7), SRH, Ti);
    k_sa_prod<<<G1(NB * NN * NN)>>>(SLH, SRH, I(ba + 8), P1, Ti);  // x_tat consumed
    k_transpose<<<dim3(16, 16), dim3(256), 0, stream>>>(I(ba + 9), VST);
    {
      dim3 gg(8, 8, NB), bb(16, 16);
      k_gemm_vs<<<gg, bb, 0, stream>>>(VST, P1, P2);  // s1T into bufC
    }
    k_sa_smax_row<<<dim3(NN, NB), dim3(256), 0, stream>>>(P2, P1);  // st into P1; bufC free
    // transpose h for cheb (t-major): bufB -> HT (bufC)
    k_htrans<<<G1(NB * NN * NF * Ti)>>>(bufB, HT, Ti);
    // chebyshev fused GEMM+theta: HT + st -> bufB (t-major output)
    {
      dim3 gc((Ti + 1) / 2, 8, NB), bc(256);
      if (Ti == 19)      k_chebf<19><<<gc, bc, 0, stream>>>(HT, P1, CT, I(60), bufB);
      else if (Ti == 13) k_chebf<13><<<gc, bc, 0, stream>>>(HT, P1, CT, I(60), bufB);
      else               k_chebf<7><<<gc, bc, 0, stream>>>(HT, P1, CT, I(60), bufB);
    }
    // second gated TCN (t-major input) + fc2 + relu-add + residual : bufB (+bufA) -> bufC
    gtufcx(Ti, To, bufB, I(17 + 2 * i), I(18 + 2 * i), bufA, bufC);
    // layer norm: bufC -> bufA
    int M = NF * NN * To;
    k_zero<<<dim3(1), dim3(256), 0, stream>>>(ACC, 64);
    k_ln_part<<<dim3(16, NB), dim3(256), 0, stream>>>(bufC, ACC, M);
    k_ln_norm<<<G1(NB * M)>>>(bufC, ACC, I(61 + 2 * i), I(62 + 2 * i), bufA, M);
  }
  // final head
  k_fin1<<<G1(NB * 64 * NN)>>>(bufA, I(67), I(68), bufSK, F1);
  k_fin2<<<G1(NB * 128 * NN)>>>(F1, I(69), I(70), F2);
  k_fin3<<<G1(NB * 12 * NN)>>>(F2, I(71), I(72), (float*)d_out);
}

// Round 11
// 5951.655 us; speedup vs baseline: 2.2660x; 1.0034x over previous
//
#include <hip/hip_runtime.h>
#include <hip/hip_bf16.h>
#include <math.h>

#define NB 32      // batch
#define NN 500     // nodes
#define NF 32      // channels

__device__ __forceinline__ float sigf(float x) { return 1.0f / (1.0f + __expf(-x)); }

// h[b,c,n,t] = b_start[c] + sum_ci w_start[c,ci]*padded_x[b,ci,n,t]; pad 7 zeros at front (19)
__global__ void k_start(const float* x, const float* w, const float* bias, float* h) {
  int idx = blockIdx.x * 256 + threadIdx.x;
  const int total = NB * NF * NN * 19;
  if (idx >= total) return;
  int t = idx % 19;
  int n = (idx / 19) % NN;
  int c = (idx / (19 * NN)) % NF;
  int b = idx / (19 * NN * NF);
  float v = bias[c];
  if (t >= 7) {
    int tx = t - 7;
    v += w[c * 2 + 0] * x[((size_t)(b * 2 + 0) * NN + n) * 12 + tx];
    v += w[c * 2 + 1] * x[((size_t)(b * 2 + 1) * NN + n) * 12 + tx];
  }
  h[idx] = v;
}

// skip0[b,c,n] = b_sk0[c] + sum_{ci,k>=7} w_sk0[c,ci,k]*x[b,ci,n,k-7]
__global__ void k_skip0(const float* x, const float* w, const float* bias, float* s0) {
  int idx = blockIdx.x * 256 + threadIdx.x;
  const int total = NB * 64 * NN;
  if (idx >= total) return;
  int n = idx % NN;
  int c = (idx / NN) % 64;
  int b = idx / (NN * 64);
  float v = bias[c];
  for (int ci = 0; ci < 2; ci++)
    for (int k = 7; k < 19; k++)
      v += w[(c * 2 + ci) * 19 + k] * x[((size_t)(b * 2 + ci) * NN + n) * 12 + (k - 7)];
  s0[idx] = v;
}

// ---- fused gated-TCN + fc; gtu_seg generalized over LDS strides (TS=time, CS=channel) ----
template<int K, int L, int TS, int CS, int TCAT, int TO>
__device__ __forceinline__ void gtu_seg(const float* __restrict__ wseg,
                                        const float* __restrict__ bg,
                                        const float* __restrict__ hbase,
                                        const float* __restrict__ fw,
                                        float (&oacc)[TO], int c, int tbase) {
  float y0[L], y1[L];
#pragma unroll
  for (int t = 0; t < L; t++) { y0[t] = 0.f; y1[t] = 0.f; }
#pragma unroll 2
  for (int ci = 0; ci < NF; ci++) {
    float hrow[L + K - 1];
#pragma unroll
    for (int t = 0; t < L + K - 1; t++) hrow[t] = hbase[ci * CS + t * TS];
    float w0[K], w1[K];
#pragma unroll
    for (int j = 0; j < K; j++) {
      w0[j] = wseg[(c * NF + ci) * K + j];
      w1[j] = wseg[((c + 32) * NF + ci) * K + j];
    }
#pragma unroll
    for (int t = 0; t < L; t++)
#pragma unroll
      for (int j = 0; j < K; j++) {
        y0[t] += w0[j] * hrow[t + j];
        y1[t] += w1[j] * hrow[t + j];
      }
  }
  float b0 = bg[c], b1 = bg[c + 32];
#pragma unroll
  for (int t = 0; t < L; t++) {
    float tcv = tanhf(y0[t] + b0) * sigf(y1[t] + b1);
#pragma unroll
    for (int o = 0; o < TO; o++) oacc[o] += tcv * fw[o * TCAT + tbase + t];
  }
}

// standard-layout input h[b,c,n,t]
template<int TI, int TO>
__global__ __launch_bounds__(256) void k_gtufc_t(
    const float* __restrict__ h,
    const float* __restrict__ wg3, const float* __restrict__ bg3,
    const float* __restrict__ wg5, const float* __restrict__ bg5,
    const float* __restrict__ wg7, const float* __restrict__ bg7,
    const float* __restrict__ fw, const float* __restrict__ fb,
    const float* __restrict__ res, float* __restrict__ out) {
  constexpr int TCAT = 3 * TI - 12;
  constexpr int TP = (TI + 3) & ~3;
  constexpr int OFF = TI - TO;
  const int b = blockIdx.y;
  const int n0 = blockIdx.x * 8;
  const int tid = threadIdx.x;
  const int c = tid & 31, nn = tid >> 5;
  const int n = n0 + nn;
  __shared__ float hs[8 * NF * TP];
  for (int l = tid; l < 8 * NF * TP; l += 256) {
    int t = l % TP;
    int ci = (l / TP) % NF;
    int n2 = l / (TP * NF);
    int gn = n0 + n2;
    hs[l] = (t < TI && gn < NN) ? h[((size_t)(b * NF + ci) * NN + gn) * TI + t] : 0.f;
  }
  __syncthreads();
  const float* hbase = hs + nn * NF * TP;
  float oacc[TO];
#pragma unroll
  for (int o = 0; o < TO; o++) oacc[o] = 0.f;
  gtu_seg<3, TI - 2, 1, TP, TCAT, TO>(wg3, bg3, hbase, fw, oacc, c, 0);
  gtu_seg<5, TI - 4, 1, TP, TCAT, TO>(wg5, bg5, hbase, fw, oacc, c, TI - 2);
  gtu_seg<7, TI - 6, 1, TP, TCAT, TO>(wg7, bg7, hbase, fw, oacc, c, 2 * TI - 6);
  if (n < NN) {
    size_t base = (size_t)(b * NF + c) * NN + n;
#pragma unroll
    for (int o = 0; o < TO; o++) {
      float v = fmaxf(hbase[c * TP + OFF + o] + oacc[o] + fb[o], 0.f);
      if (res) v += res[base * TI + OFF + o];
      out[base * TO + o] = v;
    }
  }
}

// t-major input hX[b][n][t*NF+f] (cheb output layout); output standard layout
template<int TI, int TO>
__global__ __launch_bounds__(256) void k_gtufc_x(
    const float* __restrict__ hX,
    const float* __restrict__ wg3, const float* __restrict__ bg3,
    const float* __restrict__ wg5, const float* __restrict__ bg5,
    const float* __restrict__ wg7, const float* __restrict__ bg7,
    const float* __restrict__ fw, const float* __restrict__ fb,
    const float* __restrict__ res, float* __restrict__ out) {
  constexpr int TCAT = 3 * TI - 12;
  constexpr int NFT = NF * TI;
  constexpr int OFF = TI - TO;
  const int b = blockIdx.y;
  const int n0 = blockIdx.x * 8;
  const int tid = threadIdx.x;
  const int c = tid & 31, nn = tid >> 5;
  const int n = n0 + nn;
  __shared__ float hs[8 * NFT];
  for (int l = tid; l < 8 * NFT; l += 256) {
    int n2 = l / NFT, l2 = l % NFT;
    int gn = n0 + n2;
    hs[l] = (gn < NN) ? hX[(size_t)(b * NN + gn) * NFT + l2] : 0.f;
  }
  __syncthreads();
  const float* hbase = hs + nn * NFT;
  float oacc[TO];
#pragma unroll
  for (int o = 0; o < TO; o++) oacc[o] = 0.f;
  gtu_seg<3, TI - 2, NF, 1, TCAT, TO>(wg3, bg3, hbase, fw, oacc, c, 0);
  gtu_seg<5, TI - 4, NF, 1, TCAT, TO>(wg5, bg5, hbase, fw, oacc, c, TI - 2);
  gtu_seg<7, TI - 6, NF, 1, TCAT, TO>(wg7, bg7, hbase, fw, oacc, c, 2 * TI - 6);
  if (n < NN) {
    size_t base = (size_t)(b * NF + c) * NN + n;
#pragma unroll
    for (int o = 0; o < TO; o++) {
      float v = fmaxf(hbase[(OFF + o) * NF + c] + oacc[o] + fb[o], 0.f);
      if (res) v += res[base * TI + OFF + o];
      out[base * TO + o] = v;
    }
  }
}

// ---- skip conv, LDS h staging, weights in registers, K unrolled ----
template<int TI, int K>
__global__ __launch_bounds__(256) void k_skipconv_t(
    const float* __restrict__ h, const float* __restrict__ w,
    const float* __restrict__ bias, const float* __restrict__ prev, int prevT,
    float* __restrict__ out) {
  constexpr int TP = (TI + 3) & ~3;
  const int b = blockIdx.y, n0 = blockIdx.x * 8, tid = threadIdx.x;
  __shared__ float hs[8 * NF * TP];
  for (int l = tid; l < 8 * NF * TP; l += 256) {
    int t = l % TP;
    int ci = (l / TP) % NF;
    int n2 = l / (TP * NF);
    int gn = n0 + n2;
    hs[l] = (t < TI && gn < NN) ? h[((size_t)(b * NF + ci) * NN + gn) * TI + t] : 0.f;
  }
  __syncthreads();
  const int c = tid & 63, ng = tid >> 6;
  float bv = bias[c];
  float o[2][7];
#pragma unroll
  for (int q = 0; q < 2; q++)
#pragma unroll
    for (int t = 0; t < 7; t++) o[q][t] = bv;
  for (int ci = 0; ci < NF; ci++) {
    float wv[K];
#pragma unroll
    for (int j = 0; j < K; j++) wv[j] = w[(c * NF + ci) * K + j];
#pragma unroll
    for (int q = 0; q < 2; q++) {
      const float* hp = hs + ((ng + q * 4) * NF + ci) * TP;
#pragma unroll
      for (int t = 0; t < 7; t++) {
        float s = 0.f;
#pragma unroll
        for (int j = 0; j < K; j++) s += wv[j] * hp[t + j];
        o[q][t] += s;
      }
    }
  }
#pragma unroll
  for (int q = 0; q < 2; q++) {
    int n = n0 + ng + q * 4;
    if (n < NN) {
      size_t base = (size_t)(b * 64 + c) * NN + n;
#pragma unroll
      for (int t = 0; t < 7; t++) {
        float pv = (prevT == 1) ? prev[base] : prev[base * 7 + t];
        out[base * 7 + t] = o[q][t] + pv;
      }
    }
  }
}

// ---- temporal attention ----
__global__ void k_ta_lhs1(const float* h, const float* u1, float* out, int T) {
  int total = NB * T * NF;
  int idx = blockIdx.x * 256 + threadIdx.x;
  if (idx >= total) return;
  int f = idx % NF;
  int t = (idx / NF) % T;
  int b = idx / (NF * T);
  const float* hp = h + ((size_t)(b * NF + f) * NN) * T + t;
  float acc = 0.f;
  for (int n = 0; n < NN; n++) acc += hp[(size_t)n * T] * u1[n];
  out[(b * T + t) * NF + f] = acc;
}
__global__ void k_ta_lhs(const float* l1, const float* u2, float* out, int T) {
  int total = NB * T * NN;
  int idx = blockIdx.x * 256 + threadIdx.x;
  if (idx >= total) return;
  int n = idx % NN;
  int t = (idx / NN) % T;
  int b = idx / (NN * T);
  float acc = 0.f;
  for (int f = 0; f < NF; f++) acc += l1[(b * T + t) * NF + f] * u2[f * NN + n];
  out[idx] = acc;  // (b,t,n)
}
__global__ void k_ta_rhs(const float* h, const float* u3, float* out, int T) {
  int total = NB * NN * T;
  int idx = blockIdx.x * 256 + threadIdx.x;
  if (idx >= total) return;
  int t = idx % T;
  int n = (idx / T) % NN;
  int b = idx / (T * NN);
  float acc = 0.f;
  for (int f = 0; f < NF; f++) acc += u3[f] * h[((size_t)(b * NF + f) * NN + n) * T + t];
  out[idx] = acc;  // (b,n,t)
}
// fused: e0 = sigf(lhs@rhs + be); e1 = ve@e0; e = softmax over t. one block per b.
__global__ __launch_bounds__(256) void k_ta_att(const float* __restrict__ lhs,
                                                const float* __restrict__ rhs,
                                                const float* __restrict__ be,
                                                const float* __restrict__ ve,
                                                float* __restrict__ e, int T) {
  int b = blockIdx.x, tid = threadIdx.x;
  __shared__ float e0[19 * 19];
  __shared__ float e1[19 * 19];
  int TT = T * T;
  for (int l = tid; l < TT; l += 256) {
    int t = l / T, m = l % T;
    float acc = 0.f;
    const float* lp = lhs + ((size_t)b * T + t) * NN;
    const float* rp = rhs + (size_t)b * NN * T + m;
    for (int n = 0; n < NN; n++) acc += lp[n] * rp[(size_t)n * T];
    e0[l] = sigf(acc + be[l]);
  }
  __syncthreads();
  for (int l = tid; l < TT; l += 256) {
    int t = l / T, m = l % T;
    float acc = 0.f;
    for (int j = 0; j < T; j++) acc += ve[t * T + j] * e0[j * T + m];
    e1[l] = acc;
  }
  __syncthreads();
  if (tid < T) {
    int m = tid;
    float mx = -1e30f;
    for (int t = 0; t < T; t++) mx = fmaxf(mx, e1[t * T + m]);
    float s = 0.f;
    for (int t = 0; t < T; t++) s += __expf(e1[t * T + m] - mx);
    float inv = 1.f / s;
    for (int t = 0; t < T; t++)
      e[((size_t)b * T + t) * T + m] = __expf(e1[t * T + m] - mx) * inv;
  }
}
// xt[b,f,n,t] = sum_j e[b,t,j] * h[b,f,n,j]
__global__ void k_xtat(const float* e, const float* h, float* xt, int T) {
  int total = NB * NF * NN * T;
  int idx = blockIdx.x * 256 + threadIdx.x;
  if (idx >= total) return;
  int t = idx % T;
  int n = (idx / T) % NN;
  int f = (idx / (T * NN)) % NF;
  int b = idx / (T * NN * NF);
  const float* hp = h + ((size_t)(b * NF + f) * NN + n) * T;
  float acc = 0.f;
  for (int j = 0; j < T; j++) acc += e[(b * T + t) * T + j] * hp[j];
  xt[idx] = acc;
}

// ---- spatial attention ----
__global__ void k_sa_lhs1(const float* xt, const float* w1, float* out, int T) {
  int total = NB * NN * NF;
  int idx = blockIdx.x * 256 + threadIdx.x;
  if (idx >= total) return;
  int f = idx % NF;
  int n = (idx / NF) % NN;
  int b = idx / (NF * NN);
  const float* xp = xt + ((size_t)(b * NF + f) * NN + n) * T;
  float acc = 0.f;
  for (int t = 0; t < T; t++) acc += xp[t] * w1[t];
  out[(b * NN + n) * NF + f] = acc;
}
__global__ void k_sa_lhs(const float* l1, const float* w2, float* out, int T) {
  int total = NB * NN * T;
  int idx = blockIdx.x * 256 + threadIdx.x;
  if (idx >= total) return;
  int t = idx % T;
  int n = (idx / T) % NN;
  int b = idx / (T * NN);
  float acc = 0.f;
  for (int f = 0; f < NF; f++) acc += l1[(b * NN + n) * NF + f] * w2[f * T + t];
  out[idx] = acc;  // (b,n,t)
}
__global__ void k_sa_rhs(const float* xt, const float* w3, float* out, int T) {
  int total = NB * T * NN;
  int idx = blockIdx.x * 256 + threadIdx.x;
  if (idx >= total) return;
  int n = idx % NN;
  int t = (idx / NN) % T;
  int b = idx / (NN * T);
  float acc = 0.f;
  for (int f = 0; f < NF; f++) acc += w3[f] * xt[((size_t)(b * NF + f) * NN + n) * T + t];
  out[idx] = acc;  // (b,t,n)
}
__global__ void k_sa_prod(const float* lhs, const float* rhs, const float* bs, float* s0, int T) {
  int total = NB * NN * NN;
  int idx = blockIdx.x * 256 + threadIdx.x;
  if (idx >= total) return;
  int m = idx % NN;
  int n = (idx / NN) % NN;
  int b = idx / (NN * NN);
  float acc = 0.f;
  for (int t = 0; t < T; t++)
    acc += lhs[((size_t)b * NN + n) * T + t] * rhs[((size_t)b * T + t) * NN + m];
  s0[idx] = sigf(acc + bs[(size_t)n * NN + m]);
}

// 500x500 transpose (for vs)
__global__ __launch_bounds__(256) void k_transpose(const float* in, float* outT) {
  __shared__ float tile[32][33];
  int x0 = blockIdx.x * 32, y0 = blockIdx.y * 32;
  int tx = threadIdx.x & 31, ty8 = threadIdx.x >> 5;
  for (int yy = ty8; yy < 32; yy += 8) {
    int x = x0 + tx, y = y0 + yy;
    tile[yy][tx] = (x < NN && y < NN) ? in[(size_t)y * NN + x] : 0.f;
  }
  __syncthreads();
  for (int yy = ty8; yy < 32; yy += 8) {
    int x = y0 + tx, y = x0 + yy;
    if (x < NN && y < NN) outT[(size_t)y * NN + x] = tile[tx][yy];
  }
}

// s1T[b,c,r] = (vs @ s0[b])[r,c] — float4 staging, b128 LDS reads, transposed output
__global__ __launch_bounds__(256) void k_gemm_vs(const float* __restrict__ vsT,
                                                 const float* __restrict__ s0,
                                                 float* __restrict__ s1t) {
  __shared__ float As[16][68];
  __shared__ float Bs[16][68];
  int b = blockIdx.z;
  int row0 = blockIdx.y * 64, col0 = blockIdx.x * 64;
  int tx = threadIdx.x, ty = threadIdx.y;
  int tid = ty * 16 + tx;
  float acc[4][4] = {};
  const float* S0 = s0 + (size_t)b * NN * NN;
  for (int k0 = 0; k0 < NN; k0 += 16) {
    {
      int rq = tid & 15, kk = tid >> 4;
      int gi = row0 + rq * 4, gk = k0 + kk;
      float4 v = {0.f, 0.f, 0.f, 0.f};
      if (gk < NN && gi < NN) v = *(const float4*)&vsT[(size_t)gk * NN + gi];
      *(float4*)&As[kk][rq * 4] = v;
      float4 w = {0.f, 0.f, 0.f, 0.f};
      int gc = col0 + rq * 4;
      if (gk < NN && gc < NN) w = *(const float4*)&S0[(size_t)gk * NN + gc];
      *(float4*)&Bs[kk][rq * 4] = w;
    }
    __syncthreads();
    for (int kk = 0; kk < 16; kk++) {
      float4 a4 = *(const float4*)&As[kk][ty * 4];
      float4 b4 = *(const float4*)&Bs[kk][tx * 4];
      float a[4] = {a4.x, a4.y, a4.z, a4.w};
      float bb[4] = {b4.x, b4.y, b4.z, b4.w};
#pragma unroll
      for (int i = 0; i < 4; i++)
#pragma unroll
        for (int j = 0; j < 4; j++) acc[i][j] += a[i] * bb[j];
    }
    __syncthreads();
  }
  float* S1 = s1t + (size_t)b * NN * NN;
  for (int j = 0; j < 4; j++)
    for (int i = 0; i < 4; i++) {
      int gi = row0 + ty * 4 + i, gc = col0 + tx * 4 + j;
      if (gi < NN && gc < NN) S1[(size_t)gc * NN + gi] = acc[i][j];  // transposed
    }
}
// softmax over r (contiguous): st[b,c,r] = softmax_r(s1t[b,c,r]); block per (c,b)
__global__ __launch_bounds__(256) void k_sa_smax_row(const float* s1t, float* st) {
  int c = blockIdx.x, b = blockIdx.y;
  int tid = threadIdx.x;
  const float* S = s1t + ((size_t)b * NN + c) * NN;
  float* O = st + ((size_t)b * NN + c) * NN;
  __shared__ float red[256];
  float mx = -1e30f;
  for (int i = tid; i < NN; i += 256) mx = fmaxf(mx, S[i]);
  red[tid] = mx;
  __syncthreads();
  for (int s = 128; s > 0; s >>= 1) {
    if (tid < s) red[tid] = fmaxf(red[tid], red[tid + s]);
    __syncthreads();
  }
  mx = red[0];
  __syncthreads();
  float sum = 0.f;
  for (int i = tid; i < NN; i += 256) sum += __expf(S[i] - mx);
  red[tid] = sum;
  __syncthreads();
  for (int s = 128; s > 0; s >>= 1) {
    if (tid < s) red[tid] += red[tid + s];
    __syncthreads();
  }
  float inv = 1.f / red[0];
  for (int i = tid; i < NN; i += 256) O[i] = __expf(S[i] - mx) * inv;
}

// chebT[k,n,m] = cheb[k,m,n]
__global__ void k_chebT(const float* cheb, float* ct) {
  int total = 3 * NN * NN;
  int idx = blockIdx.x * 256 + threadIdx.x;
  if (idx >= total) return;
  int m = idx % NN;
  int n = (idx / NN) % NN;
  int k = idx / (NN * NN);
  ct[idx] = cheb[((size_t)k * NN + m) * NN + n];
}

// hT2[b][m][t*NF+f] = h[b][f][m][t]  (t-major columns; coalesced writes)
__global__ void k_htrans(const float* __restrict__ h, float* __restrict__ hT2, int T) {
  int NFT = NF * T;
  int total = NB * NN * NFT;
  int idx = blockIdx.x * 256 + threadIdx.x;
  if (idx >= total) return;
  int tf = idx % NFT;
  int m = (idx / NFT) % NN;
  int b = idx / (NFT * NN);
  int f = tf & 31, t = tf >> 5;
  hT2[idx] = h[((size_t)(b * NF + f) * NN + m) * T + t];
}

// ---- chebyshev conv: 64n x 128c tiled GEMM + theta epilogue, float4 staging ----
// outX[b][n][t*NF+f2] = relu(sum_k sum_f theta[k,f,f2]*Y_k); k=0 via identity-diagonal.
template<int T>
__global__ __launch_bounds__(256) void k_chebg(const float* __restrict__ hT2,
                                               const float* __restrict__ st,
                                               const float* __restrict__ ct,
                                               const float* __restrict__ theta,
                                               float* __restrict__ outX) {
  constexpr int NFT = NF * T;
  const int b = blockIdx.z;
  const int n0 = blockIdx.y * 64;
  const int cb = blockIdx.x * 128;
  const int tid = threadIdx.x;
  const int tx = tid & 15, ty = tid >> 4;
  __shared__ float smem[8704];      // union: As(2176)+Bs(2112) | Y1/Y2 (2*4352)
  __shared__ float sdiag[64];
  float* As = smem;                 // [2][16][68]
  float* Bs = smem + 2176;          // [16][132]
  float acc1[4][8] = {}, acc2[4][8] = {};
  const float* hTb = hT2 + (size_t)b * NN * NFT;
  for (int m0 = 0; m0 < NN; m0 += 16) {
    // As: ct*st, float4 over m (quads fully in/out since NN%4==0)
    for (int l = tid; l < 512; l += 256) {
      int q = l & 3, nn = (l >> 2) & 63, ks = l >> 8;
      int n = n0 + nn, m = m0 + q * 4;
      float4 v = {0.f, 0.f, 0.f, 0.f};
      if (n < NN && m < NN) {
        float4 c4 = *(const float4*)&ct[((size_t)(ks + 1) * NN + n) * NN + m];
        float4 s4 = *(const float4*)&st[((size_t)b * NN + n) * NN + m];
        v.x = c4.x * s4.x; v.y = c4.y * s4.y; v.z = c4.z * s4.z; v.w = c4.w * s4.w;
      }
      int base = ks * 1088 + nn;
      As[base + (q * 4 + 0) * 68] = v.x;
      As[base + (q * 4 + 1) * 68] = v.y;
      As[base + (q * 4 + 2) * 68] = v.z;
      As[base + (q * 4 + 3) * 68] = v.w;
    }
    // Bs: float4 over cols (NFT%4==0)
    for (int l = tid; l < 512; l += 256) {
      int q = l & 31, kk = l >> 5;
      int m = m0 + kk, c = cb + q * 4;
      float4 v = {0.f, 0.f, 0.f, 0.f};
      if (m < NN && c < NFT) v = *(const float4*)&hTb[(size_t)m * NFT + c];
      *(float4*)&Bs[kk * 132 + q * 4] = v;
    }
    __syncthreads();
#pragma unroll
    for (int kk = 0; kk < 16; kk++) {
      float4 a1 = *(const float4*)&As[kk * 68 + ty * 4];
      float4 a2 = *(const float4*)&As[1088 + kk * 68 + ty * 4];
      float4 b0 = *(const float4*)&Bs[kk * 132 + tx * 4];
      float4 b1 = *(const float4*)&Bs[kk * 132 + 64 + tx * 4];
      float av1[4] = {a1.x, a1.y, a1.z, a1.w};
      float av2[4] = {a2.x, a2.y, a2.z, a2.w};
      float bb[8] = {b0.x, b0.y, b0.z, b0.w, b1.x, b1.y, b1.z, b1.w};
#pragma unroll
      for (int i = 0; i < 4; i++)
#pragma unroll
        for (int j = 0; j < 8; j++) {
          acc1[i][j] += av1[i] * bb[j];
          acc2[i][j] += av2[i] * bb[j];
        }
    }
    __syncthreads();
  }
  if (tid < 64) {
    int n = n0 + tid;
    sdiag[tid] = (n < NN) ? st[((size_t)b * NN + n) * NN + n] : 0.f;
  }
  float* Y1 = smem;                 // [64][68]
  float* Y2 = smem + 4352;
  for (int hh = 0; hh < 2; hh++) {
    __syncthreads();
#pragma unroll
    for (int i = 0; i < 4; i++)
#pragma unroll
      for (int j = 0; j < 4; j++) {
        Y1[(ty * 4 + i) * 68 + tx * 4 + j] = acc1[i][hh * 4 + j];
        Y2[(ty * 4 + i) * 68 + tx * 4 + j] = acc2[i][hh * 4 + j];
      }
    __syncthreads();
    int cbh = cb + hh * 64;
    for (int j = 0; j < 16; j++) {
      int it = tid + j * 256;
      int cc = it & 63, nn = it >> 6;
      int n = n0 + nn, c = cbh + cc;
      if (n < NN && c < NFT) {
        int ts = cc >> 5, f2 = cc & 31;
        int cbb = ts * NF;
        float sd = sdiag[nn];
        const float* hrow = hTb + (size_t)n * NFT + cbh + cbb;  // diag row (broadcast)
        float o = 0.f;
#pragma unroll 8
        for (int f = 0; f < NF; f++) {
          o += theta[f * NF + f2] * (sd * hrow[f])
             + theta[(NF + f) * NF + f2] * Y1[nn * 68 + cbb + f]
             + theta[(2 * NF + f) * NF + f2] * Y2[nn * 68 + cbb + f];
        }
        outX[(size_t)(b * NN + n) * NFT + c] = fmaxf(o, 0.f);
      }
    }
  }
}

// ---- layer norm over (C,N,T) per sample; one block per b ----
__global__ __launch_bounds__(256) void k_ln_stat(const float* x, float* stat, int M) {
  int b = blockIdx.x;
  const float* xp = x + (size_t)b * M;
  float s1 = 0.f, s2 = 0.f;
  for (int i = threadIdx.x; i < M; i += 256) {
    float v = xp[i]; s1 += v; s2 += v * v;
  }
  __shared__ float r1[256], r2[256];
  int tid = threadIdx.x;
  r1[tid] = s1; r2[tid] = s2;
  __syncthreads();
  for (int s = 128; s > 0; s >>= 1) {
    if (tid < s) { r1[tid] += r1[tid + s]; r2[tid] += r2[tid + s]; }
    __syncthreads();
  }
  if (tid == 0) {
    float mean = r1[0] / M;
    float var = r2[0] / M - mean * mean;
    stat[b * 2] = mean;
    stat[b * 2 + 1] = rsqrtf(var + 1e-5f);
  }
}
__global__ void k_ln_norm(const float* x, const float* stat, const float* wn, const float* bn,
                          float* out, int M) {
  int total = NB * M;
  int idx = blockIdx.x * 256 + threadIdx.x;
  if (idx >= total) return;
  int b = idx / M;
  int i = idx % M;
  float y = (x[idx] - stat[b * 2]) * stat[b * 2 + 1];
  out[idx] = y * wn[i] + bn[i];
}

// ---- final head ----
__global__ void k_fin1(const float* h, const float* w, const float* bias, const float* skip,
                       float* out) {
  int total = NB * 64 * NN;
  int idx = blockIdx.x * 256 + threadIdx.x;
  if (idx >= total) return;
  int n = idx % NN;
  int c = (idx / NN) % 64;
  int b = idx / (NN * 64);
  float v = bias[c];
  for (int ci = 0; ci < 32; ci++) v += w[c * 32 + ci] * h[(b * NF + ci) * NN + n];
  v += skip[((size_t)(b * 64 + c) * NN + n) * 7 + 6];
  out[idx] = fmaxf(v, 0.f);
}
__global__ void k_fin2(const float* in, const float* w, const float* bias, float* out) {
  int total = NB * 128 * NN;
  int idx = blockIdx.x * 256 + threadIdx.x;
  if (idx >= total) return;
  int n = idx % NN;
  int c = (idx / NN) % 128;
  int b = idx / (NN * 128);
  float v = bias[c];
  for (int ci = 0; ci < 64; ci++) v += w[c * 64 + ci] * in[(b * 64 + ci) * NN + n];
  out[idx] = fmaxf(v, 0.f);
}
__global__ void k_fin3(const float* in, const float* w, const float* bias, float* out) {
  int total = NB * 12 * NN;
  int idx = blockIdx.x * 256 + threadIdx.x;
  if (idx >= total) return;
  int n = idx % NN;
  int c = (idx / NN) % 12;
  int b = idx / (NN * 12);
  float v = bias[c];
  for (int ci = 0; ci < 128; ci++) v += w[c * 128 + ci] * in[(b * 128 + ci) * NN + n];
  out[idx] = v;
}

#define G1(tot) dim3((unsigned)(((tot) + 255) / 256)), dim3(256), 0, stream

extern "C" void kernel_launch(void* const* d_in, const int* in_sizes, int n_in,
                              void* d_out, int out_size, void* d_ws, size_t ws_size,
                              hipStream_t stream) {
  (void)in_sizes; (void)n_in; (void)out_size; (void)ws_size;
  auto I = [&](int i) { return (const float*)d_in[i]; };
  float* W = (float*)d_ws;
  size_t off = 0;
  auto alloc = [&](size_t nel) { float* p = W + off; off += nel; return p; };

  float* bufA  = alloc(9728000);   // h / residual [B,32,N,19max]
  float* bufB  = alloc(9728000);   // h after fc1; later cheb output (t-major)
  float* bufC  = alloc(9728000);   // x_tat -> s1T -> hT2 ; later gtufc#2 output
  float* bufSK = alloc(7168000);   // skip [B,64,N,7]
  float* skip0 = alloc(1024000);   // skip [B,64,N,1]
  float* P1    = alloc(8000000);   // s0 / st; reused for F1/F2 at end
  float* CT    = alloc(750000);    // chebT
  float* VST   = alloc(250000);    // vs transposed (per layer)
  float* TL1   = alloc(19456);
  float* TLH   = alloc(304000);
  float* TRH   = alloc(304000);
  float* TE    = alloc(11552);
  float* SL1   = alloc(512000);
  float* SLH   = alloc(304000);
  float* SRH   = alloc(304000);
  float* ACC   = alloc(64);
  float* P2 = bufC;                // s1T lives in bufC until smax consumes it
  float* HT = bufC;                // hT2[b][m][t*NF+f] lives in bufC after smax
  float* F1 = P1;                  // [B,64,N] final head, after P1 (st) is dead
  float* F2 = P1 + 1024000;        // [B,128,N]

  k_start<<<G1(NB * NF * NN * 19)>>>(I(0), I(1), I(2), bufA);
  k_skip0<<<G1(NB * 64 * NN)>>>(I(0), I(3), I(4), skip0);
  k_chebT<<<G1(3 * NN * NN)>>>(I(59), CT);

  dim3 ggt((NN + 7) / 8, NB), bgt(256);
  auto gtufc = [&](int Ti, int To, const float* hin, const float* fw, const float* fb,
                   const float* res, float* o) {
    if (Ti == 19 && To == 19)
      k_gtufc_t<19, 19><<<ggt, bgt, 0, stream>>>(hin, I(5), I(6), I(7), I(8), I(9), I(10), fw, fb, res, o);
    else if (Ti == 13 && To == 13)
      k_gtufc_t<13, 13><<<ggt, bgt, 0, stream>>>(hin, I(5), I(6), I(7), I(8), I(9), I(10), fw, fb, res, o);
    else
      k_gtufc_t<7, 7><<<ggt, bgt, 0, stream>>>(hin, I(5), I(6), I(7), I(8), I(9), I(10), fw, fb, res, o);
  };
  auto gtufcx = [&](int Ti, int To, const float* hin, const float* fw, const float* fb,
                    const float* res, float* o) {
    if (Ti == 19)
      k_gtufc_x<19, 13><<<ggt, bgt, 0, stream>>>(hin, I(5), I(6), I(7), I(8), I(9), I(10), fw, fb, res, o);
    else if (Ti == 13)
      k_gtufc_x<13, 7><<<ggt, bgt, 0, stream>>>(hin, I(5), I(6), I(7), I(8), I(9), I(10), fw, fb, res, o);
    else
      k_gtufc_x<7, 1><<<ggt, bgt, 0, stream>>>(hin, I(5), I(6), I(7), I(8), I(9), I(10), fw, fb, res, o);
  };

  const int Tin[3] = {19, 13, 7}, Tout[3] = {13, 7, 1};
  for (int i = 0; i < 3; i++) {
    int Ti = Tin[i], To = Tout[i];
    // gated TCN + fc1 + relu-add : bufA -> bufB
    gtufc(Ti, Ti, bufA, I(11 + 2 * i), I(12 + 2 * i), nullptr, bufB);
    // skip conv
    if (i == 0)
      k_skipconv_t<19, 13><<<ggt, bgt, 0, stream>>>(bufB, I(23), I(24), skip0, 1, bufSK);
    else if (i == 1)
      k_skipconv_t<13, 7><<<ggt, bgt, 0, stream>>>(bufB, I(25), I(26), bufSK, 7, bufSK);
    else
      k_skipconv_t<7, 1><<<ggt, bgt, 0, stream>>>(bufB, I(27), I(28), bufSK, 7, bufSK);
    // temporal attention
    int ba = 29 + i * 10;
    k_ta_lhs1<<<G1(NB * Ti * NF)>>>(bufB, I(ba + 0), TL1, Ti);
    k_ta_lhs<<<G1(NB * Ti * NN)>>>(TL1, I(ba + 1), TLH, Ti);
    k_ta_rhs<<<G1(NB * NN * Ti)>>>(bufB, I(ba + 2), TRH, Ti);
    k_ta_att<<<dim3(NB), dim3(256), 0, stream>>>(TLH, TRH, I(ba + 3), I(ba + 4), TE, Ti);
    k_xtat<<<G1(NB * NF * NN * Ti)>>>(TE, bufB, bufC, Ti);  // x_tat into bufC
    // spatial attention
    k_sa_lhs1<<<G1(NB * NN * NF)>>>(bufC, I(ba + 5), SL1, Ti);
    k_sa_lhs<<<G1(NB * NN * Ti)>>>(SL1, I(ba + 6), SLH, Ti);
    k_sa_rhs<<<G1(NB * Ti * NN)>>>(bufC, I(ba + 7), SRH, Ti);
    k_sa_prod<<<G1(NB * NN * NN)>>>(SLH, SRH, I(ba + 8), P1, Ti);  // x_tat consumed
    k_transpose<<<dim3(16, 16), dim3(256), 0, stream>>>(I(ba + 9), VST);
    {
      dim3 gg(8, 8, NB), bb(16, 16);
      k_gemm_vs<<<gg, bb, 0, stream>>>(VST, P1, P2);  // s1T into bufC
    }
    k_sa_smax_row<<<dim3(NN, NB), dim3(256), 0, stream>>>(P2, P1);  // st into P1; bufC free
    // transpose h for cheb (t-major): bufB -> HT (bufC)
    k_htrans<<<G1(NB * NN * NF * Ti)>>>(bufB, HT, Ti);
    // chebyshev fused GEMM+theta: HT + st -> bufB (t-major output)
    {
      int NFT = NF * Ti;
      dim3 gc((NFT + 127) / 128, 8, NB), bc(256);
      if (Ti == 19)      k_chebg<19><<<gc, bc, 0, stream>>>(HT, P1, CT, I(60), bufB);
      else if (Ti == 13) k_chebg<13><<<gc, bc, 0, stream>>>(HT, P1, CT, I(60), bufB);
      else               k_chebg<7><<<gc, bc, 0, stream>>>(HT, P1, CT, I(60), bufB);
    }
    // second gated TCN (t-major input) + fc2 + relu-add + residual : bufB (+bufA) -> bufC
    gtufcx(Ti, To, bufB, I(17 + 2 * i), I(18 + 2 * i), bufA, bufC);
    // layer norm: bufC -> bufA
    int M = NF * NN * To;
    k_ln_stat<<<dim3(NB), dim3(256), 0, stream>>>(bufC, ACC, M);
    k_ln_norm<<<G1(NB * M)>>>(bufC, ACC, I(61 + 2 * i), I(62 + 2 * i), bufA, M);
  }
  // final head
  k_fin1<<<G1(NB * 64 * NN)>>>(bufA, I(67), I(68), bufSK, F1);
  k_fin2<<<G1(NB * 128 * NN)>>>(F1, I(69), I(70), F2);
  k_fin3<<<G1(NB * 12 * NN)>>>(F2, I(71), I(72), (float*)d_out);
}

// Round 12
// 5546.419 us; speedup vs baseline: 2.4315x; 1.0731x over previous
//
#include <hip/hip_runtime.h>
#include <hip/hip_bf16.h>
#include <math.h>

#define NB 32      // batch
#define NN 500     // nodes
#define NF 32      // channels

__device__ __forceinline__ float sigf(float x) { return 1.0f / (1.0f + __expf(-x)); }

// h[b,c,n,t] = b_start[c] + sum_ci w_start[c,ci]*padded_x[b,ci,n,t]; pad 7 zeros at front (19)
__global__ void k_start(const float* x, const float* w, const float* bias, float* h) {
  int idx = blockIdx.x * 256 + threadIdx.x;
  const int total = NB * NF * NN * 19;
  if (idx >= total) return;
  int t = idx % 19;
  int n = (idx / 19) % NN;
  int c = (idx / (19 * NN)) % NF;
  int b = idx / (19 * NN * NF);
  float v = bias[c];
  if (t >= 7) {
    int tx = t - 7;
    v += w[c * 2 + 0] * x[((size_t)(b * 2 + 0) * NN + n) * 12 + tx];
    v += w[c * 2 + 1] * x[((size_t)(b * 2 + 1) * NN + n) * 12 + tx];
  }
  h[idx] = v;
}

// skip0[b,c,n] = b_sk0[c] + sum_{ci,k>=7} w_sk0[c,ci,k]*x[b,ci,n,k-7]
__global__ void k_skip0(const float* x, const float* w, const float* bias, float* s0) {
  int idx = blockIdx.x * 256 + threadIdx.x;
  const int total = NB * 64 * NN;
  if (idx >= total) return;
  int n = idx % NN;
  int c = (idx / NN) % 64;
  int b = idx / (NN * 64);
  float v = bias[c];
  for (int ci = 0; ci < 2; ci++)
    for (int k = 7; k < 19; k++)
      v += w[(c * 2 + ci) * 19 + k] * x[((size_t)(b * 2 + ci) * NN + n) * 12 + (k - 7)];
  s0[idx] = v;
}

// ---- fused gated-TCN + fc; gtu_seg generalized over LDS strides (TS=time, CS=channel) ----
template<int K, int L, int TS, int CS, int TCAT, int TO>
__device__ __forceinline__ void gtu_seg(const float* __restrict__ wseg,
                                        const float* __restrict__ bg,
                                        const float* __restrict__ hbase,
                                        const float* __restrict__ fw,
                                        float (&oacc)[TO], int c, int tbase) {
  float y0[L], y1[L];
#pragma unroll
  for (int t = 0; t < L; t++) { y0[t] = 0.f; y1[t] = 0.f; }
#pragma unroll 2
  for (int ci = 0; ci < NF; ci++) {
    float hrow[L + K - 1];
#pragma unroll
    for (int t = 0; t < L + K - 1; t++) hrow[t] = hbase[ci * CS + t * TS];
    float w0[K], w1[K];
#pragma unroll
    for (int j = 0; j < K; j++) {
      w0[j] = wseg[(c * NF + ci) * K + j];
      w1[j] = wseg[((c + 32) * NF + ci) * K + j];
    }
#pragma unroll
    for (int t = 0; t < L; t++)
#pragma unroll
      for (int j = 0; j < K; j++) {
        y0[t] += w0[j] * hrow[t + j];
        y1[t] += w1[j] * hrow[t + j];
      }
  }
  float b0 = bg[c], b1 = bg[c + 32];
#pragma unroll
  for (int t = 0; t < L; t++) {
    float tcv = tanhf(y0[t] + b0) * sigf(y1[t] + b1);
#pragma unroll
    for (int o = 0; o < TO; o++) oacc[o] += tcv * fw[o * TCAT + tbase + t];
  }
}

// standard-layout input h[b,c,n,t]
template<int TI, int TO>
__global__ __launch_bounds__(256) void k_gtufc_t(
    const float* __restrict__ h,
    const float* __restrict__ wg3, const float* __restrict__ bg3,
    const float* __restrict__ wg5, const float* __restrict__ bg5,
    const float* __restrict__ wg7, const float* __restrict__ bg7,
    const float* __restrict__ fw, const float* __restrict__ fb,
    const float* __restrict__ res, float* __restrict__ out) {
  constexpr int TCAT = 3 * TI - 12;
  constexpr int TP = (TI + 3) & ~3;
  constexpr int OFF = TI - TO;
  const int b = blockIdx.y;
  const int n0 = blockIdx.x * 8;
  const int tid = threadIdx.x;
  const int c = tid & 31, nn = tid >> 5;
  const int n = n0 + nn;
  __shared__ float hs[8 * NF * TP];
  for (int l = tid; l < 8 * NF * TP; l += 256) {
    int t = l % TP;
    int ci = (l / TP) % NF;
    int n2 = l / (TP * NF);
    int gn = n0 + n2;
    hs[l] = (t < TI && gn < NN) ? h[((size_t)(b * NF + ci) * NN + gn) * TI + t] : 0.f;
  }
  __syncthreads();
  const float* hbase = hs + nn * NF * TP;
  float oacc[TO];
#pragma unroll
  for (int o = 0; o < TO; o++) oacc[o] = 0.f;
  gtu_seg<3, TI - 2, 1, TP, TCAT, TO>(wg3, bg3, hbase, fw, oacc, c, 0);
  gtu_seg<5, TI - 4, 1, TP, TCAT, TO>(wg5, bg5, hbase, fw, oacc, c, TI - 2);
  gtu_seg<7, TI - 6, 1, TP, TCAT, TO>(wg7, bg7, hbase, fw, oacc, c, 2 * TI - 6);
  if (n < NN) {
    size_t base = (size_t)(b * NF + c) * NN + n;
#pragma unroll
    for (int o = 0; o < TO; o++) {
      float v = fmaxf(hbase[c * TP + OFF + o] + oacc[o] + fb[o], 0.f);
      if (res) v += res[base * TI + OFF + o];
      out[base * TO + o] = v;
    }
  }
}

// t-major input hX[b][n][t*NF+f] (cheb output layout); output standard layout
template<int TI, int TO>
__global__ __launch_bounds__(256) void k_gtufc_x(
    const float* __restrict__ hX,
    const float* __restrict__ wg3, const float* __restrict__ bg3,
    const float* __restrict__ wg5, const float* __restrict__ bg5,
    const float* __restrict__ wg7, const float* __restrict__ bg7,
    const float* __restrict__ fw, const float* __restrict__ fb,
    const float* __restrict__ res, float* __restrict__ out) {
  constexpr int TCAT = 3 * TI - 12;
  constexpr int NFT = NF * TI;
  constexpr int OFF = TI - TO;
  const int b = blockIdx.y;
  const int n0 = blockIdx.x * 8;
  const int tid = threadIdx.x;
  const int c = tid & 31, nn = tid >> 5;
  const int n = n0 + nn;
  __shared__ float hs[8 * NFT];
  for (int l = tid; l < 8 * NFT; l += 256) {
    int n2 = l / NFT, l2 = l % NFT;
    int gn = n0 + n2;
    hs[l] = (gn < NN) ? hX[(size_t)(b * NN + gn) * NFT + l2] : 0.f;
  }
  __syncthreads();
  const float* hbase = hs + nn * NFT;
  float oacc[TO];
#pragma unroll
  for (int o = 0; o < TO; o++) oacc[o] = 0.f;
  gtu_seg<3, TI - 2, NF, 1, TCAT, TO>(wg3, bg3, hbase, fw, oacc, c, 0);
  gtu_seg<5, TI - 4, NF, 1, TCAT, TO>(wg5, bg5, hbase, fw, oacc, c, TI - 2);
  gtu_seg<7, TI - 6, NF, 1, TCAT, TO>(wg7, bg7, hbase, fw, oacc, c, 2 * TI - 6);
  if (n < NN) {
    size_t base = (size_t)(b * NF + c) * NN + n;
#pragma unroll
    for (int o = 0; o < TO; o++) {
      float v = fmaxf(hbase[(OFF + o) * NF + c] + oacc[o] + fb[o], 0.f);
      if (res) v += res[base * TI + OFF + o];
      out[base * TO + o] = v;
    }
  }
}

// ---- skip conv, LDS h staging, weights in registers, K unrolled ----
template<int TI, int K>
__global__ __launch_bounds__(256) void k_skipconv_t(
    const float* __restrict__ h, const float* __restrict__ w,
    const float* __restrict__ bias, const float* __restrict__ prev, int prevT,
    float* __restrict__ out) {
  constexpr int TP = (TI + 3) & ~3;
  const int b = blockIdx.y, n0 = blockIdx.x * 8, tid = threadIdx.x;
  __shared__ float hs[8 * NF * TP];
  for (int l = tid; l < 8 * NF * TP; l += 256) {
    int t = l % TP;
    int ci = (l / TP) % NF;
    int n2 = l / (TP * NF);
    int gn = n0 + n2;
    hs[l] = (t < TI && gn < NN) ? h[((size_t)(b * NF + ci) * NN + gn) * TI + t] : 0.f;
  }
  __syncthreads();
  const int c = tid & 63, ng = tid >> 6;
  float bv = bias[c];
  float o[2][7];
#pragma unroll
  for (int q = 0; q < 2; q++)
#pragma unroll
    for (int t = 0; t < 7; t++) o[q][t] = bv;
  for (int ci = 0; ci < NF; ci++) {
    float wv[K];
#pragma unroll
    for (int j = 0; j < K; j++) wv[j] = w[(c * NF + ci) * K + j];
#pragma unroll
    for (int q = 0; q < 2; q++) {
      const float* hp = hs + ((ng + q * 4) * NF + ci) * TP;
#pragma unroll
      for (int t = 0; t < 7; t++) {
        float s = 0.f;
#pragma unroll
        for (int j = 0; j < K; j++) s += wv[j] * hp[t + j];
        o[q][t] += s;
      }
    }
  }
#pragma unroll
  for (int q = 0; q < 2; q++) {
    int n = n0 + ng + q * 4;
    if (n < NN) {
      size_t base = (size_t)(b * 64 + c) * NN + n;
#pragma unroll
      for (int t = 0; t < 7; t++) {
        float pv = (prevT == 1) ? prev[base] : prev[base * 7 + t];
        out[base * 7 + t] = o[q][t] + pv;
      }
    }
  }
}

// ---- temporal attention ----
__global__ void k_ta_lhs1(const float* h, const float* u1, float* out, int T) {
  int total = NB * T * NF;
  int idx = blockIdx.x * 256 + threadIdx.x;
  if (idx >= total) return;
  int f = idx % NF;
  int t = (idx / NF) % T;
  int b = idx / (NF * T);
  const float* hp = h + ((size_t)(b * NF + f) * NN) * T + t;
  float acc = 0.f;
  for (int n = 0; n < NN; n++) acc += hp[(size_t)n * T] * u1[n];
  out[(b * T + t) * NF + f] = acc;
}
__global__ void k_ta_lhs(const float* l1, const float* u2, float* out, int T) {
  int total = NB * T * NN;
  int idx = blockIdx.x * 256 + threadIdx.x;
  if (idx >= total) return;
  int n = idx % NN;
  int t = (idx / NN) % T;
  int b = idx / (NN * T);
  float acc = 0.f;
  for (int f = 0; f < NF; f++) acc += l1[(b * T + t) * NF + f] * u2[f * NN + n];
  out[idx] = acc;  // (b,t,n)
}
__global__ void k_ta_rhs(const float* h, const float* u3, float* out, int T) {
  int total = NB * NN * T;
  int idx = blockIdx.x * 256 + threadIdx.x;
  if (idx >= total) return;
  int t = idx % T;
  int n = (idx / T) % NN;
  int b = idx / (T * NN);
  float acc = 0.f;
  for (int f = 0; f < NF; f++) acc += u3[f] * h[((size_t)(b * NF + f) * NN + n) * T + t];
  out[idx] = acc;  // (b,n,t)
}
// fused: e0 = sigf(lhs@rhs + be); e1 = ve@e0; e = softmax over t. one block per b.
__global__ __launch_bounds__(256) void k_ta_att(const float* __restrict__ lhs,
                                                const float* __restrict__ rhs,
                                                const float* __restrict__ be,
                                                const float* __restrict__ ve,
                                                float* __restrict__ e, int T) {
  int b = blockIdx.x, tid = threadIdx.x;
  __shared__ float e0[19 * 19];
  __shared__ float e1[19 * 19];
  int TT = T * T;
  for (int l = tid; l < TT; l += 256) {
    int t = l / T, m = l % T;
    float acc = 0.f;
    const float* lp = lhs + ((size_t)b * T + t) * NN;
    const float* rp = rhs + (size_t)b * NN * T + m;
    for (int n = 0; n < NN; n++) acc += lp[n] * rp[(size_t)n * T];
    e0[l] = sigf(acc + be[l]);
  }
  __syncthreads();
  for (int l = tid; l < TT; l += 256) {
    int t = l / T, m = l % T;
    float acc = 0.f;
    for (int j = 0; j < T; j++) acc += ve[t * T + j] * e0[j * T + m];
    e1[l] = acc;
  }
  __syncthreads();
  if (tid < T) {
    int m = tid;
    float mx = -1e30f;
    for (int t = 0; t < T; t++) mx = fmaxf(mx, e1[t * T + m]);
    float s = 0.f;
    for (int t = 0; t < T; t++) s += __expf(e1[t * T + m] - mx);
    float inv = 1.f / s;
    for (int t = 0; t < T; t++)
      e[((size_t)b * T + t) * T + m] = __expf(e1[t * T + m] - mx) * inv;
  }
}
// xt[b,f,n,t] = sum_j e[b,t,j] * h[b,f,n,j]
__global__ void k_xtat(const float* e, const float* h, float* xt, int T) {
  int total = NB * NF * NN * T;
  int idx = blockIdx.x * 256 + threadIdx.x;
  if (idx >= total) return;
  int t = idx % T;
  int n = (idx / T) % NN;
  int f = (idx / (T * NN)) % NF;
  int b = idx / (T * NN * NF);
  const float* hp = h + ((size_t)(b * NF + f) * NN + n) * T;
  float acc = 0.f;
  for (int j = 0; j < T; j++) acc += e[(b * T + t) * T + j] * hp[j];
  xt[idx] = acc;
}

// ---- spatial attention ----
__global__ void k_sa_lhs1(const float* xt, const float* w1, float* out, int T) {
  int total = NB * NN * NF;
  int idx = blockIdx.x * 256 + threadIdx.x;
  if (idx >= total) return;
  int f = idx % NF;
  int n = (idx / NF) % NN;
  int b = idx / (NF * NN);
  const float* xp = xt + ((size_t)(b * NF + f) * NN + n) * T;
  float acc = 0.f;
  for (int t = 0; t < T; t++) acc += xp[t] * w1[t];
  out[(b * NN + n) * NF + f] = acc;
}
__global__ void k_sa_lhs(const float* l1, const float* w2, float* out, int T) {
  int total = NB * NN * T;
  int idx = blockIdx.x * 256 + threadIdx.x;
  if (idx >= total) return;
  int t = idx % T;
  int n = (idx / T) % NN;
  int b = idx / (T * NN);
  float acc = 0.f;
  for (int f = 0; f < NF; f++) acc += l1[(b * NN + n) * NF + f] * w2[f * T + t];
  out[idx] = acc;  // (b,n,t)
}
__global__ void k_sa_rhs(const float* xt, const float* w3, float* out, int T) {
  int total = NB * T * NN;
  int idx = blockIdx.x * 256 + threadIdx.x;
  if (idx >= total) return;
  int n = idx % NN;
  int t = (idx / NN) % T;
  int b = idx / (NN * T);
  float acc = 0.f;
  for (int f = 0; f < NF; f++) acc += w3[f] * xt[((size_t)(b * NF + f) * NN + n) * T + t];
  out[idx] = acc;  // (b,t,n)
}
__global__ void k_sa_prod(const float* lhs, const float* rhs, const float* bs, float* s0, int T) {
  int total = NB * NN * NN;
  int idx = blockIdx.x * 256 + threadIdx.x;
  if (idx >= total) return;
  int m = idx % NN;
  int n = (idx / NN) % NN;
  int b = idx / (NN * NN);
  float acc = 0.f;
  for (int t = 0; t < T; t++)
    acc += lhs[((size_t)b * NN + n) * T + t] * rhs[((size_t)b * T + t) * NN + m];
  s0[idx] = sigf(acc + bs[(size_t)n * NN + m]);
}

// 500x500 transpose (for vs)
__global__ __launch_bounds__(256) void k_transpose(const float* in, float* outT) {
  __shared__ float tile[32][33];
  int x0 = blockIdx.x * 32, y0 = blockIdx.y * 32;
  int tx = threadIdx.x & 31, ty8 = threadIdx.x >> 5;
  for (int yy = ty8; yy < 32; yy += 8) {
    int x = x0 + tx, y = y0 + yy;
    tile[yy][tx] = (x < NN && y < NN) ? in[(size_t)y * NN + x] : 0.f;
  }
  __syncthreads();
  for (int yy = ty8; yy < 32; yy += 8) {
    int x = y0 + tx, y = x0 + yy;
    if (x < NN && y < NN) outT[(size_t)y * NN + x] = tile[tx][yy];
  }
}

// s1T[b,c,r] = (vs @ s0[b])[r,c] — 64x128 tile, double-buffered, float4 everywhere
__global__ __launch_bounds__(256) void k_gemm_vs(const float* __restrict__ vsT,
                                                 const float* __restrict__ s0,
                                                 float* __restrict__ s1t) {
  const int b = blockIdx.z;
  const int row0 = blockIdx.y * 64, col0 = blockIdx.x * 128;
  const int tid = threadIdx.x;
  const int tx = tid & 15, ty = tid >> 4;
  __shared__ float smem[6400];      // 2 x (As 16x68 + Bs 16x132)
  float acc[4][8] = {};
  const float* S0 = s0 + (size_t)b * NN * NN;
  const int nch = (NN + 15) / 16;
  float4 pa, pb0, pb1;
  auto loadregs = [&](int k0) {
    {
      int rq = tid & 15, kk = tid >> 4;
      int gk = k0 + kk, gi = row0 + rq * 4;
      float4 v = {0.f, 0.f, 0.f, 0.f};
      if (gk < NN && gi < NN) v = *(const float4*)&vsT[(size_t)gk * NN + gi];
      pa = v;
    }
#pragma unroll
    for (int it = 0; it < 2; it++) {
      int l = tid + it * 256;
      int q = l & 31, kk = l >> 5;
      int gk = k0 + kk, gc = col0 + q * 4;
      float4 v = {0.f, 0.f, 0.f, 0.f};
      if (gk < NN && gc < NN) v = *(const float4*)&S0[(size_t)gk * NN + gc];
      if (it == 0) pb0 = v; else pb1 = v;
    }
  };
  auto writebuf = [&](int buf) {
    float* As = smem + buf * 3200;
    float* Bs = As + 1088;
    {
      int rq = tid & 15, kk = tid >> 4;
      *(float4*)&As[kk * 68 + rq * 4] = pa;
    }
#pragma unroll
    for (int it = 0; it < 2; it++) {
      int l = tid + it * 256;
      int q = l & 31, kk = l >> 5;
      *(float4*)&Bs[kk * 132 + q * 4] = (it == 0) ? pb0 : pb1;
    }
  };
  loadregs(0);
  writebuf(0);
  for (int ch = 0; ch < nch; ch++) {
    int cur = ch & 1;
    if (ch + 1 < nch) loadregs((ch + 1) * 16);
    __syncthreads();
    const float* As = smem + cur * 3200;
    const float* Bs = As + 1088;
#pragma unroll
    for (int kk = 0; kk < 16; kk++) {
      float4 a4 = *(const float4*)&As[kk * 68 + ty * 4];
      float4 b0 = *(const float4*)&Bs[kk * 132 + tx * 4];
      float4 b1 = *(const float4*)&Bs[kk * 132 + 64 + tx * 4];
      float a[4] = {a4.x, a4.y, a4.z, a4.w};
      float bb[8] = {b0.x, b0.y, b0.z, b0.w, b1.x, b1.y, b1.z, b1.w};
#pragma unroll
      for (int i = 0; i < 4; i++)
#pragma unroll
        for (int j = 0; j < 8; j++) acc[i][j] += a[i] * bb[j];
    }
    if (ch + 1 < nch) writebuf((ch + 1) & 1);
  }
  float* S1 = s1t + (size_t)b * NN * NN;
  int gi0 = row0 + ty * 4;
  if (gi0 < NN) {  // NN%4==0 so gi0<NN implies gi0+3<NN
#pragma unroll
    for (int j = 0; j < 8; j++) {
      int gc = col0 + (j < 4 ? tx * 4 + j : 64 + tx * 4 + (j - 4));
      if (gc < NN) {
        float4 v = {acc[0][j], acc[1][j], acc[2][j], acc[3][j]};
        *(float4*)&S1[(size_t)gc * NN + gi0] = v;
      }
    }
  }
}
// softmax over r (contiguous): st[b,c,r] = softmax_r(s1t[b,c,r]); block per (c,b)
__global__ __launch_bounds__(256) void k_sa_smax_row(const float* s1t, float* st) {
  int c = blockIdx.x, b = blockIdx.y;
  int tid = threadIdx.x;
  const float* S = s1t + ((size_t)b * NN + c) * NN;
  float* O = st + ((size_t)b * NN + c) * NN;
  __shared__ float red[256];
  float mx = -1e30f;
  for (int i = tid; i < NN; i += 256) mx = fmaxf(mx, S[i]);
  red[tid] = mx;
  __syncthreads();
  for (int s = 128; s > 0; s >>= 1) {
    if (tid < s) red[tid] = fmaxf(red[tid], red[tid + s]);
    __syncthreads();
  }
  mx = red[0];
  __syncthreads();
  float sum = 0.f;
  for (int i = tid; i < NN; i += 256) sum += __expf(S[i] - mx);
  red[tid] = sum;
  __syncthreads();
  for (int s = 128; s > 0; s >>= 1) {
    if (tid < s) red[tid] += red[tid + s];
    __syncthreads();
  }
  float inv = 1.f / red[0];
  for (int i = tid; i < NN; i += 256) O[i] = __expf(S[i] - mx) * inv;
}

// chebT[k,n,m] = cheb[k,m,n]
__global__ void k_chebT(const float* cheb, float* ct) {
  int total = 3 * NN * NN;
  int idx = blockIdx.x * 256 + threadIdx.x;
  if (idx >= total) return;
  int m = idx % NN;
  int n = (idx / NN) % NN;
  int k = idx / (NN * NN);
  ct[idx] = cheb[((size_t)k * NN + m) * NN + n];
}

// hT2[b][m][t*NF+f] = h[b][f][m][t]  (t-major columns; coalesced writes)
__global__ void k_htrans(const float* __restrict__ h, float* __restrict__ hT2, int T) {
  int NFT = NF * T;
  int total = NB * NN * NFT;
  int idx = blockIdx.x * 256 + threadIdx.x;
  if (idx >= total) return;
  int tf = idx % NFT;
  int m = (idx / NFT) % NN;
  int b = idx / (NFT * NN);
  int f = tf & 31, t = tf >> 5;
  hT2[idx] = h[((size_t)(b * NF + f) * NN + m) * T + t];
}

// ---- chebyshev conv: 64n x 128c tiled GEMM, double-buffered + theta epilogue ----
template<int T>
__global__ __launch_bounds__(256) void k_chebg(const float* __restrict__ hT2,
                                               const float* __restrict__ st,
                                               const float* __restrict__ ct,
                                               const float* __restrict__ theta,
                                               float* __restrict__ outX) {
  constexpr int NFT = NF * T;
  const int b = blockIdx.z;
  const int n0 = blockIdx.y * 64;
  const int cb = blockIdx.x * 128;
  const int tid = threadIdx.x;
  const int tx = tid & 15, ty = tid >> 4;
  __shared__ float smem[8704];      // ping-pong 2x4288 (As 2176 + Bs 2112); epilogue union
  __shared__ float sdiag[64];
  float acc1[4][8] = {}, acc2[4][8] = {};
  const float* hTb = hT2 + (size_t)b * NN * NFT;
  const int nch = (NN + 15) / 16;
  float4 pc[2], ps[2], pb[2];
  auto loadregs = [&](int m0) {
#pragma unroll
    for (int it = 0; it < 2; it++) {
      int l = tid + it * 256;
      int q = l & 3, nn = (l >> 2) & 63, ks = l >> 8;
      int n = n0 + nn, m = m0 + q * 4;
      float4 cv = {0.f, 0.f, 0.f, 0.f}, sv = {0.f, 0.f, 0.f, 0.f};
      if (n < NN && m < NN) {
        cv = *(const float4*)&ct[((size_t)(ks + 1) * NN + n) * NN + m];
        sv = *(const float4*)&st[((size_t)b * NN + n) * NN + m];
      }
      pc[it] = cv; ps[it] = sv;
    }
#pragma unroll
    for (int it = 0; it < 2; it++) {
      int l = tid + it * 256;
      int q = l & 31, kk = l >> 5;
      int m = m0 + kk, c = cb + q * 4;
      float4 v = {0.f, 0.f, 0.f, 0.f};
      if (m < NN && c < NFT) v = *(const float4*)&hTb[(size_t)m * NFT + c];
      pb[it] = v;
    }
  };
  auto writebuf = [&](int buf) {
    float* As = smem + buf * 4288;
    float* Bs = As + 2176;
#pragma unroll
    for (int it = 0; it < 2; it++) {
      int l = tid + it * 256;
      int q = l & 3, nn = (l >> 2) & 63, ks = l >> 8;
      int base = ks * 1088 + nn;
      float4 cv = pc[it], sv = ps[it];
      As[base + (q * 4 + 0) * 68] = cv.x * sv.x;
      As[base + (q * 4 + 1) * 68] = cv.y * sv.y;
      As[base + (q * 4 + 2) * 68] = cv.z * sv.z;
      As[base + (q * 4 + 3) * 68] = cv.w * sv.w;
    }
#pragma unroll
    for (int it = 0; it < 2; it++) {
      int l = tid + it * 256;
      int q = l & 31, kk = l >> 5;
      *(float4*)&Bs[kk * 132 + q * 4] = pb[it];
    }
  };
  loadregs(0);
  writebuf(0);
  for (int ch = 0; ch < nch; ch++) {
    int cur = ch & 1;
    if (ch + 1 < nch) loadregs((ch + 1) * 16);
    __syncthreads();
    const float* As = smem + cur * 4288;
    const float* Bs = As + 2176;
#pragma unroll
    for (int kk = 0; kk < 16; kk++) {
      float4 a1 = *(const float4*)&As[kk * 68 + ty * 4];
      float4 a2 = *(const float4*)&As[1088 + kk * 68 + ty * 4];
      float4 b0 = *(const float4*)&Bs[kk * 132 + tx * 4];
      float4 b1 = *(const float4*)&Bs[kk * 132 + 64 + tx * 4];
      float av1[4] = {a1.x, a1.y, a1.z, a1.w};
      float av2[4] = {a2.x, a2.y, a2.z, a2.w};
      float bb[8] = {b0.x, b0.y, b0.z, b0.w, b1.x, b1.y, b1.z, b1.w};
#pragma unroll
      for (int i = 0; i < 4; i++)
#pragma unroll
        for (int j = 0; j < 8; j++) {
          acc1[i][j] += av1[i] * bb[j];
          acc2[i][j] += av2[i] * bb[j];
        }
    }
    if (ch + 1 < nch) writebuf((ch + 1) & 1);
  }
  if (tid < 64) {
    int n = n0 + tid;
    sdiag[tid] = (n < NN) ? st[((size_t)b * NN + n) * NN + n] : 0.f;
  }
  float* Y1 = smem;                 // [64][68]
  float* Y2 = smem + 4352;
  for (int hh = 0; hh < 2; hh++) {
    __syncthreads();
#pragma unroll
    for (int i = 0; i < 4; i++)
#pragma unroll
      for (int j = 0; j < 4; j++) {
        Y1[(ty * 4 + i) * 68 + tx * 4 + j] = acc1[i][hh * 4 + j];
        Y2[(ty * 4 + i) * 68 + tx * 4 + j] = acc2[i][hh * 4 + j];
      }
    __syncthreads();
    int cbh = cb + hh * 64;
    for (int j = 0; j < 16; j++) {
      int it = tid + j * 256;
      int cc = it & 63, nn = it >> 6;
      int n = n0 + nn, c = cbh + cc;
      if (n < NN && c < NFT) {
        int ts = cc >> 5, f2 = cc & 31;
        int cbb = ts * NF;
        float sd = sdiag[nn];
        const float* hrow = hTb + (size_t)n * NFT + cbh + cbb;  // diag row (broadcast)
        float o = 0.f;
#pragma unroll 8
        for (int f = 0; f < NF; f++) {
          o += theta[f * NF + f2] * (sd * hrow[f])
             + theta[(NF + f) * NF + f2] * Y1[nn * 68 + cbb + f]
             + theta[(2 * NF + f) * NF + f2] * Y2[nn * 68 + cbb + f];
        }
        outX[(size_t)(b * NN + n) * NFT + c] = fmaxf(o, 0.f);
      }
    }
  }
}

// ---- layer norm over (C,N,T) per sample; one block per b ----
__global__ __launch_bounds__(256) void k_ln_stat(const float* x, float* stat, int M) {
  int b = blockIdx.x;
  const float* xp = x + (size_t)b * M;
  float s1 = 0.f, s2 = 0.f;
  for (int i = threadIdx.x; i < M; i += 256) {
    float v = xp[i]; s1 += v; s2 += v * v;
  }
  __shared__ float r1[256], r2[256];
  int tid = threadIdx.x;
  r1[tid] = s1; r2[tid] = s2;
  __syncthreads();
  for (int s = 128; s > 0; s >>= 1) {
    if (tid < s) { r1[tid] += r1[tid + s]; r2[tid] += r2[tid + s]; }
    __syncthreads();
  }
  if (tid == 0) {
    float mean = r1[0] / M;
    float var = r2[0] / M - mean * mean;
    stat[b * 2] = mean;
    stat[b * 2 + 1] = rsqrtf(var + 1e-5f);
  }
}
__global__ void k_ln_norm(const float* x, const float* stat, const float* wn, const float* bn,
                          float* out, int M) {
  int total = NB * M;
  int idx = blockIdx.x * 256 + threadIdx.x;
  if (idx >= total) return;
  int b = idx / M;
  int i = idx % M;
  float y = (x[idx] - stat[b * 2]) * stat[b * 2 + 1];
  out[idx] = y * wn[i] + bn[i];
}

// ---- final head ----
__global__ void k_fin1(const float* h, const float* w, const float* bias, const float* skip,
                       float* out) {
  int total = NB * 64 * NN;
  int idx = blockIdx.x * 256 + threadIdx.x;
  if (idx >= total) return;
  int n = idx % NN;
  int c = (idx / NN) % 64;
  int b = idx / (NN * 64);
  float v = bias[c];
  for (int ci = 0; ci < 32; ci++) v += w[c * 32 + ci] * h[(b * NF + ci) * NN + n];
  v += skip[((size_t)(b * 64 + c) * NN + n) * 7 + 6];
  out[idx] = fmaxf(v, 0.f);
}
__global__ void k_fin2(const float* in, const float* w, const float* bias, float* out) {
  int total = NB * 128 * NN;
  int idx = blockIdx.x * 256 + threadIdx.x;
  if (idx >= total) return;
  int n = idx % NN;
  int c = (idx / NN) % 128;
  int b = idx / (NN * 128);
  float v = bias[c];
  for (int ci = 0; ci < 64; ci++) v += w[c * 64 + ci] * in[(b * 64 + ci) * NN + n];
  out[idx] = fmaxf(v, 0.f);
}
__global__ void k_fin3(const float* in, const float* w, const float* bias, float* out) {
  int total = NB * 12 * NN;
  int idx = blockIdx.x * 256 + threadIdx.x;
  if (idx >= total) return;
  int n = idx % NN;
  int c = (idx / NN) % 12;
  int b = idx / (NN * 12);
  float v = bias[c];
  for (int ci = 0; ci < 128; ci++) v += w[c * 128 + ci] * in[(b * 128 + ci) * NN + n];
  out[idx] = v;
}

#define G1(tot) dim3((unsigned)(((tot) + 255) / 256)), dim3(256), 0, stream

extern "C" void kernel_launch(void* const* d_in, const int* in_sizes, int n_in,
                              void* d_out, int out_size, void* d_ws, size_t ws_size,
                              hipStream_t stream) {
  (void)in_sizes; (void)n_in; (void)out_size; (void)ws_size;
  auto I = [&](int i) { return (const float*)d_in[i]; };
  float* W = (float*)d_ws;
  size_t off = 0;
  auto alloc = [&](size_t nel) { float* p = W + off; off += nel; return p; };

  float* bufA  = alloc(9728000);   // h / residual [B,32,N,19max]
  float* bufB  = alloc(9728000);   // h after fc1; later cheb output (t-major)
  float* bufC  = alloc(9728000);   // x_tat -> s1T -> hT2 ; later gtufc#2 output
  float* bufSK = alloc(7168000);   // skip [B,64,N,7]
  float* skip0 = alloc(1024000);   // skip [B,64,N,1]
  float* P1    = alloc(8000000);   // s0 / st; reused for F1/F2 at end
  float* CT    = alloc(750000);    // chebT
  float* VST   = alloc(250000);    // vs transposed (per layer)
  float* TL1   = alloc(19456);
  float* TLH   = alloc(304000);
  float* TRH   = alloc(304000);
  float* TE    = alloc(11552);
  float* SL1   = alloc(512000);
  float* SLH   = alloc(304000);
  float* SRH   = alloc(304000);
  float* ACC   = alloc(64);
  float* P2 = bufC;                // s1T lives in bufC until smax consumes it
  float* HT = bufC;                // hT2[b][m][t*NF+f] lives in bufC after smax
  float* F1 = P1;                  // [B,64,N] final head, after P1 (st) is dead
  float* F2 = P1 + 1024000;        // [B,128,N]

  k_start<<<G1(NB * NF * NN * 19)>>>(I(0), I(1), I(2), bufA);
  k_skip0<<<G1(NB * 64 * NN)>>>(I(0), I(3), I(4), skip0);
  k_chebT<<<G1(3 * NN * NN)>>>(I(59), CT);

  dim3 ggt((NN + 7) / 8, NB), bgt(256);
  auto gtufc = [&](int Ti, int To, const float* hin, const float* fw, const float* fb,
                   const float* res, float* o) {
    if (Ti == 19 && To == 19)
      k_gtufc_t<19, 19><<<ggt, bgt, 0, stream>>>(hin, I(5), I(6), I(7), I(8), I(9), I(10), fw, fb, res, o);
    else if (Ti == 13 && To == 13)
      k_gtufc_t<13, 13><<<ggt, bgt, 0, stream>>>(hin, I(5), I(6), I(7), I(8), I(9), I(10), fw, fb, res, o);
    else
      k_gtufc_t<7, 7><<<ggt, bgt, 0, stream>>>(hin, I(5), I(6), I(7), I(8), I(9), I(10), fw, fb, res, o);
  };
  auto gtufcx = [&](int Ti, int To, const float* hin, const float* fw, const float* fb,
                    const float* res, float* o) {
    if (Ti == 19)
      k_gtufc_x<19, 13><<<ggt, bgt, 0, stream>>>(hin, I(5), I(6), I(7), I(8), I(9), I(10), fw, fb, res, o);
    else if (Ti == 13)
      k_gtufc_x<13, 7><<<ggt, bgt, 0, stream>>>(hin, I(5), I(6), I(7), I(8), I(9), I(10), fw, fb, res, o);
    else
      k_gtufc_x<7, 1><<<ggt, bgt, 0, stream>>>(hin, I(5), I(6), I(7), I(8), I(9), I(10), fw, fb, res, o);
  };

  const int Tin[3] = {19, 13, 7}, Tout[3] = {13, 7, 1};
  for (int i = 0; i < 3; i++) {
    int Ti = Tin[i], To = Tout[i];
    // gated TCN + fc1 + relu-add : bufA -> bufB
    gtufc(Ti, Ti, bufA, I(11 + 2 * i), I(12 + 2 * i), nullptr, bufB);
    // skip conv
    if (i == 0)
      k_skipconv_t<19, 13><<<ggt, bgt, 0, stream>>>(bufB, I(23), I(24), skip0, 1, bufSK);
    else if (i == 1)
      k_skipconv_t<13, 7><<<ggt, bgt, 0, stream>>>(bufB, I(25), I(26), bufSK, 7, bufSK);
    else
      k_skipconv_t<7, 1><<<ggt, bgt, 0, stream>>>(bufB, I(27), I(28), bufSK, 7, bufSK);
    // temporal attention
    int ba = 29 + i * 10;
    k_ta_lhs1<<<G1(NB * Ti * NF)>>>(bufB, I(ba + 0), TL1, Ti);
    k_ta_lhs<<<G1(NB * Ti * NN)>>>(TL1, I(ba + 1), TLH, Ti);
    k_ta_rhs<<<G1(NB * NN * Ti)>>>(bufB, I(ba + 2), TRH, Ti);
    k_ta_att<<<dim3(NB), dim3(256), 0, stream>>>(TLH, TRH, I(ba + 3), I(ba + 4), TE, Ti);
    k_xtat<<<G1(NB * NF * NN * Ti)>>>(TE, bufB, bufC, Ti);  // x_tat into bufC
    // spatial attention
    k_sa_lhs1<<<G1(NB * NN * NF)>>>(bufC, I(ba + 5), SL1, Ti);
    k_sa_lhs<<<G1(NB * NN * Ti)>>>(SL1, I(ba + 6), SLH, Ti);
    k_sa_rhs<<<G1(NB * Ti * NN)>>>(bufC, I(ba + 7), SRH, Ti);
    k_sa_prod<<<G1(NB * NN * NN)>>>(SLH, SRH, I(ba + 8), P1, Ti);  // x_tat consumed
    k_transpose<<<dim3(16, 16), dim3(256), 0, stream>>>(I(ba + 9), VST);
    {
      dim3 gg((NN + 127) / 128, 8, NB);
      k_gemm_vs<<<gg, dim3(256), 0, stream>>>(VST, P1, P2);  // s1T into bufC
    }
    k_sa_smax_row<<<dim3(NN, NB), dim3(256), 0, stream>>>(P2, P1);  // st into P1; bufC free
    // transpose h for cheb (t-major): bufB -> HT (bufC)
    k_htrans<<<G1(NB * NN * NF * Ti)>>>(bufB, HT, Ti);
    // chebyshev fused GEMM+theta: HT + st -> bufB (t-major output)
    {
      int NFT = NF * Ti;
      dim3 gc((NFT + 127) / 128, 8, NB), bc(256);
      if (Ti == 19)      k_chebg<19><<<gc, bc, 0, stream>>>(HT, P1, CT, I(60), bufB);
      else if (Ti == 13) k_chebg<13><<<gc, bc, 0, stream>>>(HT, P1, CT, I(60), bufB);
      else               k_chebg<7><<<gc, bc, 0, stream>>>(HT, P1, CT, I(60), bufB);
    }
    // second gated TCN (t-major input) + fc2 + relu-add + residual : bufB (+bufA) -> bufC
    gtufcx(Ti, To, bufB, I(17 + 2 * i), I(18 + 2 * i), bufA, bufC);
    // layer norm: bufC -> bufA
    int M = NF * NN * To;
    k_ln_stat<<<dim3(NB), dim3(256), 0, stream>>>(bufC, ACC, M);
    k_ln_norm<<<G1(NB * M)>>>(bufC, ACC, I(61 + 2 * i), I(62 + 2 * i), bufA, M);
  }
  // final head
  k_fin1<<<G1(NB * 64 * NN)>>>(bufA, I(67), I(68), bufSK, F1);
  k_fin2<<<G1(NB * 128 * NN)>>>(F1, I(69), I(70), F2);
  k_fin3<<<G1(NB * 12 * NN)>>>(F2, I(71), I(72), (float*)d_out);
}